// Round 14
// baseline (4530.931 us; speedup 1.0000x reference)
//
#include <hip/hip_runtime.h>
#include <math.h>

#define NN 100000
#define NE 1600000
#define DD 64
#define NL 4
#define NH 4
#define NC 16
#define DIN 192
#define SLOPE 0.2f
#define EB 64
#define XSTR 200
#define FSTR 66
#define LOG2E 1.44269504088896340736f

typedef __bf16 bf8 __attribute__((ext_vector_type(8)));
typedef __bf16 bf4 __attribute__((ext_vector_type(4)));
typedef __bf16 bf2 __attribute__((ext_vector_type(2)));
typedef float f32x4 __attribute__((ext_vector_type(4)));

__device__ __forceinline__ f32x4 MFMA(bf8 a, bf8 b, f32x4 c) {
  return __builtin_amdgcn_mfma_f32_16x16x32_bf16(a, b, c, 0, 0, 0);
}

// ---------------- weight packing: single bf16 plane, 1KB tiles ----------------
__global__ void k_pack_w1(const float* __restrict__ W1, __bf16* __restrict__ WH) {
  int gidx = blockIdx.x * 256 + threadIdx.x;
  if (gidx >= 4 * 4608) return;
  int lyr = gidx / 4608, rem = gidx % 4608;
  int lane = rem & 63, ts = rem >> 6;
  int s = ts % 6, t = ts / 6;
  const float* Wl = W1 + (size_t)lyr * DIN * DIN;
  size_t base = (size_t)lyr * 36864 + ((size_t)(t * 6 + s) * 64 + lane) * 8;
  int k0 = s * 32 + (lane >> 4) * 8, n = t * 16 + (lane & 15);
#pragma unroll
  for (int j = 0; j < 8; ++j)
    WH[base + j] = (__bf16)Wl[(size_t)(k0 + j) * DIN + n];
}

__global__ void k_pack_w2(const float* __restrict__ W2, __bf16* __restrict__ WH) {
  int gidx = blockIdx.x * 256 + threadIdx.x;
  if (gidx >= 4 * 1536) return;
  int lyr = gidx / 1536, rem = gidx % 1536;
  int lane = rem & 63, ts = rem >> 6;
  int s = ts % 6, t = ts / 6;
  const float* Wl = W2 + (size_t)lyr * DIN * DD;
  size_t base = (size_t)lyr * 12288 + ((size_t)(t * 6 + s) * 64 + lane) * 8;
  int k0 = s * 32 + (lane >> 4) * 8, n = t * 16 + (lane & 15);
#pragma unroll
  for (int j = 0; j < 8; ++j)
    WH[base + j] = (__bf16)Wl[(size_t)(k0 + j) * DD + n];
}

// ---------------- CSR build ----------------
__global__ void k_zero(int* __restrict__ deg) {
  int i = blockIdx.x * 256 + threadIdx.x;
  if (i < NN) deg[i] = 0;
}

__global__ void k_hist(const int* __restrict__ dst, int* __restrict__ deg) {
  int e = blockIdx.x * 256 + threadIdx.x;
  if (e < NE) atomicAdd(&deg[dst[e]], 1);
}

__global__ void k_scan1(const int* __restrict__ deg, int* __restrict__ offs,
                        int* __restrict__ bsum) {
  __shared__ int sh[256];
  int t = threadIdx.x, b = blockIdx.x;
  int i0 = b * 1024 + t * 4;
  int d0 = (i0 + 0 < NN) ? deg[i0 + 0] : 0;
  int d1 = (i0 + 1 < NN) ? deg[i0 + 1] : 0;
  int d2 = (i0 + 2 < NN) ? deg[i0 + 2] : 0;
  int d3 = (i0 + 3 < NN) ? deg[i0 + 3] : 0;
  int s4 = d0 + d1 + d2 + d3;
  sh[t] = s4;
  __syncthreads();
  int p = 0;
#pragma unroll
  for (int off = 1; off < 256; off <<= 1) {
    int v = (t >= off) ? sh[t - off] : 0;
    __syncthreads();
    sh[t] += v;
    __syncthreads();
  }
  p = sh[t] - s4;
  if (t == 255) bsum[b] = sh[255];
  if (i0 + 0 < NN) offs[i0 + 0] = p;
  if (i0 + 1 < NN) offs[i0 + 1] = p + d0;
  if (i0 + 2 < NN) offs[i0 + 2] = p + d0 + d1;
  if (i0 + 3 < NN) offs[i0 + 3] = p + d0 + d1 + d2;
}

__global__ void k_scan2(int* __restrict__ bsum, int* __restrict__ boff,
                        int* __restrict__ offs, int nb) {
  if (threadIdx.x == 0 && blockIdx.x == 0) {
    int run = 0;
    for (int k = 0; k < nb; ++k) { boff[k] = run; run += bsum[k]; }
    offs[NN] = NE;
  }
}

__global__ void k_scan3(int* __restrict__ offs, const int* __restrict__ boff,
                        int* __restrict__ cursor) {
  int i = blockIdx.x * 256 + threadIdx.x;
  if (i < NN) {
    int v = offs[i] + boff[i >> 10];
    offs[i] = v;
    cursor[i] = v;
  }
}

__global__ void k_scatter(const int* __restrict__ src, const int* __restrict__ dst,
                          int* __restrict__ cursor, int* __restrict__ csr_src,
                          int* __restrict__ posmap) {
  int e = blockIdx.x * 256 + threadIdx.x;
  if (e >= NE) return;
  int pos = atomicAdd(&cursor[dst[e]], 1);
  csr_src[pos] = src[e];
  posmap[e] = pos;
}

// ---------------- upfront precomputes ----------------
__global__ void k_v_all(const float* __restrict__ ew_all, const float* __restrict__ ae_all,
                        float* __restrict__ vbuf) {
  int l = blockIdx.x;
  const float* ew = ew_all + (size_t)l * DD * DD;
  const float* ae = ae_all + (size_t)l * NH * NC;
  int d = threadIdx.x >> 2, h = threadIdx.x & 3;
  float s = 0.f;
#pragma unroll
  for (int c = 0; c < NC; ++c) s = fmaf(ew[d * DD + h * NC + c], ae[h * NC + c], s);
  vbuf[l * 256 + d * NH + h] = s;
}

__global__ void k_init_nf(const float* __restrict__ node_feats, float* __restrict__ nf) {
  int i = blockIdx.x * 256 + threadIdx.x;
  if (i < NN * DD) nf[i] = node_feats[i];
}

// ---------------- conv path ----------------
__global__ void k_xh(const float* __restrict__ nf, const float* __restrict__ W,
                     const float* __restrict__ as_, const float* __restrict__ ad_,
                     __bf16* __restrict__ xh16, float* __restrict__ asrc,
                     float* __restrict__ adst) {
  int t = blockIdx.x * 4 + (threadIdx.x >> 6);
  int d = threadIdx.x & 63;
  if (t >= NN) return;
  const float* x = nf + (size_t)t * DD;
  float acc = 0.f;
#pragma unroll
  for (int k = 0; k < DD; ++k) acc = fmaf(x[k], W[k * DD + d], acc);
  xh16[(size_t)t * DD + d] = (__bf16)acc;
  int h = d >> 4, c = d & 15;
  float ps = acc * as_[h * NC + c];
  float pd = acc * ad_[h * NC + c];
#pragma unroll
  for (int off = 8; off >= 1; off >>= 1) {
    ps += __shfl_xor(ps, off, 64);
    pd += __shfl_xor(pd, off, 64);
  }
  if (c == 0) { asrc[t * NH + h] = ps; adst[t * NH + h] = pd; }
}

// pass1 layer 0: reads edge_feats fp32, writes ef16 AND finished alpha
__global__ void k_pass1f(const float* __restrict__ edge_feats,
                         const int* __restrict__ src, const int* __restrict__ dst,
                         const float* __restrict__ v,
                         const float* __restrict__ asrc, const float* __restrict__ adst,
                         const int* __restrict__ posmap,
                         __bf16* __restrict__ ef16, float* __restrict__ araw) {
  int e = blockIdx.x * 64 + (threadIdx.x >> 2);
  int part = threadIdx.x & 3;
  if (e >= NE) return;
  int s = src[e], t = dst[e];
  float ph0 = 0.f, ph1 = 0.f, ph2 = 0.f, ph3 = 0.f;
  const float4* ep = (const float4*)(edge_feats + (size_t)e * DD + part * 16);
  const float4* v4 = (const float4*)v;
  bf4 outv[4];
#pragma unroll
  for (int c4 = 0; c4 < 4; ++c4) {
    float4 x = ep[c4];
    outv[c4][0] = (__bf16)x.x; outv[c4][1] = (__bf16)x.y;
    outv[c4][2] = (__bf16)x.z; outv[c4][3] = (__bf16)x.w;
    int d0 = part * 16 + c4 * 4;
    float4 va = v4[d0], vb = v4[d0 + 1], vc = v4[d0 + 2], vd = v4[d0 + 3];
    ph0 = fmaf(x.x, va.x, fmaf(x.y, vb.x, fmaf(x.z, vc.x, fmaf(x.w, vd.x, ph0))));
    ph1 = fmaf(x.x, va.y, fmaf(x.y, vb.y, fmaf(x.z, vc.y, fmaf(x.w, vd.y, ph1))));
    ph2 = fmaf(x.x, va.z, fmaf(x.y, vb.z, fmaf(x.z, vc.z, fmaf(x.w, vd.z, ph2))));
    ph3 = fmaf(x.x, va.w, fmaf(x.y, vb.w, fmaf(x.z, vc.w, fmaf(x.w, vd.w, ph3))));
  }
  *(bf8*)&ef16[(size_t)e * DD + part * 16] =
      (bf8){outv[0][0], outv[0][1], outv[0][2], outv[0][3],
            outv[1][0], outv[1][1], outv[1][2], outv[1][3]};
  *(bf8*)&ef16[(size_t)e * DD + part * 16 + 8] =
      (bf8){outv[2][0], outv[2][1], outv[2][2], outv[2][3],
            outv[3][0], outv[3][1], outv[3][2], outv[3][3]};
#pragma unroll
  for (int off = 1; off <= 2; off <<= 1) {
    ph0 += __shfl_xor(ph0, off, 64);
    ph1 += __shfl_xor(ph1, off, 64);
    ph2 += __shfl_xor(ph2, off, 64);
    ph3 += __shfl_xor(ph3, off, 64);
  }
  float pe = (part == 0) ? ph0 : (part == 1) ? ph1 : (part == 2) ? ph2 : ph3;
  float a = asrc[s * NH + part] + adst[t * NH + part] + pe;
  a = (a > 0.f) ? a : SLOPE * a;
  araw[(size_t)posmap[e] * NH + part] = a * LOG2E;
}

// pass1 layers 1..3: reads ef16
__global__ void k_pass1b(const __bf16* __restrict__ ef16,
                         const int* __restrict__ src, const int* __restrict__ dst,
                         const float* __restrict__ v,
                         const float* __restrict__ asrc, const float* __restrict__ adst,
                         const int* __restrict__ posmap, float* __restrict__ araw) {
  int e = blockIdx.x * 64 + (threadIdx.x >> 2);
  int part = threadIdx.x & 3;
  if (e >= NE) return;
  int s = src[e], t = dst[e];
  float ph0 = 0.f, ph1 = 0.f, ph2 = 0.f, ph3 = 0.f;
  const bf8* ep = (const bf8*)(ef16 + (size_t)e * DD + part * 16);
  bf8 x0 = ep[0], x1 = ep[1];
  const float4* v4 = (const float4*)v;
#pragma unroll
  for (int m = 0; m < 16; ++m) {
    float xv = (m < 8) ? (float)x0[m] : (float)x1[m - 8];
    float4 vn = v4[part * 16 + m];
    ph0 = fmaf(xv, vn.x, ph0);
    ph1 = fmaf(xv, vn.y, ph1);
    ph2 = fmaf(xv, vn.z, ph2);
    ph3 = fmaf(xv, vn.w, ph3);
  }
#pragma unroll
  for (int off = 1; off <= 2; off <<= 1) {
    ph0 += __shfl_xor(ph0, off, 64);
    ph1 += __shfl_xor(ph1, off, 64);
    ph2 += __shfl_xor(ph2, off, 64);
    ph3 += __shfl_xor(ph3, off, 64);
  }
  float pe = (part == 0) ? ph0 : (part == 1) ? ph1 : (part == 2) ? ph2 : ph3;
  float a = asrc[s * NH + part] + adst[t * NH + part] + pe;
  a = (a > 0.f) ? a : SLOPE * a;
  araw[(size_t)posmap[e] * NH + part] = a * LOG2E;
}

// gather: araw holds finished alpha (leaky'd, *LOG2E)
__global__ __launch_bounds__(256) void k_gather(
    const __bf16* __restrict__ xh16, const float* __restrict__ araw,
    const int* __restrict__ csr_src, const int* __restrict__ offs,
    const float* __restrict__ asrc, const float* __restrict__ adst,
    const float* __restrict__ cb, const float* __restrict__ g,
    const float* __restrict__ bln, float* __restrict__ nf,
    __bf16* __restrict__ nf16) {
  int t = blockIdx.x * 4 + (threadIdx.x >> 6);
  int d = threadIdx.x & 63;
  if (t >= NN) return;
  int h = d >> 4;
  int o0 = offs[t], o1 = offs[t + 1];
  int deg = o1 - o0;

  float m0 = -INFINITY, m1 = -INFINITY, m2 = -INFINITY, m3 = -INFINITY;
  for (int base = 0; base < deg; base += 64) {
    int j = base + d;
    if (j < deg) {
      float4 a = *(const float4*)(araw + (size_t)(o0 + j) * NH);
      m0 = fmaxf(m0, a.x); m1 = fmaxf(m1, a.y);
      m2 = fmaxf(m2, a.z); m3 = fmaxf(m3, a.w);
    }
  }
#pragma unroll
  for (int off = 32; off >= 1; off >>= 1) {
    m0 = fmaxf(m0, __shfl_xor(m0, off, 64));
    m1 = fmaxf(m1, __shfl_xor(m1, off, 64));
    m2 = fmaxf(m2, __shfl_xor(m2, off, 64));
    m3 = fmaxf(m3, __shfl_xor(m3, off, 64));
  }
  float sh = asrc[t * NH + h] + adst[t * NH + h];
  sh = ((sh > 0.f) ? sh : SLOPE * sh) * LOG2E;
  float mh = (h == 0) ? m0 : (h == 1) ? m1 : (h == 2) ? m2 : m3;
  mh = fmaxf(mh, sh);

  float acc = 0.f, wsum = 0.f;
  int j = 0;
  for (; j + 1 < deg; j += 2) {
    int sp0 = csr_src[o0 + j], sp1 = csr_src[o0 + j + 1];
    float ar0 = araw[(size_t)(o0 + j) * NH + h];
    float ar1 = araw[(size_t)(o0 + j + 1) * NH + h];
    float w0 = exp2f(ar0 - mh), w1 = exp2f(ar1 - mh);
    acc = fmaf(w0, (float)xh16[(size_t)sp0 * DD + d], acc);
    acc = fmaf(w1, (float)xh16[(size_t)sp1 * DD + d], acc);
    wsum += w0 + w1;
  }
  if (j < deg) {
    int sp = csr_src[o0 + j];
    float ar = araw[(size_t)(o0 + j) * NH + h];
    float w = exp2f(ar - mh);
    acc = fmaf(w, (float)xh16[(size_t)sp * DD + d], acc);
    wsum += w;
  }
  float wself = exp2f(sh - mh);
  acc = fmaf(wself, (float)xh16[(size_t)t * DD + d], acc);
  wsum += wself;

  float val = acc / (wsum + 1e-16f) + cb[d];
  float m = val;
#pragma unroll
  for (int off = 32; off >= 1; off >>= 1) m += __shfl_xor(m, off, 64);
  m *= (1.f / 64.f);
  float c = val - m;
  float q = c * c;
#pragma unroll
  for (int off = 32; off >= 1; off >>= 1) q += __shfl_xor(q, off, 64);
  float rstd = 1.f / sqrtf(q * (1.f / 64.f) + 1e-5f);
  float y = c * rstd * g[d] + bln[d];
  y = fmaxf(y, 0.f);
  float out = y + nf[(size_t)t * DD + d];
  nf[(size_t)t * DD + d] = out;
  nf16[(size_t)t * DD + d] = (__bf16)out;
}

// ---------------- edge MLP v11: 64 edges, 768 thr, 12 waves (low-VGPR) -------
// Wave w owns ALL 64 rows x GEMM1 n-tile t=w (16 cols) -> acc[4] only (16 AGPR).
// GEMM2's 16 (cg,rt) units: wave w does unit w; waves 0..3 also unit 12+w.
// ef16 carry, dedup LN, LDS output funnel (full-line stores) as in v10.
__global__ __launch_bounds__(768) void k_edge_mlp11(
    const __bf16* __restrict__ nf16, __bf16* __restrict__ ef16,
    float* __restrict__ efout,
    const int* __restrict__ src, const int* __restrict__ dst,
    const __bf16* __restrict__ W1H, const float* __restrict__ b1,
    const float* __restrict__ g, const float* __restrict__ bg,
    const __bf16* __restrict__ W2H, const float* __restrict__ b2, int last) {
  __shared__ __bf16 XH[EB * XSTR];   // 25600 B: X | H | f32 output funnel
  __shared__ __bf16 Pb[EB * 24];     // 3072 B: 12 wave-partials (sm,sq) per row
  int tid = threadIdx.x;
  int e0 = blockIdx.x * EB;
  float* XF = (float*)XH;            // funnel view (64*66*4 = 16896 B)

  // stage X: 768 threads = 64 rows x 3 sections x 4 quarters; 32B per thread
  {
    int row = tid / 12, rem = tid % 12;
    int sec = rem >> 2, p = rem & 3;
    const bf8* sp;
    if (sec == 0)      sp = (const bf8*)(nf16 + (size_t)src[e0 + row] * DD + p * 16);
    else if (sec == 1) sp = (const bf8*)(nf16 + (size_t)dst[e0 + row] * DD + p * 16);
    else               sp = (const bf8*)(ef16 + (size_t)(e0 + row) * DD + p * 16);
    bf8 v0 = sp[0], v1 = sp[1];
    *(bf8*)&XH[row * XSTR + sec * 64 + p * 16]     = v0;
    *(bf8*)&XH[row * XSTR + sec * 64 + p * 16 + 8] = v1;
  }
  __syncthreads();

  int w = tid >> 6, l = tid & 63;
  int gq = l >> 4, i = l & 15;

  f32x4 acc[4];
#pragma unroll
  for (int rt = 0; rt < 4; ++rt) acc[rt] = (f32x4){0.f, 0.f, 0.f, 0.f};

  // GEMM1: wave w -> cols w*16..w*16+15, all 64 rows; no barriers
#pragma unroll
  for (int s = 0; s < 6; ++s) {
    bf8 bh = *(const bf8*)(W1H + ((size_t)(w * 6 + s) * 64 + l) * 8);
#pragma unroll
    for (int rt = 0; rt < 4; ++rt) {
      bf8 a = *(const bf8*)&XH[(rt * 16 + i) * XSTR + s * 32 + gq * 8];
      acc[rt] = MFMA(a, bh, acc[rt]);
    }
  }

  // GEMM2 unit assignment + residual snapshot from staged ef (pre-overwrite)
  int u1 = w;                       // unit = cg*4+rt
  int u2 = (w < 4) ? 12 + w : -1;
  float res1[4], res2[4];
  {
    int cg = u1 >> 2, rt = u1 & 3;
#pragma unroll
    for (int r = 0; r < 4; ++r)
      res1[r] = (float)XH[(rt * 16 + gq * 4 + r) * XSTR + 128 + cg * 16 + i];
  }
  if (u2 >= 0) {
    int cg = u2 >> 2, rt = u2 & 3;
#pragma unroll
    for (int r = 0; r < 4; ++r)
      res2[r] = (float)XH[(rt * 16 + gq * 4 + r) * XSTR + 128 + cg * 16 + i];
  }

  // bias + per-wave LN partials (16 cols each)
  float b1v = b1[w * 16 + i];
  float gv  = g[w * 16 + i];
  float bgv = bg[w * 16 + i];
#pragma unroll
  for (int rt = 0; rt < 4; ++rt)
#pragma unroll
    for (int r = 0; r < 4; ++r) acc[rt][r] += b1v;

#pragma unroll
  for (int rt = 0; rt < 4; ++rt)
#pragma unroll
    for (int r = 0; r < 4; ++r) {
      float x = acc[rt][r];
      float sm = x, sq = x * x;
#pragma unroll
      for (int off = 1; off <= 8; off <<= 1) {
        sm += __shfl_xor(sm, off, 64);
        sq += __shfl_xor(sq, off, 64);
      }
      if (i == 0) {
        int row = rt * 16 + gq * 4 + r;
        bf2 pr; pr[0] = (__bf16)sm; pr[1] = (__bf16)sq;
        *(bf2*)&Pb[row * 24 + w * 2] = pr;
      }
    }
  __syncthreads();   // barrier 1: partials ready; all X/ef reads done

  // per-row finalize, once (thread tid<64 owns row tid); result into slot 0
  if (tid < EB) {
    float sm = 0.f, sq = 0.f;
#pragma unroll
    for (int k = 0; k < 12; ++k) {
      bf2 pv = *(const bf2*)&Pb[tid * 24 + k * 2];
      sm += (float)pv[0]; sq += (float)pv[1];
    }
    float mean = sm * (1.f / (float)DIN);
    float var = sq * (1.f / (float)DIN) - mean * mean;
    float rstd = 1.f / sqrtf(var + 1e-5f);
    bf2 mv; mv[0] = (__bf16)mean; mv[1] = (__bf16)rstd;
    *(bf2*)&Pb[tid * 24] = mv;
  }
  __syncthreads();   // barrier 2: (mean,rstd) ready

  // LN apply + relu, write H over X (wave's 16 cols)
#pragma unroll
  for (int rt = 0; rt < 4; ++rt)
#pragma unroll
    for (int r = 0; r < 4; ++r) {
      int row = rt * 16 + gq * 4 + r;
      bf2 mv = *(const bf2*)&Pb[row * 24];
      float mean = (float)mv[0], rstd = (float)mv[1];
      float y = (acc[rt][r] - mean) * rstd * gv + bgv;
      XH[row * XSTR + w * 16 + i] = (__bf16)fmaxf(y, 0.f);
    }
  __syncthreads();   // barrier 3: H fully published

  // GEMM2: unit u = (cg = u>>2, rt = u&3): rows rt*16.., cols cg*16..
  f32x4 acc21 = (f32x4){0.f, 0.f, 0.f, 0.f};
  f32x4 acc22 = (f32x4){0.f, 0.f, 0.f, 0.f};
  {
    int cg1 = u1 >> 2, rt1 = u1 & 3;
    int cg2 = (u2 >= 0) ? (u2 >> 2) : 0, rt2 = (u2 >= 0) ? (u2 & 3) : 0;
#pragma unroll
    for (int s = 0; s < 6; ++s) {
      bf8 a1 = *(const bf8*)&XH[(rt1 * 16 + i) * XSTR + s * 32 + gq * 8];
      bf8 bh1 = *(const bf8*)(W2H + ((size_t)(cg1 * 6 + s) * 64 + l) * 8);
      acc21 = MFMA(a1, bh1, acc21);
      if (u2 >= 0) {
        bf8 a2 = *(const bf8*)&XH[(rt2 * 16 + i) * XSTR + s * 32 + gq * 8];
        bf8 bh2 = *(const bf8*)(W2H + ((size_t)(cg2 * 6 + s) * 64 + l) * 8);
        acc22 = MFMA(a2, bh2, acc22);
      }
    }
  }
  __syncthreads();   // barrier 4: all H reads done; XH free for funnel

  {
    int cg = u1 >> 2, rt = u1 & 3;
    float b2v = b2[cg * 16 + i];
#pragma unroll
    for (int r = 0; r < 4; ++r)
      XF[(rt * 16 + gq * 4 + r) * FSTR + cg * 16 + i] = acc21[r] + b2v + res1[r];
  }
  if (u2 >= 0) {
    int cg = u2 >> 2, rt = u2 & 3;
    float b2v = b2[cg * 16 + i];
#pragma unroll
    for (int r = 0; r < 4; ++r)
      XF[(rt * 16 + gq * 4 + r) * FSTR + cg * 16 + i] = acc22[r] + b2v + res2[r];
  }
  __syncthreads();   // barrier 5: funnel filled

  // full-line coalesced output: thread tid<256 owns (row = tid>>2, q = tid&3)
  if (tid < 256) {
    int row = tid >> 2, q = tid & 3;
    const float* fr = &XF[row * FSTR + q * 16];
    if (last) {
      float* op = efout + (size_t)(e0 + row) * DD + q * 16;
#pragma unroll
      for (int k = 0; k < 4; ++k)
        *(float4*)(op + k * 4) = *(const float4*)(fr + k * 4);
    } else {
      bf8 o0, o1;
#pragma unroll
      for (int k = 0; k < 8; ++k) { o0[k] = (__bf16)fr[k]; o1[k] = (__bf16)fr[k + 8]; }
      __bf16* op = ef16 + (size_t)(e0 + row) * DD + q * 16;
      *(bf8*)op = o0;
      *(bf8*)(op + 8) = o1;
    }
  }
}

extern "C" void kernel_launch(void* const* d_in, const int* in_sizes, int n_in,
                              void* d_out, int out_size, void* d_ws, size_t ws_size,
                              hipStream_t stream) {
  const float* node_feats = (const float*)d_in[0];
  const float* edge_feats = (const float*)d_in[1];
  const int*   edge_index = (const int*)d_in[2];
  const float* conv_w  = (const float*)d_in[3];
  const float* att_src = (const float*)d_in[4];
  const float* att_dst = (const float*)d_in[5];
  const float* edge_w  = (const float*)d_in[6];
  const float* att_edge= (const float*)d_in[7];
  const float* conv_b  = (const float*)d_in[8];
  const float* ln_g    = (const float*)d_in[9];
  const float* ln_b    = (const float*)d_in[10];
  const float* up1_w   = (const float*)d_in[11];
  const float* up1_b   = (const float*)d_in[12];
  const float* up_ln_g = (const float*)d_in[13];
  const float* up_ln_b = (const float*)d_in[14];
  const float* up2_w   = (const float*)d_in[15];
  const float* up2_b   = (const float*)d_in[16];

  const int* src = edge_index;
  const int* dst = edge_index + NE;

  float* nf = (float*)d_out;
  float* efout = nf + (size_t)NN * DD;

  float* w = (float*)d_ws;
  __bf16* xh16 = (__bf16*)w; w += (size_t)NN * DD / 2;
  __bf16* nf16 = (__bf16*)w; w += (size_t)NN * DD / 2;
  __bf16* ef16 = (__bf16*)w; w += (size_t)NE * DD / 2;
  float* asrc  = w; w += (size_t)NN * NH;
  float* adst  = w; w += (size_t)NN * NH;
  float* araw  = w; w += (size_t)NE * NH;
  float* vbuf  = w; w += 4 * 256;
  __bf16* W1H  = (__bf16*)w; w += (size_t)4 * 36864 / 2;
  __bf16* W2H  = (__bf16*)w; w += (size_t)4 * 12288 / 2;
  int* deg     = (int*)w; w += NN;
  int* offs    = (int*)w; w += NN + 1;
  int* cursor  = (int*)w; w += NN;
  int* bsum    = (int*)w; w += 128;
  int* boff    = (int*)w; w += 128;
  int* csr_src = (int*)w; w += NE;
  int* posmap  = (int*)w; w += NE;

  k_init_nf<<<(NN * DD + 255) / 256, 256, 0, stream>>>(node_feats, nf);
  k_pack_w1<<<72, 256, 0, stream>>>(up1_w, W1H);
  k_pack_w2<<<24, 256, 0, stream>>>(up2_w, W2H);

  const int nb = (NN + 1023) / 1024;
  k_zero<<<(NN + 255) / 256, 256, 0, stream>>>(deg);
  k_hist<<<(NE + 255) / 256, 256, 0, stream>>>(dst, deg);
  k_scan1<<<nb, 256, 0, stream>>>(deg, offs, bsum);
  k_scan2<<<1, 64, 0, stream>>>(bsum, boff, offs, nb);
  k_scan3<<<(NN + 255) / 256, 256, 0, stream>>>(offs, boff, cursor);
  k_scatter<<<(NE + 255) / 256, 256, 0, stream>>>(src, dst, cursor, csr_src, posmap);

  k_v_all<<<4, 256, 0, stream>>>(edge_w, att_edge, vbuf);

  for (int l = 0; l < NL; ++l) {
    int last = (l == NL - 1) ? 1 : 0;
    k_xh<<<NN / 4, 256, 0, stream>>>(nf, conv_w + (size_t)l * DD * DD,
                                     att_src + (size_t)l * NH * NC,
                                     att_dst + (size_t)l * NH * NC, xh16, asrc, adst);
    if (l == 0)
      k_pass1f<<<NE / 64, 256, 0, stream>>>(edge_feats, src, dst, vbuf,
                                            asrc, adst, posmap, ef16, araw);
    else
      k_pass1b<<<NE / 64, 256, 0, stream>>>(ef16, src, dst,
                                            vbuf + (size_t)l * 256,
                                            asrc, adst, posmap, araw);
    k_gather<<<NN / 4, 256, 0, stream>>>(xh16, araw, csr_src, offs, asrc, adst,
                                         conv_b + (size_t)l * DD,
                                         ln_g + (size_t)l * DD,
                                         ln_b + (size_t)l * DD, nf, nf16);
    k_edge_mlp11<<<NE / EB, 768, 0, stream>>>(
        nf16, ef16, efout, src, dst,
        W1H + (size_t)l * 36864, up1_b + (size_t)l * DIN,
        up_ln_g + (size_t)l * DIN, up_ln_b + (size_t)l * DIN,
        W2H + (size_t)l * 12288, up2_b + (size_t)l * DD, last);
  }
}

// Round 15
// 3492.394 us; speedup vs baseline: 1.2974x; 1.2974x over previous
//
#include <hip/hip_runtime.h>
#include <math.h>

#define NN 100000
#define NE 1600000
#define DD 64
#define NL 4
#define NH 4
#define NC 16
#define DIN 192
#define SLOPE 0.2f
#define EB 128
#define XSTR 200
#define FSTR 66
#define LOG2E 1.44269504088896340736f

typedef __bf16 bf8 __attribute__((ext_vector_type(8)));
typedef __bf16 bf4 __attribute__((ext_vector_type(4)));
typedef __bf16 bf2 __attribute__((ext_vector_type(2)));
typedef float f32x4 __attribute__((ext_vector_type(4)));

__device__ __forceinline__ f32x4 MFMA(bf8 a, bf8 b, f32x4 c) {
  return __builtin_amdgcn_mfma_f32_16x16x32_bf16(a, b, c, 0, 0, 0);
}

// ---------------- weight packing: single bf16 plane, 1KB tiles ----------------
__global__ void k_pack_w1(const float* __restrict__ W1, __bf16* __restrict__ WH) {
  int gidx = blockIdx.x * 256 + threadIdx.x;
  if (gidx >= 4 * 4608) return;
  int lyr = gidx / 4608, rem = gidx % 4608;
  int lane = rem & 63, ts = rem >> 6;
  int s = ts % 6, t = ts / 6;
  const float* Wl = W1 + (size_t)lyr * DIN * DIN;
  size_t base = (size_t)lyr * 36864 + ((size_t)(t * 6 + s) * 64 + lane) * 8;
  int k0 = s * 32 + (lane >> 4) * 8, n = t * 16 + (lane & 15);
#pragma unroll
  for (int j = 0; j < 8; ++j)
    WH[base + j] = (__bf16)Wl[(size_t)(k0 + j) * DIN + n];
}

__global__ void k_pack_w2(const float* __restrict__ W2, __bf16* __restrict__ WH) {
  int gidx = blockIdx.x * 256 + threadIdx.x;
  if (gidx >= 4 * 1536) return;
  int lyr = gidx / 1536, rem = gidx % 1536;
  int lane = rem & 63, ts = rem >> 6;
  int s = ts % 6, t = ts / 6;
  const float* Wl = W2 + (size_t)lyr * DIN * DD;
  size_t base = (size_t)lyr * 12288 + ((size_t)(t * 6 + s) * 64 + lane) * 8;
  int k0 = s * 32 + (lane >> 4) * 8, n = t * 16 + (lane & 15);
#pragma unroll
  for (int j = 0; j < 8; ++j)
    WH[base + j] = (__bf16)Wl[(size_t)(k0 + j) * DD + n];
}

// ---------------- CSR build ----------------
__global__ void k_zero(int* __restrict__ deg) {
  int i = blockIdx.x * 256 + threadIdx.x;
  if (i < NN) deg[i] = 0;
}

__global__ void k_hist(const int* __restrict__ dst, int* __restrict__ deg) {
  int e = blockIdx.x * 256 + threadIdx.x;
  if (e < NE) atomicAdd(&deg[dst[e]], 1);
}

__global__ void k_scan1(const int* __restrict__ deg, int* __restrict__ offs,
                        int* __restrict__ bsum) {
  __shared__ int sh[256];
  int t = threadIdx.x, b = blockIdx.x;
  int i0 = b * 1024 + t * 4;
  int d0 = (i0 + 0 < NN) ? deg[i0 + 0] : 0;
  int d1 = (i0 + 1 < NN) ? deg[i0 + 1] : 0;
  int d2 = (i0 + 2 < NN) ? deg[i0 + 2] : 0;
  int d3 = (i0 + 3 < NN) ? deg[i0 + 3] : 0;
  int s4 = d0 + d1 + d2 + d3;
  sh[t] = s4;
  __syncthreads();
  int p = 0;
#pragma unroll
  for (int off = 1; off < 256; off <<= 1) {
    int v = (t >= off) ? sh[t - off] : 0;
    __syncthreads();
    sh[t] += v;
    __syncthreads();
  }
  p = sh[t] - s4;
  if (t == 255) bsum[b] = sh[255];
  if (i0 + 0 < NN) offs[i0 + 0] = p;
  if (i0 + 1 < NN) offs[i0 + 1] = p + d0;
  if (i0 + 2 < NN) offs[i0 + 2] = p + d0 + d1;
  if (i0 + 3 < NN) offs[i0 + 3] = p + d0 + d1 + d2;
}

__global__ void k_scan2(int* __restrict__ bsum, int* __restrict__ boff,
                        int* __restrict__ offs, int nb) {
  if (threadIdx.x == 0 && blockIdx.x == 0) {
    int run = 0;
    for (int k = 0; k < nb; ++k) { boff[k] = run; run += bsum[k]; }
    offs[NN] = NE;
  }
}

__global__ void k_scan3(int* __restrict__ offs, const int* __restrict__ boff,
                        int* __restrict__ cursor) {
  int i = blockIdx.x * 256 + threadIdx.x;
  if (i < NN) {
    int v = offs[i] + boff[i >> 10];
    offs[i] = v;
    cursor[i] = v;
  }
}

__global__ void k_scatter(const int* __restrict__ src, const int* __restrict__ dst,
                          int* __restrict__ cursor, int* __restrict__ csr_src,
                          int* __restrict__ posmap) {
  int e = blockIdx.x * 256 + threadIdx.x;
  if (e >= NE) return;
  int pos = atomicAdd(&cursor[dst[e]], 1);
  csr_src[pos] = src[e];
  posmap[e] = pos;
}

// ---------------- upfront precomputes ----------------
__global__ void k_v_all(const float* __restrict__ ew_all, const float* __restrict__ ae_all,
                        float* __restrict__ vbuf) {
  int l = blockIdx.x;
  const float* ew = ew_all + (size_t)l * DD * DD;
  const float* ae = ae_all + (size_t)l * NH * NC;
  int d = threadIdx.x >> 2, h = threadIdx.x & 3;
  float s = 0.f;
#pragma unroll
  for (int c = 0; c < NC; ++c) s = fmaf(ew[d * DD + h * NC + c], ae[h * NC + c], s);
  vbuf[l * 256 + d * NH + h] = s;
}

__global__ void k_init_nf(const float* __restrict__ node_feats, float* __restrict__ nf) {
  int i = blockIdx.x * 256 + threadIdx.x;
  if (i < NN * DD) nf[i] = node_feats[i];
}

// ---------------- conv path ----------------
__global__ void k_xh(const float* __restrict__ nf, const float* __restrict__ W,
                     const float* __restrict__ as_, const float* __restrict__ ad_,
                     __bf16* __restrict__ xh16, float* __restrict__ asrc,
                     float* __restrict__ adst) {
  int t = blockIdx.x * 4 + (threadIdx.x >> 6);
  int d = threadIdx.x & 63;
  if (t >= NN) return;
  const float* x = nf + (size_t)t * DD;
  float acc = 0.f;
#pragma unroll
  for (int k = 0; k < DD; ++k) acc = fmaf(x[k], W[k * DD + d], acc);
  xh16[(size_t)t * DD + d] = (__bf16)acc;
  int h = d >> 4, c = d & 15;
  float ps = acc * as_[h * NC + c];
  float pd = acc * ad_[h * NC + c];
#pragma unroll
  for (int off = 8; off >= 1; off >>= 1) {
    ps += __shfl_xor(ps, off, 64);
    pd += __shfl_xor(pd, off, 64);
  }
  if (c == 0) { asrc[t * NH + h] = ps; adst[t * NH + h] = pd; }
}

// pass1 layer 0 only: reads edge_feats fp32, writes ef16 AND RAW pe
__global__ void k_pass1f(const float* __restrict__ edge_feats,
                         const float* __restrict__ v,
                         const int* __restrict__ posmap,
                         __bf16* __restrict__ ef16, float* __restrict__ araw) {
  int e = blockIdx.x * 64 + (threadIdx.x >> 2);
  int part = threadIdx.x & 3;
  if (e >= NE) return;
  float ph0 = 0.f, ph1 = 0.f, ph2 = 0.f, ph3 = 0.f;
  const float4* ep = (const float4*)(edge_feats + (size_t)e * DD + part * 16);
  const float4* v4 = (const float4*)v;
  bf4 outv[4];
#pragma unroll
  for (int c4 = 0; c4 < 4; ++c4) {
    float4 x = ep[c4];
    outv[c4][0] = (__bf16)x.x; outv[c4][1] = (__bf16)x.y;
    outv[c4][2] = (__bf16)x.z; outv[c4][3] = (__bf16)x.w;
    int d0 = part * 16 + c4 * 4;
    float4 va = v4[d0], vb = v4[d0 + 1], vc = v4[d0 + 2], vd = v4[d0 + 3];
    ph0 = fmaf(x.x, va.x, fmaf(x.y, vb.x, fmaf(x.z, vc.x, fmaf(x.w, vd.x, ph0))));
    ph1 = fmaf(x.x, va.y, fmaf(x.y, vb.y, fmaf(x.z, vc.y, fmaf(x.w, vd.y, ph1))));
    ph2 = fmaf(x.x, va.z, fmaf(x.y, vb.z, fmaf(x.z, vc.z, fmaf(x.w, vd.z, ph2))));
    ph3 = fmaf(x.x, va.w, fmaf(x.y, vb.w, fmaf(x.z, vc.w, fmaf(x.w, vd.w, ph3))));
  }
  *(bf8*)&ef16[(size_t)e * DD + part * 16] =
      (bf8){outv[0][0], outv[0][1], outv[0][2], outv[0][3],
            outv[1][0], outv[1][1], outv[1][2], outv[1][3]};
  *(bf8*)&ef16[(size_t)e * DD + part * 16 + 8] =
      (bf8){outv[2][0], outv[2][1], outv[2][2], outv[2][3],
            outv[3][0], outv[3][1], outv[3][2], outv[3][3]};
#pragma unroll
  for (int off = 1; off <= 2; off <<= 1) {
    ph0 += __shfl_xor(ph0, off, 64);
    ph1 += __shfl_xor(ph1, off, 64);
    ph2 += __shfl_xor(ph2, off, 64);
    ph3 += __shfl_xor(ph3, off, 64);
  }
  float pe = (part == 0) ? ph0 : (part == 1) ? ph1 : (part == 2) ? ph2 : ph3;
  araw[(size_t)posmap[e] * NH + part] = pe;  // RAW pe; gather applies leaky
}

// gather (leaky-inline, R10/R11-proven): araw holds RAW pe
__global__ __launch_bounds__(256) void k_gather2(
    const __bf16* __restrict__ xh16, const float* __restrict__ araw,
    const int* __restrict__ csr_src, const int* __restrict__ offs,
    const float* __restrict__ asrc, const float* __restrict__ adst,
    const float* __restrict__ cb, const float* __restrict__ g,
    const float* __restrict__ bln, float* __restrict__ nf,
    __bf16* __restrict__ nf16) {
  int t = blockIdx.x * 4 + (threadIdx.x >> 6);
  int d = threadIdx.x & 63;
  if (t >= NN) return;
  int h = d >> 4;
  int o0 = offs[t], o1 = offs[t + 1];
  int deg = o1 - o0;
  float4 ad4 = ((const float4*)adst)[t];

  float m0 = -INFINITY, m1 = -INFINITY, m2 = -INFINITY, m3 = -INFINITY;
  for (int base = 0; base < deg; base += 64) {
    int j = base + d;
    if (j < deg) {
      int pos = o0 + j;
      float4 pe = *(const float4*)(araw + (size_t)pos * NH);
      int sp = csr_src[pos];
      float4 as4 = ((const float4*)asrc)[sp];
      float a0 = as4.x + ad4.x + pe.x; a0 = ((a0 > 0.f) ? a0 : SLOPE * a0) * LOG2E;
      float a1 = as4.y + ad4.y + pe.y; a1 = ((a1 > 0.f) ? a1 : SLOPE * a1) * LOG2E;
      float a2 = as4.z + ad4.z + pe.z; a2 = ((a2 > 0.f) ? a2 : SLOPE * a2) * LOG2E;
      float a3 = as4.w + ad4.w + pe.w; a3 = ((a3 > 0.f) ? a3 : SLOPE * a3) * LOG2E;
      m0 = fmaxf(m0, a0); m1 = fmaxf(m1, a1);
      m2 = fmaxf(m2, a2); m3 = fmaxf(m3, a3);
    }
  }
#pragma unroll
  for (int off = 32; off >= 1; off >>= 1) {
    m0 = fmaxf(m0, __shfl_xor(m0, off, 64));
    m1 = fmaxf(m1, __shfl_xor(m1, off, 64));
    m2 = fmaxf(m2, __shfl_xor(m2, off, 64));
    m3 = fmaxf(m3, __shfl_xor(m3, off, 64));
  }
  float adh = (h == 0) ? ad4.x : (h == 1) ? ad4.y : (h == 2) ? ad4.z : ad4.w;
  float sh = asrc[t * NH + h] + adh;
  sh = ((sh > 0.f) ? sh : SLOPE * sh) * LOG2E;
  float mh = (h == 0) ? m0 : (h == 1) ? m1 : (h == 2) ? m2 : m3;
  mh = fmaxf(mh, sh);

  float acc = 0.f, wsum = 0.f;
  int j = 0;
  for (; j + 1 < deg; j += 2) {
    int pos0 = o0 + j, pos1 = o0 + j + 1;
    int sp0 = csr_src[pos0], sp1 = csr_src[pos1];
    float ar0 = asrc[sp0 * NH + h] + adh + araw[(size_t)pos0 * NH + h];
    float ar1 = asrc[sp1 * NH + h] + adh + araw[(size_t)pos1 * NH + h];
    ar0 = ((ar0 > 0.f) ? ar0 : SLOPE * ar0) * LOG2E;
    ar1 = ((ar1 > 0.f) ? ar1 : SLOPE * ar1) * LOG2E;
    float w0 = exp2f(ar0 - mh), w1 = exp2f(ar1 - mh);
    acc = fmaf(w0, (float)xh16[(size_t)sp0 * DD + d], acc);
    acc = fmaf(w1, (float)xh16[(size_t)sp1 * DD + d], acc);
    wsum += w0 + w1;
  }
  if (j < deg) {
    int pos = o0 + j;
    int sp = csr_src[pos];
    float ar = asrc[sp * NH + h] + adh + araw[(size_t)pos * NH + h];
    ar = ((ar > 0.f) ? ar : SLOPE * ar) * LOG2E;
    float w = exp2f(ar - mh);
    acc = fmaf(w, (float)xh16[(size_t)sp * DD + d], acc);
    wsum += w;
  }
  float wself = exp2f(sh - mh);
  acc = fmaf(wself, (float)xh16[(size_t)t * DD + d], acc);
  wsum += wself;

  float val = acc / (wsum + 1e-16f) + cb[d];
  float m = val;
#pragma unroll
  for (int off = 32; off >= 1; off >>= 1) m += __shfl_xor(m, off, 64);
  m *= (1.f / 64.f);
  float c = val - m;
  float q = c * c;
#pragma unroll
  for (int off = 32; off >= 1; off >>= 1) q += __shfl_xor(q, off, 64);
  float rstd = 1.f / sqrtf(q * (1.f / 64.f) + 1e-5f);
  float y = c * rstd * g[d] + bln[d];
  y = fmaxf(y, 0.f);
  float out = y + nf[(size_t)t * DD + d];
  nf[(size_t)t * DD + d] = out;
  nf16[(size_t)t * DD + d] = (__bf16)out;
}

// ---------------- edge MLP v12: mlp10 + fused next-layer pe in funnel --------
// (512,4): proven no-spill. When !last, output stage also computes
// pe = ef_new . v_next per row (fp32 funnel values) -> araw[posmap] (RAW).
__global__ __launch_bounds__(512, 4) void k_edge_mlp12(
    const __bf16* __restrict__ nf16, __bf16* __restrict__ ef16,
    float* __restrict__ efout,
    const int* __restrict__ src, const int* __restrict__ dst,
    const __bf16* __restrict__ W1H, const float* __restrict__ b1,
    const float* __restrict__ g, const float* __restrict__ bg,
    const __bf16* __restrict__ W2H, const float* __restrict__ b2,
    const float* __restrict__ vnext, const int* __restrict__ posmap,
    float* __restrict__ araw, int last) {
  __shared__ __bf16 XH[EB * XSTR];   // 51200 B: X | H | f32 output funnel
  __shared__ __bf16 Pb[EB * 8];      // 2048 B: LN partials; slot 0 -> (mean,rstd)
  int tid = threadIdx.x;
  int e0 = blockIdx.x * EB;
  float* XF = (float*)XH;            // funnel view (128*66*4 = 33792 B)

  // stage X: thread owns (row = tid>>2, part p = tid&3); all bf16 copies
  {
    int row = tid >> 2, p = tid & 3;
    int se = src[e0 + row], de = dst[e0 + row];
    const bf8* psrc = (const bf8*)(nf16 + (size_t)se * DD + p * 16);
    *(bf8*)&XH[row * XSTR + p * 16]     = psrc[0];
    *(bf8*)&XH[row * XSTR + p * 16 + 8] = psrc[1];
    const bf8* pdst = (const bf8*)(nf16 + (size_t)de * DD + p * 16);
    *(bf8*)&XH[row * XSTR + 64 + p * 16]     = pdst[0];
    *(bf8*)&XH[row * XSTR + 64 + p * 16 + 8] = pdst[1];
    const bf8* pef = (const bf8*)(ef16 + (size_t)(e0 + row) * DD + p * 16);
    *(bf8*)&XH[row * XSTR + 128 + p * 16]     = pef[0];
    *(bf8*)&XH[row * XSTR + 128 + p * 16 + 8] = pef[1];
  }
  __syncthreads();

  int w = tid >> 6, l = tid & 63;
  int rg = w >> 2, cg = w & 3;
  int gq = l >> 4, i = l & 15;
  int col = cg * 16 + i;

  f32x4 acc[4][3];
#pragma unroll
  for (int rt = 0; rt < 4; ++rt)
#pragma unroll
    for (int t = 0; t < 3; ++t) acc[rt][t] = (f32x4){0.f, 0.f, 0.f, 0.f};

  // GEMM1: no barriers; B-tiles from global (L2-hot)
#pragma unroll
  for (int s = 0; s < 6; ++s) {
    bf8 a[4];
#pragma unroll
    for (int rt = 0; rt < 4; ++rt)
      a[rt] = *(const bf8*)&XH[(rg * 64 + rt * 16 + i) * XSTR + s * 32 + gq * 8];
#pragma unroll
    for (int t = 0; t < 3; ++t) {
      bf8 bh = *(const bf8*)(W1H + ((size_t)((cg * 3 + t) * 6 + s) * 64 + l) * 8);
#pragma unroll
      for (int rt = 0; rt < 4; ++rt) acc[rt][t] = MFMA(a[rt], bh, acc[rt][t]);
    }
  }

  // residual snapshot from staged ef (stable until H overwrite after barrier 2)
  float res[4][4];
#pragma unroll
  for (int rt = 0; rt < 4; ++rt)
#pragma unroll
    for (int r = 0; r < 4; ++r)
      res[rt][r] = (float)XH[(rg * 64 + rt * 16 + gq * 4 + r) * XSTR + 128 + col];

  float b1v[3], gv[3], bgv[3];
#pragma unroll
  for (int t = 0; t < 3; ++t) {
    int n = cg * 48 + t * 16 + i;
    b1v[t] = b1[n]; gv[t] = g[n]; bgv[t] = bg[n];
  }
#pragma unroll
  for (int rt = 0; rt < 4; ++rt)
#pragma unroll
    for (int t = 0; t < 3; ++t)
#pragma unroll
      for (int r = 0; r < 4; ++r) acc[rt][t][r] += b1v[t];

#pragma unroll
  for (int rt = 0; rt < 4; ++rt)
#pragma unroll
    for (int r = 0; r < 4; ++r) {
      float sm = 0.f, sq = 0.f;
#pragma unroll
      for (int t = 0; t < 3; ++t) { float x = acc[rt][t][r]; sm += x; sq = fmaf(x, x, sq); }
#pragma unroll
      for (int off = 1; off <= 8; off <<= 1) {
        sm += __shfl_xor(sm, off, 64);
        sq += __shfl_xor(sq, off, 64);
      }
      if (i == 0) {
        int row = rg * 64 + rt * 16 + gq * 4 + r;
        bf2 pr; pr[0] = (__bf16)sm; pr[1] = (__bf16)sq;
        *(bf2*)&Pb[row * 8 + cg * 2] = pr;
      }
    }
  __syncthreads();   // barrier 1: partials ready; all X reads (incl. res) done

  if (tid < EB) {
    bf8 pv = *(const bf8*)&Pb[tid * 8];
    float sm = (float)pv[0] + (float)pv[2] + (float)pv[4] + (float)pv[6];
    float sq = (float)pv[1] + (float)pv[3] + (float)pv[5] + (float)pv[7];
    float mean = sm * (1.f / (float)DIN);
    float var = sq * (1.f / (float)DIN) - mean * mean;
    float rstd = 1.f / sqrtf(var + 1e-5f);
    bf2 mv; mv[0] = (__bf16)mean; mv[1] = (__bf16)rstd;
    *(bf2*)&Pb[tid * 8] = mv;
  }
  __syncthreads();   // barrier 2: (mean,rstd) ready

#pragma unroll
  for (int rt = 0; rt < 4; ++rt)
#pragma unroll
    for (int r = 0; r < 4; ++r) {
      int row = rg * 64 + rt * 16 + gq * 4 + r;
      bf2 mv = *(const bf2*)&Pb[row * 8];
      float mean = (float)mv[0], rstd = (float)mv[1];
#pragma unroll
      for (int t = 0; t < 3; ++t) {
        float y = (acc[rt][t][r] - mean) * rstd * gv[t] + bgv[t];
        y = fmaxf(y, 0.f);
        XH[row * XSTR + cg * 48 + t * 16 + i] = (__bf16)y;
      }
    }
  __syncthreads();   // barrier 3: H fully published

  // GEMM2
  f32x4 acc2[4];
#pragma unroll
  for (int rt = 0; rt < 4; ++rt) acc2[rt] = (f32x4){0.f, 0.f, 0.f, 0.f};

#pragma unroll
  for (int s = 0; s < 6; ++s) {
    bf8 a2[4];
#pragma unroll
    for (int rt = 0; rt < 4; ++rt)
      a2[rt] = *(const bf8*)&XH[(rg * 64 + rt * 16 + i) * XSTR + s * 32 + gq * 8];
    bf8 bh = *(const bf8*)(W2H + ((size_t)(cg * 6 + s) * 64 + l) * 8);
#pragma unroll
    for (int rt = 0; rt < 4; ++rt) acc2[rt] = MFMA(a2[rt], bh, acc2[rt]);
  }
  __syncthreads();   // barrier 4: all H reads done; XH free for funnel

  float b2v = b2[col];
#pragma unroll
  for (int rt = 0; rt < 4; ++rt)
#pragma unroll
    for (int r = 0; r < 4; ++r) {
      int row = rg * 64 + rt * 16 + gq * 4 + r;
      XF[row * FSTR + col] = acc2[rt][r] + b2v + res[rt][r];
    }
  __syncthreads();   // barrier 5: funnel filled

  // full-line coalesced output + fused next-layer pe
  {
    int row = tid >> 2, q = tid & 3;
    const float* fr = &XF[row * FSTR + q * 16];
    float f[16];
#pragma unroll
    for (int k = 0; k < 4; ++k)
      *(float4*)(f + k * 4) = *(const float4*)(fr + k * 4);
    if (last) {
      float* op = efout + (size_t)(e0 + row) * DD + q * 16;
#pragma unroll
      for (int k = 0; k < 4; ++k)
        *(float4*)(op + k * 4) = *(const float4*)(f + k * 4);
    } else {
      bf8 o0, o1;
#pragma unroll
      for (int k = 0; k < 8; ++k) { o0[k] = (__bf16)f[k]; o1[k] = (__bf16)f[k + 8]; }
      __bf16* op = ef16 + (size_t)(e0 + row) * DD + q * 16;
      *(bf8*)op = o0;
      *(bf8*)(op + 8) = o1;
      // pe partial over this thread's 16 cols
      float p0 = 0.f, p1 = 0.f, p2 = 0.f, p3 = 0.f;
      const float4* v4 = (const float4*)vnext;
#pragma unroll
      for (int m2 = 0; m2 < 16; ++m2) {
        float4 vn = v4[q * 16 + m2];
        p0 = fmaf(f[m2], vn.x, p0);
        p1 = fmaf(f[m2], vn.y, p1);
        p2 = fmaf(f[m2], vn.z, p2);
        p3 = fmaf(f[m2], vn.w, p3);
      }
      // reduce across the 4 q-lanes (adjacent lanes, same wave: 16 rows/wave)
#pragma unroll
      for (int off = 1; off <= 2; off <<= 1) {
        p0 += __shfl_xor(p0, off, 64);
        p1 += __shfl_xor(p1, off, 64);
        p2 += __shfl_xor(p2, off, 64);
        p3 += __shfl_xor(p3, off, 64);
      }
      if (q == 0) {
        int pos = posmap[e0 + row];
        float4 pe; pe.x = p0; pe.y = p1; pe.z = p2; pe.w = p3;
        *(float4*)(araw + (size_t)pos * NH) = pe;
      }
    }
  }
}

extern "C" void kernel_launch(void* const* d_in, const int* in_sizes, int n_in,
                              void* d_out, int out_size, void* d_ws, size_t ws_size,
                              hipStream_t stream) {
  const float* node_feats = (const float*)d_in[0];
  const float* edge_feats = (const float*)d_in[1];
  const int*   edge_index = (const int*)d_in[2];
  const float* conv_w  = (const float*)d_in[3];
  const float* att_src = (const float*)d_in[4];
  const float* att_dst = (const float*)d_in[5];
  const float* edge_w  = (const float*)d_in[6];
  const float* att_edge= (const float*)d_in[7];
  const float* conv_b  = (const float*)d_in[8];
  const float* ln_g    = (const float*)d_in[9];
  const float* ln_b    = (const float*)d_in[10];
  const float* up1_w   = (const float*)d_in[11];
  const float* up1_b   = (const float*)d_in[12];
  const float* up_ln_g = (const float*)d_in[13];
  const float* up_ln_b = (const float*)d_in[14];
  const float* up2_w   = (const float*)d_in[15];
  const float* up2_b   = (const float*)d_in[16];

  const int* src = edge_index;
  const int* dst = edge_index + NE;

  float* nf = (float*)d_out;
  float* efout = nf + (size_t)NN * DD;

  float* w = (float*)d_ws;
  __bf16* xh16 = (__bf16*)w; w += (size_t)NN * DD / 2;
  __bf16* nf16 = (__bf16*)w; w += (size_t)NN * DD / 2;
  __bf16* ef16 = (__bf16*)w; w += (size_t)NE * DD / 2;
  float* asrc  = w; w += (size_t)NN * NH;
  float* adst  = w; w += (size_t)NN * NH;
  float* araw  = w; w += (size_t)NE * NH;          // RAW pe (CSR order)
  float* vbuf  = w; w += 4 * 256;
  __bf16* W1H  = (__bf16*)w; w += (size_t)4 * 36864 / 2;
  __bf16* W2H  = (__bf16*)w; w += (size_t)4 * 12288 / 2;
  int* deg     = (int*)w; w += NN;
  int* offs    = (int*)w; w += NN + 1;
  int* cursor  = (int*)w; w += NN;
  int* bsum    = (int*)w; w += 128;
  int* boff    = (int*)w; w += 128;
  int* csr_src = (int*)w; w += NE;
  int* posmap  = (int*)w; w += NE;

  k_init_nf<<<(NN * DD + 255) / 256, 256, 0, stream>>>(node_feats, nf);
  k_pack_w1<<<72, 256, 0, stream>>>(up1_w, W1H);
  k_pack_w2<<<24, 256, 0, stream>>>(up2_w, W2H);

  const int nb = (NN + 1023) / 1024;
  k_zero<<<(NN + 255) / 256, 256, 0, stream>>>(deg);
  k_hist<<<(NE + 255) / 256, 256, 0, stream>>>(dst, deg);
  k_scan1<<<nb, 256, 0, stream>>>(deg, offs, bsum);
  k_scan2<<<1, 64, 0, stream>>>(bsum, boff, offs, nb);
  k_scan3<<<(NN + 255) / 256, 256, 0, stream>>>(offs, boff, cursor);
  k_scatter<<<(NE + 255) / 256, 256, 0, stream>>>(src, dst, cursor, csr_src, posmap);

  k_v_all<<<4, 256, 0, stream>>>(edge_w, att_edge, vbuf);
  // layer-0 pe + ef16 init in one pass over edge_feats
  k_pass1f<<<NE / 64, 256, 0, stream>>>(edge_feats, vbuf, posmap, ef16, araw);

  for (int l = 0; l < NL; ++l) {
    int last = (l == NL - 1) ? 1 : 0;
    k_xh<<<NN / 4, 256, 0, stream>>>(nf, conv_w + (size_t)l * DD * DD,
                                     att_src + (size_t)l * NH * NC,
                                     att_dst + (size_t)l * NH * NC, xh16, asrc, adst);
    k_gather2<<<NN / 4, 256, 0, stream>>>(xh16, araw, csr_src, offs, asrc, adst,
                                          conv_b + (size_t)l * DD,
                                          ln_g + (size_t)l * DD,
                                          ln_b + (size_t)l * DD, nf, nf16);
    k_edge_mlp12<<<NE / EB, 512, 0, stream>>>(
        nf16, ef16, efout, src, dst,
        W1H + (size_t)l * 36864, up1_b + (size_t)l * DIN,
        up_ln_g + (size_t)l * DIN, up_ln_b + (size_t)l * DIN,
        W2H + (size_t)l * 12288, up2_b + (size_t)l * DD,
        last ? vbuf : (vbuf + (size_t)(l + 1) * 256),
        posmap, araw, last);
  }
}

// Round 16
// 3466.233 us; speedup vs baseline: 1.3072x; 1.0075x over previous
//
#include <hip/hip_runtime.h>
#include <math.h>

#define NN 100000
#define NE 1600000
#define DD 64
#define NL 4
#define NH 4
#define NC 16
#define DIN 192
#define SLOPE 0.2f
#define EB 128
#define XSTR 200
#define FSTR 66
#define LOG2E 1.44269504088896340736f

typedef __bf16 bf8 __attribute__((ext_vector_type(8)));
typedef __bf16 bf4 __attribute__((ext_vector_type(4)));
typedef __bf16 bf2 __attribute__((ext_vector_type(2)));
typedef float f32x4 __attribute__((ext_vector_type(4)));

__device__ __forceinline__ f32x4 MFMA(bf8 a, bf8 b, f32x4 c) {
  return __builtin_amdgcn_mfma_f32_16x16x32_bf16(a, b, c, 0, 0, 0);
}

// ---------------- weight packing: single bf16 plane, 1KB tiles ----------------
__global__ void k_pack_w1(const float* __restrict__ W1, __bf16* __restrict__ WH) {
  int gidx = blockIdx.x * 256 + threadIdx.x;
  if (gidx >= 4 * 4608) return;
  int lyr = gidx / 4608, rem = gidx % 4608;
  int lane = rem & 63, ts = rem >> 6;
  int s = ts % 6, t = ts / 6;
  const float* Wl = W1 + (size_t)lyr * DIN * DIN;
  size_t base = (size_t)lyr * 36864 + ((size_t)(t * 6 + s) * 64 + lane) * 8;
  int k0 = s * 32 + (lane >> 4) * 8, n = t * 16 + (lane & 15);
#pragma unroll
  for (int j = 0; j < 8; ++j)
    WH[base + j] = (__bf16)Wl[(size_t)(k0 + j) * DIN + n];
}

__global__ void k_pack_w2(const float* __restrict__ W2, __bf16* __restrict__ WH) {
  int gidx = blockIdx.x * 256 + threadIdx.x;
  if (gidx >= 4 * 1536) return;
  int lyr = gidx / 1536, rem = gidx % 1536;
  int lane = rem & 63, ts = rem >> 6;
  int s = ts % 6, t = ts / 6;
  const float* Wl = W2 + (size_t)lyr * DIN * DD;
  size_t base = (size_t)lyr * 12288 + ((size_t)(t * 6 + s) * 64 + lane) * 8;
  int k0 = s * 32 + (lane >> 4) * 8, n = t * 16 + (lane & 15);
#pragma unroll
  for (int j = 0; j < 8; ++j)
    WH[base + j] = (__bf16)Wl[(size_t)(k0 + j) * DD + n];
}

// ---------------- CSR build ----------------
__global__ void k_zero(int* __restrict__ deg) {
  int i = blockIdx.x * 256 + threadIdx.x;
  if (i < NN) deg[i] = 0;
}

__global__ void k_hist(const int* __restrict__ dst, int* __restrict__ deg) {
  int e = blockIdx.x * 256 + threadIdx.x;
  if (e < NE) atomicAdd(&deg[dst[e]], 1);
}

__global__ void k_scan1(const int* __restrict__ deg, int* __restrict__ offs,
                        int* __restrict__ bsum) {
  __shared__ int sh[256];
  int t = threadIdx.x, b = blockIdx.x;
  int i0 = b * 1024 + t * 4;
  int d0 = (i0 + 0 < NN) ? deg[i0 + 0] : 0;
  int d1 = (i0 + 1 < NN) ? deg[i0 + 1] : 0;
  int d2 = (i0 + 2 < NN) ? deg[i0 + 2] : 0;
  int d3 = (i0 + 3 < NN) ? deg[i0 + 3] : 0;
  int s4 = d0 + d1 + d2 + d3;
  sh[t] = s4;
  __syncthreads();
  int p = 0;
#pragma unroll
  for (int off = 1; off < 256; off <<= 1) {
    int v = (t >= off) ? sh[t - off] : 0;
    __syncthreads();
    sh[t] += v;
    __syncthreads();
  }
  p = sh[t] - s4;
  if (t == 255) bsum[b] = sh[255];
  if (i0 + 0 < NN) offs[i0 + 0] = p;
  if (i0 + 1 < NN) offs[i0 + 1] = p + d0;
  if (i0 + 2 < NN) offs[i0 + 2] = p + d0 + d1;
  if (i0 + 3 < NN) offs[i0 + 3] = p + d0 + d1 + d2;
}

__global__ void k_scan2(int* __restrict__ bsum, int* __restrict__ boff,
                        int* __restrict__ offs, int nb) {
  if (threadIdx.x == 0 && blockIdx.x == 0) {
    int run = 0;
    for (int k = 0; k < nb; ++k) { boff[k] = run; run += bsum[k]; }
    offs[NN] = NE;
  }
}

__global__ void k_scan3(int* __restrict__ offs, const int* __restrict__ boff,
                        int* __restrict__ cursor) {
  int i = blockIdx.x * 256 + threadIdx.x;
  if (i < NN) {
    int v = offs[i] + boff[i >> 10];
    offs[i] = v;
    cursor[i] = v;
  }
}

// csr_src[pos] = src[e]; csr_eid[pos] = e  (araw stays in EDGE order)
__global__ void k_scatter(const int* __restrict__ src, const int* __restrict__ dst,
                          int* __restrict__ cursor, int* __restrict__ csr_src,
                          int* __restrict__ csr_eid) {
  int e = blockIdx.x * 256 + threadIdx.x;
  if (e >= NE) return;
  int pos = atomicAdd(&cursor[dst[e]], 1);
  csr_src[pos] = src[e];
  csr_eid[pos] = e;
}

// ---------------- upfront precomputes ----------------
__global__ void k_v_all(const float* __restrict__ ew_all, const float* __restrict__ ae_all,
                        float* __restrict__ vbuf) {
  int l = blockIdx.x;
  const float* ew = ew_all + (size_t)l * DD * DD;
  const float* ae = ae_all + (size_t)l * NH * NC;
  int d = threadIdx.x >> 2, h = threadIdx.x & 3;
  float s = 0.f;
#pragma unroll
  for (int c = 0; c < NC; ++c) s = fmaf(ew[d * DD + h * NC + c], ae[h * NC + c], s);
  vbuf[l * 256 + d * NH + h] = s;
}

__global__ void k_init_nf(const float* __restrict__ node_feats, float* __restrict__ nf) {
  int i = blockIdx.x * 256 + threadIdx.x;
  if (i < NN * DD) nf[i] = node_feats[i];
}

// ---------------- conv path ----------------
__global__ void k_xh(const float* __restrict__ nf, const float* __restrict__ W,
                     const float* __restrict__ as_, const float* __restrict__ ad_,
                     __bf16* __restrict__ xh16, float* __restrict__ asrc,
                     float* __restrict__ adst) {
  int t = blockIdx.x * 4 + (threadIdx.x >> 6);
  int d = threadIdx.x & 63;
  if (t >= NN) return;
  const float* x = nf + (size_t)t * DD;
  float acc = 0.f;
#pragma unroll
  for (int k = 0; k < DD; ++k) acc = fmaf(x[k], W[k * DD + d], acc);
  xh16[(size_t)t * DD + d] = (__bf16)acc;
  int h = d >> 4, c = d & 15;
  float ps = acc * as_[h * NC + c];
  float pd = acc * ad_[h * NC + c];
#pragma unroll
  for (int off = 8; off >= 1; off >>= 1) {
    ps += __shfl_xor(ps, off, 64);
    pd += __shfl_xor(pd, off, 64);
  }
  if (c == 0) { asrc[t * NH + h] = ps; adst[t * NH + h] = pd; }
}

// layer-0: edge_feats -> ef16 + RAW pe into araw[e] (both coalesced)
__global__ void k_pass1f(const float* __restrict__ edge_feats,
                         const float* __restrict__ v,
                         __bf16* __restrict__ ef16, float* __restrict__ araw) {
  int e = blockIdx.x * 64 + (threadIdx.x >> 2);
  int part = threadIdx.x & 3;
  if (e >= NE) return;
  float ph0 = 0.f, ph1 = 0.f, ph2 = 0.f, ph3 = 0.f;
  const float4* ep = (const float4*)(edge_feats + (size_t)e * DD + part * 16);
  const float4* v4 = (const float4*)v;
  bf4 outv[4];
#pragma unroll
  for (int c4 = 0; c4 < 4; ++c4) {
    float4 x = ep[c4];
    outv[c4][0] = (__bf16)x.x; outv[c4][1] = (__bf16)x.y;
    outv[c4][2] = (__bf16)x.z; outv[c4][3] = (__bf16)x.w;
    int d0 = part * 16 + c4 * 4;
    float4 va = v4[d0], vb = v4[d0 + 1], vc = v4[d0 + 2], vd = v4[d0 + 3];
    ph0 = fmaf(x.x, va.x, fmaf(x.y, vb.x, fmaf(x.z, vc.x, fmaf(x.w, vd.x, ph0))));
    ph1 = fmaf(x.x, va.y, fmaf(x.y, vb.y, fmaf(x.z, vc.y, fmaf(x.w, vd.y, ph1))));
    ph2 = fmaf(x.x, va.z, fmaf(x.y, vb.z, fmaf(x.z, vc.z, fmaf(x.w, vd.z, ph2))));
    ph3 = fmaf(x.x, va.w, fmaf(x.y, vb.w, fmaf(x.z, vc.w, fmaf(x.w, vd.w, ph3))));
  }
  *(bf8*)&ef16[(size_t)e * DD + part * 16] =
      (bf8){outv[0][0], outv[0][1], outv[0][2], outv[0][3],
            outv[1][0], outv[1][1], outv[1][2], outv[1][3]};
  *(bf8*)&ef16[(size_t)e * DD + part * 16 + 8] =
      (bf8){outv[2][0], outv[2][1], outv[2][2], outv[2][3],
            outv[3][0], outv[3][1], outv[3][2], outv[3][3]};
#pragma unroll
  for (int off = 1; off <= 2; off <<= 1) {
    ph0 += __shfl_xor(ph0, off, 64);
    ph1 += __shfl_xor(ph1, off, 64);
    ph2 += __shfl_xor(ph2, off, 64);
    ph3 += __shfl_xor(ph3, off, 64);
  }
  float pe = (part == 0) ? ph0 : (part == 1) ? ph1 : (part == 2) ? ph2 : ph3;
  araw[(size_t)e * NH + part] = pe;   // EDGE order, coalesced
}

// gather: araw holds RAW pe in EDGE order; leaky+LOG2E applied inline
__global__ __launch_bounds__(256) void k_gather2(
    const __bf16* __restrict__ xh16, const float* __restrict__ araw,
    const int* __restrict__ csr_src, const int* __restrict__ csr_eid,
    const int* __restrict__ offs,
    const float* __restrict__ asrc, const float* __restrict__ adst,
    const float* __restrict__ cb, const float* __restrict__ g,
    const float* __restrict__ bln, float* __restrict__ nf,
    __bf16* __restrict__ nf16) {
  int t = blockIdx.x * 4 + (threadIdx.x >> 6);
  int d = threadIdx.x & 63;
  if (t >= NN) return;
  int h = d >> 4;
  int o0 = offs[t], o1 = offs[t + 1];
  int deg = o1 - o0;
  float4 ad4 = ((const float4*)adst)[t];

  float m0 = -INFINITY, m1 = -INFINITY, m2 = -INFINITY, m3 = -INFINITY;
  for (int base = 0; base < deg; base += 64) {
    int j = base + d;
    if (j < deg) {
      int pos = o0 + j;
      int eid = csr_eid[pos];
      float4 pe = *(const float4*)(araw + (size_t)eid * NH);
      int sp = csr_src[pos];
      float4 as4 = ((const float4*)asrc)[sp];
      float a0 = as4.x + ad4.x + pe.x; a0 = ((a0 > 0.f) ? a0 : SLOPE * a0) * LOG2E;
      float a1 = as4.y + ad4.y + pe.y; a1 = ((a1 > 0.f) ? a1 : SLOPE * a1) * LOG2E;
      float a2 = as4.z + ad4.z + pe.z; a2 = ((a2 > 0.f) ? a2 : SLOPE * a2) * LOG2E;
      float a3 = as4.w + ad4.w + pe.w; a3 = ((a3 > 0.f) ? a3 : SLOPE * a3) * LOG2E;
      m0 = fmaxf(m0, a0); m1 = fmaxf(m1, a1);
      m2 = fmaxf(m2, a2); m3 = fmaxf(m3, a3);
    }
  }
#pragma unroll
  for (int off = 32; off >= 1; off >>= 1) {
    m0 = fmaxf(m0, __shfl_xor(m0, off, 64));
    m1 = fmaxf(m1, __shfl_xor(m1, off, 64));
    m2 = fmaxf(m2, __shfl_xor(m2, off, 64));
    m3 = fmaxf(m3, __shfl_xor(m3, off, 64));
  }
  float adh = (h == 0) ? ad4.x : (h == 1) ? ad4.y : (h == 2) ? ad4.z : ad4.w;
  float sh = asrc[t * NH + h] + adh;
  sh = ((sh > 0.f) ? sh : SLOPE * sh) * LOG2E;
  float mh = (h == 0) ? m0 : (h == 1) ? m1 : (h == 2) ? m2 : m3;
  mh = fmaxf(mh, sh);

  float acc = 0.f, wsum = 0.f;
  int j = 0;
  for (; j + 1 < deg; j += 2) {
    int pos0 = o0 + j, pos1 = o0 + j + 1;
    int sp0 = csr_src[pos0], sp1 = csr_src[pos1];
    int e0i = csr_eid[pos0], e1i = csr_eid[pos1];
    float ar0 = asrc[sp0 * NH + h] + adh + araw[(size_t)e0i * NH + h];
    float ar1 = asrc[sp1 * NH + h] + adh + araw[(size_t)e1i * NH + h];
    ar0 = ((ar0 > 0.f) ? ar0 : SLOPE * ar0) * LOG2E;
    ar1 = ((ar1 > 0.f) ? ar1 : SLOPE * ar1) * LOG2E;
    float w0 = exp2f(ar0 - mh), w1 = exp2f(ar1 - mh);
    acc = fmaf(w0, (float)xh16[(size_t)sp0 * DD + d], acc);
    acc = fmaf(w1, (float)xh16[(size_t)sp1 * DD + d], acc);
    wsum += w0 + w1;
  }
  if (j < deg) {
    int pos = o0 + j;
    int sp = csr_src[pos];
    int ei = csr_eid[pos];
    float ar = asrc[sp * NH + h] + adh + araw[(size_t)ei * NH + h];
    ar = ((ar > 0.f) ? ar : SLOPE * ar) * LOG2E;
    float w = exp2f(ar - mh);
    acc = fmaf(w, (float)xh16[(size_t)sp * DD + d], acc);
    wsum += w;
  }
  float wself = exp2f(sh - mh);
  acc = fmaf(wself, (float)xh16[(size_t)t * DD + d], acc);
  wsum += wself;

  float val = acc / (wsum + 1e-16f) + cb[d];
  float m = val;
#pragma unroll
  for (int off = 32; off >= 1; off >>= 1) m += __shfl_xor(m, off, 64);
  m *= (1.f / 64.f);
  float c = val - m;
  float q = c * c;
#pragma unroll
  for (int off = 32; off >= 1; off >>= 1) q += __shfl_xor(q, off, 64);
  float rstd = 1.f / sqrtf(q * (1.f / 64.f) + 1e-5f);
  float y = c * rstd * g[d] + bln[d];
  y = fmaxf(y, 0.f);
  float out = y + nf[(size_t)t * DD + d];
  nf[(size_t)t * DD + d] = out;
  nf16[(size_t)t * DD + d] = (__bf16)out;
}

// ---------------- edge MLP v13: mlp10 + fused pe into EDGE-ordered araw ------
// (512,4) proven no-spill. !last: output funnel also computes
// pe = ef_new . v_next per row -> araw[e] (coalesced full-line writes).
__global__ __launch_bounds__(512, 4) void k_edge_mlp13(
    const __bf16* __restrict__ nf16, __bf16* __restrict__ ef16,
    float* __restrict__ efout,
    const int* __restrict__ src, const int* __restrict__ dst,
    const __bf16* __restrict__ W1H, const float* __restrict__ b1,
    const float* __restrict__ g, const float* __restrict__ bg,
    const __bf16* __restrict__ W2H, const float* __restrict__ b2,
    const float* __restrict__ vnext, float* __restrict__ araw, int last) {
  __shared__ __bf16 XH[EB * XSTR];   // 51200 B: X | H | f32 output funnel
  __shared__ __bf16 Pb[EB * 8];      // 2048 B: LN partials; slot 0 -> (mean,rstd)
  int tid = threadIdx.x;
  int e0 = blockIdx.x * EB;
  float* XF = (float*)XH;            // funnel view (128*66*4 = 33792 B)

  // stage X: thread owns (row = tid>>2, part p = tid&3); all bf16 copies
  {
    int row = tid >> 2, p = tid & 3;
    int se = src[e0 + row], de = dst[e0 + row];
    const bf8* psrc = (const bf8*)(nf16 + (size_t)se * DD + p * 16);
    *(bf8*)&XH[row * XSTR + p * 16]     = psrc[0];
    *(bf8*)&XH[row * XSTR + p * 16 + 8] = psrc[1];
    const bf8* pdst = (const bf8*)(nf16 + (size_t)de * DD + p * 16);
    *(bf8*)&XH[row * XSTR + 64 + p * 16]     = pdst[0];
    *(bf8*)&XH[row * XSTR + 64 + p * 16 + 8] = pdst[1];
    const bf8* pef = (const bf8*)(ef16 + (size_t)(e0 + row) * DD + p * 16);
    *(bf8*)&XH[row * XSTR + 128 + p * 16]     = pef[0];
    *(bf8*)&XH[row * XSTR + 128 + p * 16 + 8] = pef[1];
  }
  __syncthreads();

  int w = tid >> 6, l = tid & 63;
  int rg = w >> 2, cg = w & 3;
  int gq = l >> 4, i = l & 15;
  int col = cg * 16 + i;

  f32x4 acc[4][3];
#pragma unroll
  for (int rt = 0; rt < 4; ++rt)
#pragma unroll
    for (int t = 0; t < 3; ++t) acc[rt][t] = (f32x4){0.f, 0.f, 0.f, 0.f};

  // GEMM1: no barriers; B-tiles from global (L2-hot)
#pragma unroll
  for (int s = 0; s < 6; ++s) {
    bf8 a[4];
#pragma unroll
    for (int rt = 0; rt < 4; ++rt)
      a[rt] = *(const bf8*)&XH[(rg * 64 + rt * 16 + i) * XSTR + s * 32 + gq * 8];
#pragma unroll
    for (int t = 0; t < 3; ++t) {
      bf8 bh = *(const bf8*)(W1H + ((size_t)((cg * 3 + t) * 6 + s) * 64 + l) * 8);
#pragma unroll
      for (int rt = 0; rt < 4; ++rt) acc[rt][t] = MFMA(a[rt], bh, acc[rt][t]);
    }
  }

  // residual snapshot from staged ef (stable until H overwrite after barrier 2)
  float res[4][4];
#pragma unroll
  for (int rt = 0; rt < 4; ++rt)
#pragma unroll
    for (int r = 0; r < 4; ++r)
      res[rt][r] = (float)XH[(rg * 64 + rt * 16 + gq * 4 + r) * XSTR + 128 + col];

  float b1v[3], gv[3], bgv[3];
#pragma unroll
  for (int t = 0; t < 3; ++t) {
    int n = cg * 48 + t * 16 + i;
    b1v[t] = b1[n]; gv[t] = g[n]; bgv[t] = bg[n];
  }
#pragma unroll
  for (int rt = 0; rt < 4; ++rt)
#pragma unroll
    for (int t = 0; t < 3; ++t)
#pragma unroll
      for (int r = 0; r < 4; ++r) acc[rt][t][r] += b1v[t];

#pragma unroll
  for (int rt = 0; rt < 4; ++rt)
#pragma unroll
    for (int r = 0; r < 4; ++r) {
      float sm = 0.f, sq = 0.f;
#pragma unroll
      for (int t = 0; t < 3; ++t) { float x = acc[rt][t][r]; sm += x; sq = fmaf(x, x, sq); }
#pragma unroll
      for (int off = 1; off <= 8; off <<= 1) {
        sm += __shfl_xor(sm, off, 64);
        sq += __shfl_xor(sq, off, 64);
      }
      if (i == 0) {
        int row = rg * 64 + rt * 16 + gq * 4 + r;
        bf2 pr; pr[0] = (__bf16)sm; pr[1] = (__bf16)sq;
        *(bf2*)&Pb[row * 8 + cg * 2] = pr;
      }
    }
  __syncthreads();   // barrier 1: partials ready; all X reads (incl. res) done

  if (tid < EB) {
    bf8 pv = *(const bf8*)&Pb[tid * 8];
    float sm = (float)pv[0] + (float)pv[2] + (float)pv[4] + (float)pv[6];
    float sq = (float)pv[1] + (float)pv[3] + (float)pv[5] + (float)pv[7];
    float mean = sm * (1.f / (float)DIN);
    float var = sq * (1.f / (float)DIN) - mean * mean;
    float rstd = 1.f / sqrtf(var + 1e-5f);
    bf2 mv; mv[0] = (__bf16)mean; mv[1] = (__bf16)rstd;
    *(bf2*)&Pb[tid * 8] = mv;
  }
  __syncthreads();   // barrier 2: (mean,rstd) ready

#pragma unroll
  for (int rt = 0; rt < 4; ++rt)
#pragma unroll
    for (int r = 0; r < 4; ++r) {
      int row = rg * 64 + rt * 16 + gq * 4 + r;
      bf2 mv = *(const bf2*)&Pb[row * 8];
      float mean = (float)mv[0], rstd = (float)mv[1];
#pragma unroll
      for (int t = 0; t < 3; ++t) {
        float y = (acc[rt][t][r] - mean) * rstd * gv[t] + bgv[t];
        y = fmaxf(y, 0.f);
        XH[row * XSTR + cg * 48 + t * 16 + i] = (__bf16)y;
      }
    }
  __syncthreads();   // barrier 3: H fully published

  // GEMM2
  f32x4 acc2[4];
#pragma unroll
  for (int rt = 0; rt < 4; ++rt) acc2[rt] = (f32x4){0.f, 0.f, 0.f, 0.f};

#pragma unroll
  for (int s = 0; s < 6; ++s) {
    bf8 a2[4];
#pragma unroll
    for (int rt = 0; rt < 4; ++rt)
      a2[rt] = *(const bf8*)&XH[(rg * 64 + rt * 16 + i) * XSTR + s * 32 + gq * 8];
    bf8 bh = *(const bf8*)(W2H + ((size_t)(cg * 6 + s) * 64 + l) * 8);
#pragma unroll
    for (int rt = 0; rt < 4; ++rt) acc2[rt] = MFMA(a2[rt], bh, acc2[rt]);
  }
  __syncthreads();   // barrier 4: all H reads done; XH free for funnel

  float b2v = b2[col];
#pragma unroll
  for (int rt = 0; rt < 4; ++rt)
#pragma unroll
    for (int r = 0; r < 4; ++r) {
      int row = rg * 64 + rt * 16 + gq * 4 + r;
      XF[row * FSTR + col] = acc2[rt][r] + b2v + res[rt][r];
    }
  __syncthreads();   // barrier 5: funnel filled

  // full-line coalesced output + fused next-layer pe (EDGE-ordered araw)
  {
    int row = tid >> 2, q = tid & 3;
    const float* fr = &XF[row * FSTR + q * 16];
    float f[16];
#pragma unroll
    for (int k = 0; k < 4; ++k)
      *(float4*)(f + k * 4) = *(const float4*)(fr + k * 4);
    if (last) {
      float* op = efout + (size_t)(e0 + row) * DD + q * 16;
#pragma unroll
      for (int k = 0; k < 4; ++k)
        *(float4*)(op + k * 4) = *(const float4*)(f + k * 4);
    } else {
      bf8 o0, o1;
#pragma unroll
      for (int k = 0; k < 8; ++k) { o0[k] = (__bf16)f[k]; o1[k] = (__bf16)f[k + 8]; }
      __bf16* op = ef16 + (size_t)(e0 + row) * DD + q * 16;
      *(bf8*)op = o0;
      *(bf8*)(op + 8) = o1;
      // pe partial over this thread's 16 cols
      float p0 = 0.f, p1 = 0.f, p2 = 0.f, p3 = 0.f;
      const float4* v4 = (const float4*)vnext;
#pragma unroll
      for (int m2 = 0; m2 < 16; ++m2) {
        float4 vn = v4[q * 16 + m2];
        p0 = fmaf(f[m2], vn.x, p0);
        p1 = fmaf(f[m2], vn.y, p1);
        p2 = fmaf(f[m2], vn.z, p2);
        p3 = fmaf(f[m2], vn.w, p3);
      }
#pragma unroll
      for (int off = 1; off <= 2; off <<= 1) {
        p0 += __shfl_xor(p0, off, 64);
        p1 += __shfl_xor(p1, off, 64);
        p2 += __shfl_xor(p2, off, 64);
        p3 += __shfl_xor(p3, off, 64);
      }
      if (q == 0) {
        float4 pe; pe.x = p0; pe.y = p1; pe.z = p2; pe.w = p3;
        *(float4*)(araw + (size_t)(e0 + row) * NH) = pe;   // coalesced
      }
    }
  }
}

extern "C" void kernel_launch(void* const* d_in, const int* in_sizes, int n_in,
                              void* d_out, int out_size, void* d_ws, size_t ws_size,
                              hipStream_t stream) {
  const float* node_feats = (const float*)d_in[0];
  const float* edge_feats = (const float*)d_in[1];
  const int*   edge_index = (const int*)d_in[2];
  const float* conv_w  = (const float*)d_in[3];
  const float* att_src = (const float*)d_in[4];
  const float* att_dst = (const float*)d_in[5];
  const float* edge_w  = (const float*)d_in[6];
  const float* att_edge= (const float*)d_in[7];
  const float* conv_b  = (const float*)d_in[8];
  const float* ln_g    = (const float*)d_in[9];
  const float* ln_b    = (const float*)d_in[10];
  const float* up1_w   = (const float*)d_in[11];
  const float* up1_b   = (const float*)d_in[12];
  const float* up_ln_g = (const float*)d_in[13];
  const float* up_ln_b = (const float*)d_in[14];
  const float* up2_w   = (const float*)d_in[15];
  const float* up2_b   = (const float*)d_in[16];

  const int* src = edge_index;
  const int* dst = edge_index + NE;

  float* nf = (float*)d_out;
  float* efout = nf + (size_t)NN * DD;

  float* w = (float*)d_ws;
  __bf16* xh16 = (__bf16*)w; w += (size_t)NN * DD / 2;
  __bf16* nf16 = (__bf16*)w; w += (size_t)NN * DD / 2;
  __bf16* ef16 = (__bf16*)w; w += (size_t)NE * DD / 2;
  float* asrc  = w; w += (size_t)NN * NH;
  float* adst  = w; w += (size_t)NN * NH;
  float* araw  = w; w += (size_t)NE * NH;          // RAW pe, EDGE order
  float* vbuf  = w; w += 4 * 256;
  __bf16* W1H  = (__bf16*)w; w += (size_t)4 * 36864 / 2;
  __bf16* W2H  = (__bf16*)w; w += (size_t)4 * 12288 / 2;
  int* deg     = (int*)w; w += NN;
  int* offs    = (int*)w; w += NN + 1;
  int* cursor  = (int*)w; w += NN;
  int* bsum    = (int*)w; w += 128;
  int* boff    = (int*)w; w += 128;
  int* csr_src = (int*)w; w += NE;
  int* csr_eid = (int*)w; w += NE;

  k_init_nf<<<(NN * DD + 255) / 256, 256, 0, stream>>>(node_feats, nf);
  k_pack_w1<<<72, 256, 0, stream>>>(up1_w, W1H);
  k_pack_w2<<<24, 256, 0, stream>>>(up2_w, W2H);

  const int nb = (NN + 1023) / 1024;
  k_zero<<<(NN + 255) / 256, 256, 0, stream>>>(deg);
  k_hist<<<(NE + 255) / 256, 256, 0, stream>>>(dst, deg);
  k_scan1<<<nb, 256, 0, stream>>>(deg, offs, bsum);
  k_scan2<<<1, 64, 0, stream>>>(bsum, boff, offs, nb);
  k_scan3<<<(NN + 255) / 256, 256, 0, stream>>>(offs, boff, cursor);
  k_scatter<<<(NE + 255) / 256, 256, 0, stream>>>(src, dst, cursor, csr_src, csr_eid);

  k_v_all<<<4, 256, 0, stream>>>(edge_w, att_edge, vbuf);
  k_pass1f<<<NE / 64, 256, 0, stream>>>(edge_feats, vbuf, ef16, araw);

  for (int l = 0; l < NL; ++l) {
    int last = (l == NL - 1) ? 1 : 0;
    k_xh<<<NN / 4, 256, 0, stream>>>(nf, conv_w + (size_t)l * DD * DD,
                                     att_src + (size_t)l * NH * NC,
                                     att_dst + (size_t)l * NH * NC, xh16, asrc, adst);
    k_gather2<<<NN / 4, 256, 0, stream>>>(xh16, araw, csr_src, csr_eid, offs,
                                          asrc, adst,
                                          conv_b + (size_t)l * DD,
                                          ln_g + (size_t)l * DD,
                                          ln_b + (size_t)l * DD, nf, nf16);
    k_edge_mlp13<<<NE / EB, 512, 0, stream>>>(
        nf16, ef16, efout, src, dst,
        W1H + (size_t)l * 36864, up1_b + (size_t)l * DIN,
        up_ln_g + (size_t)l * DIN, up_ln_b + (size_t)l * DIN,
        W2H + (size_t)l * 12288, up2_b + (size_t)l * DD,
        last ? vbuf : (vbuf + (size_t)(l + 1) * 256),
        araw, last);
  }
}

// Round 17
// 2906.474 us; speedup vs baseline: 1.5589x; 1.1926x over previous
//
#include <hip/hip_runtime.h>
#include <math.h>

#define NN 100000
#define NE 1600000
#define DD 64
#define NL 4
#define NH 4
#define NC 16
#define DIN 192
#define SLOPE 0.2f
#define EB 128
#define XSTR 200
#define FSTR 66
#define RSTR 68
#define LOG2E 1.44269504088896340736f

typedef __bf16 bf8 __attribute__((ext_vector_type(8)));
typedef __bf16 bf4 __attribute__((ext_vector_type(4)));
typedef __bf16 bf2 __attribute__((ext_vector_type(2)));
typedef float f32x4 __attribute__((ext_vector_type(4)));

__device__ __forceinline__ f32x4 MFMA(bf8 a, bf8 b, f32x4 c) {
  return __builtin_amdgcn_mfma_f32_16x16x32_bf16(a, b, c, 0, 0, 0);
}

// ---------------- weight packing: single bf16 plane, 1KB tiles ----------------
__global__ void k_pack_w1(const float* __restrict__ W1, __bf16* __restrict__ WH) {
  int gidx = blockIdx.x * 256 + threadIdx.x;
  if (gidx >= 4 * 4608) return;
  int lyr = gidx / 4608, rem = gidx % 4608;
  int lane = rem & 63, ts = rem >> 6;
  int s = ts % 6, t = ts / 6;
  const float* Wl = W1 + (size_t)lyr * DIN * DIN;
  size_t base = (size_t)lyr * 36864 + ((size_t)(t * 6 + s) * 64 + lane) * 8;
  int k0 = s * 32 + (lane >> 4) * 8, n = t * 16 + (lane & 15);
#pragma unroll
  for (int j = 0; j < 8; ++j)
    WH[base + j] = (__bf16)Wl[(size_t)(k0 + j) * DIN + n];
}

__global__ void k_pack_w2(const float* __restrict__ W2, __bf16* __restrict__ WH) {
  int gidx = blockIdx.x * 256 + threadIdx.x;
  if (gidx >= 4 * 1536) return;
  int lyr = gidx / 1536, rem = gidx % 1536;
  int lane = rem & 63, ts = rem >> 6;
  int s = ts % 6, t = ts / 6;
  const float* Wl = W2 + (size_t)lyr * DIN * DD;
  size_t base = (size_t)lyr * 12288 + ((size_t)(t * 6 + s) * 64 + lane) * 8;
  int k0 = s * 32 + (lane >> 4) * 8, n = t * 16 + (lane & 15);
#pragma unroll
  for (int j = 0; j < 8; ++j)
    WH[base + j] = (__bf16)Wl[(size_t)(k0 + j) * DD + n];
}

// W2VP[l] = W2_l @ v_{l+1} packed as 6 B-tiles; VP[l] = v_{l+1} packed as 2 B-tiles;
// bvdot[l][h] = b2_l . v_{l+1}[:,h]   (l = 0..2)
__global__ void k_w2v(const float* __restrict__ up2_w, const float* __restrict__ up2_b,
                      const float* __restrict__ vbuf, __bf16* __restrict__ W2VP,
                      __bf16* __restrict__ VP, float* __restrict__ bvdot) {
  int l = blockIdx.x;                         // 0..2
  const float* vn = vbuf + (l + 1) * 256;     // [64][4]
  int t = threadIdx.x;
  if (t < 384) {
    int s = t >> 6, lane = t & 63;
    int i = lane & 15, k0 = s * 32 + (lane >> 4) * 8;
    const float* W2 = up2_w + (size_t)l * DIN * DD;
    __bf16* out = W2VP + (size_t)l * 3072 + ((size_t)(s * 64 + lane)) * 8;
#pragma unroll
    for (int j = 0; j < 8; ++j) {
      float val = 0.f;
      if (i < 4)
        for (int n = 0; n < DD; ++n)
          val = fmaf(W2[(size_t)(k0 + j) * DD + n], vn[n * NH + i], val);
      out[j] = (__bf16)val;
    }
  }
  if (t < 128) {
    int s2 = t >> 6, lane = t & 63;
    int i = lane & 15, k0 = s2 * 32 + (lane >> 4) * 8;
    __bf16* out = VP + (size_t)l * 1024 + ((size_t)(s2 * 64 + lane)) * 8;
#pragma unroll
    for (int j = 0; j < 8; ++j)
      out[j] = (i < 4) ? (__bf16)vn[(k0 + j) * NH + i] : (__bf16)0.f;
  }
  if (t < 4) {
    const float* b2 = up2_b + (size_t)l * DD;
    float bv = 0.f;
    for (int n = 0; n < DD; ++n) bv = fmaf(b2[n], vn[n * NH + t], bv);
    bvdot[l * 4 + t] = bv;
  }
}

// ---------------- CSR build ----------------
__global__ void k_zero(int* __restrict__ deg) {
  int i = blockIdx.x * 256 + threadIdx.x;
  if (i < NN) deg[i] = 0;
}

__global__ void k_hist(const int* __restrict__ dst, int* __restrict__ deg) {
  int e = blockIdx.x * 256 + threadIdx.x;
  if (e < NE) atomicAdd(&deg[dst[e]], 1);
}

__global__ void k_scan1(const int* __restrict__ deg, int* __restrict__ offs,
                        int* __restrict__ bsum) {
  __shared__ int sh[256];
  int t = threadIdx.x, b = blockIdx.x;
  int i0 = b * 1024 + t * 4;
  int d0 = (i0 + 0 < NN) ? deg[i0 + 0] : 0;
  int d1 = (i0 + 1 < NN) ? deg[i0 + 1] : 0;
  int d2 = (i0 + 2 < NN) ? deg[i0 + 2] : 0;
  int d3 = (i0 + 3 < NN) ? deg[i0 + 3] : 0;
  int s4 = d0 + d1 + d2 + d3;
  sh[t] = s4;
  __syncthreads();
  int p = 0;
#pragma unroll
  for (int off = 1; off < 256; off <<= 1) {
    int v = (t >= off) ? sh[t - off] : 0;
    __syncthreads();
    sh[t] += v;
    __syncthreads();
  }
  p = sh[t] - s4;
  if (t == 255) bsum[b] = sh[255];
  if (i0 + 0 < NN) offs[i0 + 0] = p;
  if (i0 + 1 < NN) offs[i0 + 1] = p + d0;
  if (i0 + 2 < NN) offs[i0 + 2] = p + d0 + d1;
  if (i0 + 3 < NN) offs[i0 + 3] = p + d0 + d1 + d2;
}

__global__ void k_scan2(int* __restrict__ bsum, int* __restrict__ boff,
                        int* __restrict__ offs, int nb) {
  if (threadIdx.x == 0 && blockIdx.x == 0) {
    int run = 0;
    for (int k = 0; k < nb; ++k) { boff[k] = run; run += bsum[k]; }
    offs[NN] = NE;
  }
}

__global__ void k_scan3(int* __restrict__ offs, const int* __restrict__ boff,
                        int* __restrict__ cursor) {
  int i = blockIdx.x * 256 + threadIdx.x;
  if (i < NN) {
    int v = offs[i] + boff[i >> 10];
    offs[i] = v;
    cursor[i] = v;
  }
}

__global__ void k_scatter(const int* __restrict__ src, const int* __restrict__ dst,
                          int* __restrict__ cursor, int* __restrict__ csr_src,
                          int* __restrict__ csr_eid) {
  int e = blockIdx.x * 256 + threadIdx.x;
  if (e >= NE) return;
  int pos = atomicAdd(&cursor[dst[e]], 1);
  csr_src[pos] = src[e];
  csr_eid[pos] = e;
}

// ---------------- upfront precomputes ----------------
__global__ void k_v_all(const float* __restrict__ ew_all, const float* __restrict__ ae_all,
                        float* __restrict__ vbuf) {
  int l = blockIdx.x;
  const float* ew = ew_all + (size_t)l * DD * DD;
  const float* ae = ae_all + (size_t)l * NH * NC;
  int d = threadIdx.x >> 2, h = threadIdx.x & 3;
  float s = 0.f;
#pragma unroll
  for (int c = 0; c < NC; ++c) s = fmaf(ew[d * DD + h * NC + c], ae[h * NC + c], s);
  vbuf[l * 256 + d * NH + h] = s;
}

__global__ void k_init_nf(const float* __restrict__ node_feats, float* __restrict__ nf) {
  int i = blockIdx.x * 256 + threadIdx.x;
  if (i < NN * DD) nf[i] = node_feats[i];
}

// ---------------- conv path ----------------
__global__ void k_xh(const float* __restrict__ nf, const float* __restrict__ W,
                     const float* __restrict__ as_, const float* __restrict__ ad_,
                     __bf16* __restrict__ xh16, float* __restrict__ asrc,
                     float* __restrict__ adst) {
  int t = blockIdx.x * 4 + (threadIdx.x >> 6);
  int d = threadIdx.x & 63;
  if (t >= NN) return;
  const float* x = nf + (size_t)t * DD;
  float acc = 0.f;
#pragma unroll
  for (int k = 0; k < DD; ++k) acc = fmaf(x[k], W[k * DD + d], acc);
  xh16[(size_t)t * DD + d] = (__bf16)acc;
  int h = d >> 4, c = d & 15;
  float ps = acc * as_[h * NC + c];
  float pd = acc * ad_[h * NC + c];
#pragma unroll
  for (int off = 8; off >= 1; off >>= 1) {
    ps += __shfl_xor(ps, off, 64);
    pd += __shfl_xor(pd, off, 64);
  }
  if (c == 0) { asrc[t * NH + h] = ps; adst[t * NH + h] = pd; }
}

// layer-0: edge_feats -> ef16 + RAW pe into araw[e] (both coalesced)
__global__ void k_pass1f(const float* __restrict__ edge_feats,
                         const float* __restrict__ v,
                         __bf16* __restrict__ ef16, float* __restrict__ araw) {
  int e = blockIdx.x * 64 + (threadIdx.x >> 2);
  int part = threadIdx.x & 3;
  if (e >= NE) return;
  float ph0 = 0.f, ph1 = 0.f, ph2 = 0.f, ph3 = 0.f;
  const float4* ep = (const float4*)(edge_feats + (size_t)e * DD + part * 16);
  const float4* v4 = (const float4*)v;
  bf4 outv[4];
#pragma unroll
  for (int c4 = 0; c4 < 4; ++c4) {
    float4 x = ep[c4];
    outv[c4][0] = (__bf16)x.x; outv[c4][1] = (__bf16)x.y;
    outv[c4][2] = (__bf16)x.z; outv[c4][3] = (__bf16)x.w;
    int d0 = part * 16 + c4 * 4;
    float4 va = v4[d0], vb = v4[d0 + 1], vc = v4[d0 + 2], vd = v4[d0 + 3];
    ph0 = fmaf(x.x, va.x, fmaf(x.y, vb.x, fmaf(x.z, vc.x, fmaf(x.w, vd.x, ph0))));
    ph1 = fmaf(x.x, va.y, fmaf(x.y, vb.y, fmaf(x.z, vc.y, fmaf(x.w, vd.y, ph1))));
    ph2 = fmaf(x.x, va.z, fmaf(x.y, vb.z, fmaf(x.z, vc.z, fmaf(x.w, vd.z, ph2))));
    ph3 = fmaf(x.x, va.w, fmaf(x.y, vb.w, fmaf(x.z, vc.w, fmaf(x.w, vd.w, ph3))));
  }
  *(bf8*)&ef16[(size_t)e * DD + part * 16] =
      (bf8){outv[0][0], outv[0][1], outv[0][2], outv[0][3],
            outv[1][0], outv[1][1], outv[1][2], outv[1][3]};
  *(bf8*)&ef16[(size_t)e * DD + part * 16 + 8] =
      (bf8){outv[2][0], outv[2][1], outv[2][2], outv[2][3],
            outv[3][0], outv[3][1], outv[3][2], outv[3][3]};
#pragma unroll
  for (int off = 1; off <= 2; off <<= 1) {
    ph0 += __shfl_xor(ph0, off, 64);
    ph1 += __shfl_xor(ph1, off, 64);
    ph2 += __shfl_xor(ph2, off, 64);
    ph3 += __shfl_xor(ph3, off, 64);
  }
  float pe = (part == 0) ? ph0 : (part == 1) ? ph1 : (part == 2) ? ph2 : ph3;
  araw[(size_t)e * NH + part] = pe;   // EDGE order, coalesced
}

// gather: araw holds RAW pe in EDGE order; leaky+LOG2E applied inline
__global__ __launch_bounds__(256) void k_gather2(
    const __bf16* __restrict__ xh16, const float* __restrict__ araw,
    const int* __restrict__ csr_src, const int* __restrict__ csr_eid,
    const int* __restrict__ offs,
    const float* __restrict__ asrc, const float* __restrict__ adst,
    const float* __restrict__ cb, const float* __restrict__ g,
    const float* __restrict__ bln, float* __restrict__ nf,
    __bf16* __restrict__ nf16) {
  int t = blockIdx.x * 4 + (threadIdx.x >> 6);
  int d = threadIdx.x & 63;
  if (t >= NN) return;
  int h = d >> 4;
  int o0 = offs[t], o1 = offs[t + 1];
  int deg = o1 - o0;
  float4 ad4 = ((const float4*)adst)[t];

  float m0 = -INFINITY, m1 = -INFINITY, m2 = -INFINITY, m3 = -INFINITY;
  for (int base = 0; base < deg; base += 64) {
    int j = base + d;
    if (j < deg) {
      int pos = o0 + j;
      int eid = csr_eid[pos];
      float4 pe = *(const float4*)(araw + (size_t)eid * NH);
      int sp = csr_src[pos];
      float4 as4 = ((const float4*)asrc)[sp];
      float a0 = as4.x + ad4.x + pe.x; a0 = ((a0 > 0.f) ? a0 : SLOPE * a0) * LOG2E;
      float a1 = as4.y + ad4.y + pe.y; a1 = ((a1 > 0.f) ? a1 : SLOPE * a1) * LOG2E;
      float a2 = as4.z + ad4.z + pe.z; a2 = ((a2 > 0.f) ? a2 : SLOPE * a2) * LOG2E;
      float a3 = as4.w + ad4.w + pe.w; a3 = ((a3 > 0.f) ? a3 : SLOPE * a3) * LOG2E;
      m0 = fmaxf(m0, a0); m1 = fmaxf(m1, a1);
      m2 = fmaxf(m2, a2); m3 = fmaxf(m3, a3);
    }
  }
#pragma unroll
  for (int off = 32; off >= 1; off >>= 1) {
    m0 = fmaxf(m0, __shfl_xor(m0, off, 64));
    m1 = fmaxf(m1, __shfl_xor(m1, off, 64));
    m2 = fmaxf(m2, __shfl_xor(m2, off, 64));
    m3 = fmaxf(m3, __shfl_xor(m3, off, 64));
  }
  float adh = (h == 0) ? ad4.x : (h == 1) ? ad4.y : (h == 2) ? ad4.z : ad4.w;
  float sh = asrc[t * NH + h] + adh;
  sh = ((sh > 0.f) ? sh : SLOPE * sh) * LOG2E;
  float mh = (h == 0) ? m0 : (h == 1) ? m1 : (h == 2) ? m2 : m3;
  mh = fmaxf(mh, sh);

  float acc = 0.f, wsum = 0.f;
  int j = 0;
  for (; j + 1 < deg; j += 2) {
    int pos0 = o0 + j, pos1 = o0 + j + 1;
    int sp0 = csr_src[pos0], sp1 = csr_src[pos1];
    int e0i = csr_eid[pos0], e1i = csr_eid[pos1];
    float ar0 = asrc[sp0 * NH + h] + adh + araw[(size_t)e0i * NH + h];
    float ar1 = asrc[sp1 * NH + h] + adh + araw[(size_t)e1i * NH + h];
    ar0 = ((ar0 > 0.f) ? ar0 : SLOPE * ar0) * LOG2E;
    ar1 = ((ar1 > 0.f) ? ar1 : SLOPE * ar1) * LOG2E;
    float w0 = exp2f(ar0 - mh), w1 = exp2f(ar1 - mh);
    acc = fmaf(w0, (float)xh16[(size_t)sp0 * DD + d], acc);
    acc = fmaf(w1, (float)xh16[(size_t)sp1 * DD + d], acc);
    wsum += w0 + w1;
  }
  if (j < deg) {
    int pos = o0 + j;
    int sp = csr_src[pos];
    int ei = csr_eid[pos];
    float ar = asrc[sp * NH + h] + adh + araw[(size_t)ei * NH + h];
    ar = ((ar > 0.f) ? ar : SLOPE * ar) * LOG2E;
    float w = exp2f(ar - mh);
    acc = fmaf(w, (float)xh16[(size_t)sp * DD + d], acc);
    wsum += w;
  }
  float wself = exp2f(sh - mh);
  acc = fmaf(wself, (float)xh16[(size_t)t * DD + d], acc);
  wsum += wself;

  float val = acc / (wsum + 1e-16f) + cb[d];
  float m = val;
#pragma unroll
  for (int off = 32; off >= 1; off >>= 1) m += __shfl_xor(m, off, 64);
  m *= (1.f / 64.f);
  float c = val - m;
  float q = c * c;
#pragma unroll
  for (int off = 32; off >= 1; off >>= 1) q += __shfl_xor(q, off, 64);
  float rstd = 1.f / sqrtf(q * (1.f / 64.f) + 1e-5f);
  float y = c * rstd * g[d] + bln[d];
  y = fmaxf(y, 0.f);
  float out = y + nf[(size_t)t * DD + d];
  nf[(size_t)t * DD + d] = out;
  nf16[(size_t)t * DD + d] = (__bf16)out;
}

// ---------------- edge MLP v14: pe via MFMA (W2VP/VP/bvdot decomposition) ----
// pe = H@(W2 v) + ef_old.v + b2.v ; each wave (rg,cg) computes pe for rows
// rg*64+cg*16.. via 2 extra accumulators (8 regs, offset by moving res to LDS).
__global__ __launch_bounds__(512, 4) void k_edge_mlp14(
    const __bf16* __restrict__ nf16, __bf16* __restrict__ ef16,
    float* __restrict__ efout,
    const int* __restrict__ src, const int* __restrict__ dst,
    const __bf16* __restrict__ W1H, const float* __restrict__ b1,
    const float* __restrict__ g, const float* __restrict__ bg,
    const __bf16* __restrict__ W2H, const float* __restrict__ b2,
    const __bf16* __restrict__ W2VP, const __bf16* __restrict__ VP,
    const float* __restrict__ bvdot, float* __restrict__ araw, int last) {
  __shared__ __bf16 XH[EB * XSTR];    // 51200 B: X | H | f32 output funnel
  __shared__ __bf16 RESB[EB * RSTR];  // 17408 B: ef_old residual (survives H)
  __shared__ __bf16 Pb[EB * 8];       // 2048 B: LN partials; slot 0 -> (mean,rstd)
  int tid = threadIdx.x;
  int e0 = blockIdx.x * EB;
  float* XF = (float*)XH;             // funnel view (128*66*4 = 33792 B)

  // stage X: thread owns (row = tid>>2, part p = tid&3); ef dual-written
  {
    int row = tid >> 2, p = tid & 3;
    int se = src[e0 + row], de = dst[e0 + row];
    const bf8* psrc = (const bf8*)(nf16 + (size_t)se * DD + p * 16);
    *(bf8*)&XH[row * XSTR + p * 16]     = psrc[0];
    *(bf8*)&XH[row * XSTR + p * 16 + 8] = psrc[1];
    const bf8* pdst = (const bf8*)(nf16 + (size_t)de * DD + p * 16);
    *(bf8*)&XH[row * XSTR + 64 + p * 16]     = pdst[0];
    *(bf8*)&XH[row * XSTR + 64 + p * 16 + 8] = pdst[1];
    const bf8* pef = (const bf8*)(ef16 + (size_t)(e0 + row) * DD + p * 16);
    bf8 ev0 = pef[0], ev1 = pef[1];
    *(bf8*)&XH[row * XSTR + 128 + p * 16]     = ev0;
    *(bf8*)&XH[row * XSTR + 128 + p * 16 + 8] = ev1;
    *(bf8*)&RESB[row * RSTR + p * 16]     = ev0;
    *(bf8*)&RESB[row * RSTR + p * 16 + 8] = ev1;
  }
  __syncthreads();

  int w = tid >> 6, l = tid & 63;
  int rg = w >> 2, cg = w & 3;
  int gq = l >> 4, i = l & 15;
  int col = cg * 16 + i;

  f32x4 acc[4][3];
#pragma unroll
  for (int rt = 0; rt < 4; ++rt)
#pragma unroll
    for (int t = 0; t < 3; ++t) acc[rt][t] = (f32x4){0.f, 0.f, 0.f, 0.f};
  f32x4 accP = (f32x4){0.f, 0.f, 0.f, 0.f};   // ef_old . v_next
  f32x4 accQ = (f32x4){0.f, 0.f, 0.f, 0.f};   // H @ (W2 v_next)

  // GEMM1: no barriers; B-tiles from global (L2-hot)
#pragma unroll
  for (int s = 0; s < 6; ++s) {
    bf8 a[4];
#pragma unroll
    for (int rt = 0; rt < 4; ++rt)
      a[rt] = *(const bf8*)&XH[(rg * 64 + rt * 16 + i) * XSTR + s * 32 + gq * 8];
#pragma unroll
    for (int t = 0; t < 3; ++t) {
      bf8 bh = *(const bf8*)(W1H + ((size_t)((cg * 3 + t) * 6 + s) * 64 + l) * 8);
#pragma unroll
      for (int rt = 0; rt < 4; ++rt) acc[rt][t] = MFMA(a[rt], bh, acc[rt][t]);
    }
    if (!last && s >= 4) {
      // ef_old rows for THIS wave's pe block: rt = cg (direct load, no dyn index)
      bf8 acg = *(const bf8*)&XH[(rg * 64 + cg * 16 + i) * XSTR + s * 32 + gq * 8];
      bf8 vp = *(const bf8*)(VP + ((size_t)((s - 4) * 64 + l)) * 8);
      accP = MFMA(acg, vp, accP);
    }
  }

  float b1v[3], gv[3], bgv[3];
#pragma unroll
  for (int t = 0; t < 3; ++t) {
    int n = cg * 48 + t * 16 + i;
    b1v[t] = b1[n]; gv[t] = g[n]; bgv[t] = bg[n];
  }
#pragma unroll
  for (int rt = 0; rt < 4; ++rt)
#pragma unroll
    for (int t = 0; t < 3; ++t)
#pragma unroll
      for (int r = 0; r < 4; ++r) acc[rt][t][r] += b1v[t];

#pragma unroll
  for (int rt = 0; rt < 4; ++rt)
#pragma unroll
    for (int r = 0; r < 4; ++r) {
      float sm = 0.f, sq = 0.f;
#pragma unroll
      for (int t = 0; t < 3; ++t) { float x = acc[rt][t][r]; sm += x; sq = fmaf(x, x, sq); }
#pragma unroll
      for (int off = 1; off <= 8; off <<= 1) {
        sm += __shfl_xor(sm, off, 64);
        sq += __shfl_xor(sq, off, 64);
      }
      if (i == 0) {
        int row = rg * 64 + rt * 16 + gq * 4 + r;
        bf2 pr; pr[0] = (__bf16)sm; pr[1] = (__bf16)sq;
        *(bf2*)&Pb[row * 8 + cg * 2] = pr;
      }
    }
  __syncthreads();   // barrier 1: partials ready; all X reads done

  if (tid < EB) {
    bf8 pv = *(const bf8*)&Pb[tid * 8];
    float sm = (float)pv[0] + (float)pv[2] + (float)pv[4] + (float)pv[6];
    float sq = (float)pv[1] + (float)pv[3] + (float)pv[5] + (float)pv[7];
    float mean = sm * (1.f / (float)DIN);
    float var = sq * (1.f / (float)DIN) - mean * mean;
    float rstd = 1.f / sqrtf(var + 1e-5f);
    bf2 mv; mv[0] = (__bf16)mean; mv[1] = (__bf16)rstd;
    *(bf2*)&Pb[tid * 8] = mv;
  }
  __syncthreads();   // barrier 2: (mean,rstd) ready

#pragma unroll
  for (int rt = 0; rt < 4; ++rt)
#pragma unroll
    for (int r = 0; r < 4; ++r) {
      int row = rg * 64 + rt * 16 + gq * 4 + r;
      bf2 mv = *(const bf2*)&Pb[row * 8];
      float mean = (float)mv[0], rstd = (float)mv[1];
#pragma unroll
      for (int t = 0; t < 3; ++t) {
        float y = (acc[rt][t][r] - mean) * rstd * gv[t] + bgv[t];
        y = fmaxf(y, 0.f);
        XH[row * XSTR + cg * 48 + t * 16 + i] = (__bf16)y;
      }
    }
  __syncthreads();   // barrier 3: H fully published

  // GEMM2 (+ accQ on this wave's rt=cg rows)
  f32x4 acc2[4];
#pragma unroll
  for (int rt = 0; rt < 4; ++rt) acc2[rt] = (f32x4){0.f, 0.f, 0.f, 0.f};

#pragma unroll
  for (int s = 0; s < 6; ++s) {
    bf8 a2[4];
#pragma unroll
    for (int rt = 0; rt < 4; ++rt)
      a2[rt] = *(const bf8*)&XH[(rg * 64 + rt * 16 + i) * XSTR + s * 32 + gq * 8];
    bf8 bh = *(const bf8*)(W2H + ((size_t)(cg * 6 + s) * 64 + l) * 8);
#pragma unroll
    for (int rt = 0; rt < 4; ++rt) acc2[rt] = MFMA(a2[rt], bh, acc2[rt]);
    if (!last) {
      bf8 acg = *(const bf8*)&XH[(rg * 64 + cg * 16 + i) * XSTR + s * 32 + gq * 8];
      bf8 wv = *(const bf8*)(W2VP + ((size_t)(s * 64 + l)) * 8);
      accQ = MFMA(acg, wv, accQ);
    }
  }
  __syncthreads();   // barrier 4: all H reads done; XH free for funnel

  float b2v = b2[col];
#pragma unroll
  for (int rt = 0; rt < 4; ++rt)
#pragma unroll
    for (int r = 0; r < 4; ++r) {
      int row = rg * 64 + rt * 16 + gq * 4 + r;
      float resv = (float)RESB[row * RSTR + col];
      XF[row * FSTR + col] = acc2[rt][r] + b2v + resv;
    }

  // pe scatter: this wave's rows rg*64+cg*16+gq*4+r, head i<4 (4B stores;
  // the r-loop covers every line fully -> fully-dirty lines, no RMW)
  if (!last && i < 4) {
    float bvd = bvdot[i];
#pragma unroll
    for (int r = 0; r < 4; ++r) {
      int row = rg * 64 + cg * 16 + gq * 4 + r;
      araw[(size_t)(e0 + row) * NH + i] = accP[r] + accQ[r] + bvd;
    }
  }
  __syncthreads();   // barrier 5: funnel filled

  // full-line coalesced ef output: thread owns (row = tid>>2, q = tid&3)
  {
    int row = tid >> 2, q = tid & 3;
    const float* fr = &XF[row * FSTR + q * 16];
    if (last) {
      float* op = efout + (size_t)(e0 + row) * DD + q * 16;
#pragma unroll
      for (int k = 0; k < 4; ++k)
        *(float4*)(op + k * 4) = *(const float4*)(fr + k * 4);
    } else {
      bf8 o0, o1;
#pragma unroll
      for (int k = 0; k < 8; ++k) { o0[k] = (__bf16)fr[k]; o1[k] = (__bf16)fr[k + 8]; }
      __bf16* op = ef16 + (size_t)(e0 + row) * DD + q * 16;
      *(bf8*)op = o0;
      *(bf8*)(op + 8) = o1;
    }
  }
}

extern "C" void kernel_launch(void* const* d_in, const int* in_sizes, int n_in,
                              void* d_out, int out_size, void* d_ws, size_t ws_size,
                              hipStream_t stream) {
  const float* node_feats = (const float*)d_in[0];
  const float* edge_feats = (const float*)d_in[1];
  const int*   edge_index = (const int*)d_in[2];
  const float* conv_w  = (const float*)d_in[3];
  const float* att_src = (const float*)d_in[4];
  const float* att_dst = (const float*)d_in[5];
  const float* edge_w  = (const float*)d_in[6];
  const float* att_edge= (const float*)d_in[7];
  const float* conv_b  = (const float*)d_in[8];
  const float* ln_g    = (const float*)d_in[9];
  const float* ln_b    = (const float*)d_in[10];
  const float* up1_w   = (const float*)d_in[11];
  const float* up1_b   = (const float*)d_in[12];
  const float* up_ln_g = (const float*)d_in[13];
  const float* up_ln_b = (const float*)d_in[14];
  const float* up2_w   = (const float*)d_in[15];
  const float* up2_b   = (const float*)d_in[16];

  const int* src = edge_index;
  const int* dst = edge_index + NE;

  float* nf = (float*)d_out;
  float* efout = nf + (size_t)NN * DD;

  float* w = (float*)d_ws;
  __bf16* xh16 = (__bf16*)w; w += (size_t)NN * DD / 2;
  __bf16* nf16 = (__bf16*)w; w += (size_t)NN * DD / 2;
  __bf16* ef16 = (__bf16*)w; w += (size_t)NE * DD / 2;
  float* asrc  = w; w += (size_t)NN * NH;
  float* adst  = w; w += (size_t)NN * NH;
  float* araw  = w; w += (size_t)NE * NH;          // RAW pe, EDGE order
  float* vbuf  = w; w += 4 * 256;
  float* bvdot = w; w += 16;
  __bf16* W1H  = (__bf16*)w; w += (size_t)4 * 36864 / 2;
  __bf16* W2H  = (__bf16*)w; w += (size_t)4 * 12288 / 2;
  __bf16* W2VP = (__bf16*)w; w += (size_t)3 * 3072 / 2;
  __bf16* VPb  = (__bf16*)w; w += (size_t)3 * 1024 / 2;
  int* deg     = (int*)w; w += NN;
  int* offs    = (int*)w; w += NN + 1;
  int* cursor  = (int*)w; w += NN;
  int* bsum    = (int*)w; w += 128;
  int* boff    = (int*)w; w += 128;
  int* csr_src = (int*)w; w += NE;
  int* csr_eid = (int*)w; w += NE;

  k_init_nf<<<(NN * DD + 255) / 256, 256, 0, stream>>>(node_feats, nf);
  k_pack_w1<<<72, 256, 0, stream>>>(up1_w, W1H);
  k_pack_w2<<<24, 256, 0, stream>>>(up2_w, W2H);

  const int nb = (NN + 1023) / 1024;
  k_zero<<<(NN + 255) / 256, 256, 0, stream>>>(deg);
  k_hist<<<(NE + 255) / 256, 256, 0, stream>>>(dst, deg);
  k_scan1<<<nb, 256, 0, stream>>>(deg, offs, bsum);
  k_scan2<<<1, 64, 0, stream>>>(bsum, boff, offs, nb);
  k_scan3<<<(NN + 255) / 256, 256, 0, stream>>>(offs, boff, cursor);
  k_scatter<<<(NE + 255) / 256, 256, 0, stream>>>(src, dst, cursor, csr_src, csr_eid);

  k_v_all<<<4, 256, 0, stream>>>(edge_w, att_edge, vbuf);
  k_w2v<<<3, 384, 0, stream>>>(up2_w, up2_b, vbuf, W2VP, VPb, bvdot);
  k_pass1f<<<NE / 64, 256, 0, stream>>>(edge_feats, vbuf, ef16, araw);

  for (int l = 0; l < NL; ++l) {
    int last = (l == NL - 1) ? 1 : 0;
    k_xh<<<NN / 4, 256, 0, stream>>>(nf, conv_w + (size_t)l * DD * DD,
                                     att_src + (size_t)l * NH * NC,
                                     att_dst + (size_t)l * NH * NC, xh16, asrc, adst);
    k_gather2<<<NN / 4, 256, 0, stream>>>(xh16, araw, csr_src, csr_eid, offs,
                                          asrc, adst,
                                          conv_b + (size_t)l * DD,
                                          ln_g + (size_t)l * DD,
                                          ln_b + (size_t)l * DD, nf, nf16);
    k_edge_mlp14<<<NE / EB, 512, 0, stream>>>(
        nf16, ef16, efout, src, dst,
        W1H + (size_t)l * 36864, up1_b + (size_t)l * DIN,
        up_ln_g + (size_t)l * DIN, up_ln_b + (size_t)l * DIN,
        W2H + (size_t)l * 12288, up2_b + (size_t)l * DD,
        last ? W2VP : (W2VP + (size_t)l * 3072),
        last ? VPb : (VPb + (size_t)l * 1024),
        bvdot + (size_t)l * 4, araw, last);
  }
}

// Round 18
// 2847.972 us; speedup vs baseline: 1.5909x; 1.0205x over previous
//
#include <hip/hip_runtime.h>
#include <math.h>

#define NN 100000
#define NE 1600000
#define DD 64
#define NL 4
#define NH 4
#define NC 16
#define DIN 192
#define SLOPE 0.2f
#define EB 64
#define XSTR 200
#define FSTR 66
#define RSTR 68
#define LOG2E 1.44269504088896340736f

typedef __bf16 bf8 __attribute__((ext_vector_type(8)));
typedef __bf16 bf4 __attribute__((ext_vector_type(4)));
typedef __bf16 bf2 __attribute__((ext_vector_type(2)));
typedef float f32x4 __attribute__((ext_vector_type(4)));

__device__ __forceinline__ f32x4 MFMA(bf8 a, bf8 b, f32x4 c) {
  return __builtin_amdgcn_mfma_f32_16x16x32_bf16(a, b, c, 0, 0, 0);
}

// ---------------- weight packing: single bf16 plane, 1KB tiles ----------------
__global__ void k_pack_w1(const float* __restrict__ W1, __bf16* __restrict__ WH) {
  int gidx = blockIdx.x * 256 + threadIdx.x;
  if (gidx >= 4 * 4608) return;
  int lyr = gidx / 4608, rem = gidx % 4608;
  int lane = rem & 63, ts = rem >> 6;
  int s = ts % 6, t = ts / 6;
  const float* Wl = W1 + (size_t)lyr * DIN * DIN;
  size_t base = (size_t)lyr * 36864 + ((size_t)(t * 6 + s) * 64 + lane) * 8;
  int k0 = s * 32 + (lane >> 4) * 8, n = t * 16 + (lane & 15);
#pragma unroll
  for (int j = 0; j < 8; ++j)
    WH[base + j] = (__bf16)Wl[(size_t)(k0 + j) * DIN + n];
}

__global__ void k_pack_w2(const float* __restrict__ W2, __bf16* __restrict__ WH) {
  int gidx = blockIdx.x * 256 + threadIdx.x;
  if (gidx >= 4 * 1536) return;
  int lyr = gidx / 1536, rem = gidx % 1536;
  int lane = rem & 63, ts = rem >> 6;
  int s = ts % 6, t = ts / 6;
  const float* Wl = W2 + (size_t)lyr * DIN * DD;
  size_t base = (size_t)lyr * 12288 + ((size_t)(t * 6 + s) * 64 + lane) * 8;
  int k0 = s * 32 + (lane >> 4) * 8, n = t * 16 + (lane & 15);
#pragma unroll
  for (int j = 0; j < 8; ++j)
    WH[base + j] = (__bf16)Wl[(size_t)(k0 + j) * DD + n];
}

// W2VP[l] = W2_l @ v_{l+1} packed as 6 B-tiles; VP[l] = v_{l+1} packed as 2 B-tiles;
// bvdot[l][h] = b2_l . v_{l+1}[:,h]   (l = 0..2)
__global__ void k_w2v(const float* __restrict__ up2_w, const float* __restrict__ up2_b,
                      const float* __restrict__ vbuf, __bf16* __restrict__ W2VP,
                      __bf16* __restrict__ VP, float* __restrict__ bvdot) {
  int l = blockIdx.x;
  const float* vn = vbuf + (l + 1) * 256;
  int t = threadIdx.x;
  if (t < 384) {
    int s = t >> 6, lane = t & 63;
    int i = lane & 15, k0 = s * 32 + (lane >> 4) * 8;
    const float* W2 = up2_w + (size_t)l * DIN * DD;
    __bf16* out = W2VP + (size_t)l * 3072 + ((size_t)(s * 64 + lane)) * 8;
#pragma unroll
    for (int j = 0; j < 8; ++j) {
      float val = 0.f;
      if (i < 4)
        for (int n = 0; n < DD; ++n)
          val = fmaf(W2[(size_t)(k0 + j) * DD + n], vn[n * NH + i], val);
      out[j] = (__bf16)val;
    }
  }
  if (t < 128) {
    int s2 = t >> 6, lane = t & 63;
    int i = lane & 15, k0 = s2 * 32 + (lane >> 4) * 8;
    __bf16* out = VP + (size_t)l * 1024 + ((size_t)(s2 * 64 + lane)) * 8;
#pragma unroll
    for (int j = 0; j < 8; ++j)
      out[j] = (i < 4) ? (__bf16)vn[(k0 + j) * NH + i] : (__bf16)0.f;
  }
  if (t < 4) {
    const float* b2 = up2_b + (size_t)l * DD;
    float bv = 0.f;
    for (int n = 0; n < DD; ++n) bv = fmaf(b2[n], vn[n * NH + t], bv);
    bvdot[l * 4 + t] = bv;
  }
}

// ---------------- CSR build ----------------
__global__ void k_zero(int* __restrict__ deg) {
  int i = blockIdx.x * 256 + threadIdx.x;
  if (i < NN) deg[i] = 0;
}

__global__ void k_hist(const int* __restrict__ dst, int* __restrict__ deg) {
  int e = blockIdx.x * 256 + threadIdx.x;
  if (e < NE) atomicAdd(&deg[dst[e]], 1);
}

__global__ void k_scan1(const int* __restrict__ deg, int* __restrict__ offs,
                        int* __restrict__ bsum) {
  __shared__ int sh[256];
  int t = threadIdx.x, b = blockIdx.x;
  int i0 = b * 1024 + t * 4;
  int d0 = (i0 + 0 < NN) ? deg[i0 + 0] : 0;
  int d1 = (i0 + 1 < NN) ? deg[i0 + 1] : 0;
  int d2 = (i0 + 2 < NN) ? deg[i0 + 2] : 0;
  int d3 = (i0 + 3 < NN) ? deg[i0 + 3] : 0;
  int s4 = d0 + d1 + d2 + d3;
  sh[t] = s4;
  __syncthreads();
  int p = 0;
#pragma unroll
  for (int off = 1; off < 256; off <<= 1) {
    int v = (t >= off) ? sh[t - off] : 0;
    __syncthreads();
    sh[t] += v;
    __syncthreads();
  }
  p = sh[t] - s4;
  if (t == 255) bsum[b] = sh[255];
  if (i0 + 0 < NN) offs[i0 + 0] = p;
  if (i0 + 1 < NN) offs[i0 + 1] = p + d0;
  if (i0 + 2 < NN) offs[i0 + 2] = p + d0 + d1;
  if (i0 + 3 < NN) offs[i0 + 3] = p + d0 + d1 + d2;
}

__global__ void k_scan2(int* __restrict__ bsum, int* __restrict__ boff,
                        int* __restrict__ offs, int nb) {
  if (threadIdx.x == 0 && blockIdx.x == 0) {
    int run = 0;
    for (int k = 0; k < nb; ++k) { boff[k] = run; run += bsum[k]; }
    offs[NN] = NE;
  }
}

__global__ void k_scan3(int* __restrict__ offs, const int* __restrict__ boff,
                        int* __restrict__ cursor) {
  int i = blockIdx.x * 256 + threadIdx.x;
  if (i < NN) {
    int v = offs[i] + boff[i >> 10];
    offs[i] = v;
    cursor[i] = v;
  }
}

__global__ void k_scatter(const int* __restrict__ src, const int* __restrict__ dst,
                          int* __restrict__ cursor, int* __restrict__ csr_src,
                          int* __restrict__ csr_eid) {
  int e = blockIdx.x * 256 + threadIdx.x;
  if (e >= NE) return;
  int pos = atomicAdd(&cursor[dst[e]], 1);
  csr_src[pos] = src[e];
  csr_eid[pos] = e;
}

// ---------------- upfront precomputes ----------------
__global__ void k_v_all(const float* __restrict__ ew_all, const float* __restrict__ ae_all,
                        float* __restrict__ vbuf) {
  int l = blockIdx.x;
  const float* ew = ew_all + (size_t)l * DD * DD;
  const float* ae = ae_all + (size_t)l * NH * NC;
  int d = threadIdx.x >> 2, h = threadIdx.x & 3;
  float s = 0.f;
#pragma unroll
  for (int c = 0; c < NC; ++c) s = fmaf(ew[d * DD + h * NC + c], ae[h * NC + c], s);
  vbuf[l * 256 + d * NH + h] = s;
}

__global__ void k_init_nf(const float* __restrict__ node_feats, float* __restrict__ nf) {
  int i = blockIdx.x * 256 + threadIdx.x;
  if (i < NN * DD) nf[i] = node_feats[i];
}

// ---------------- conv path ----------------
__global__ void k_xh(const float* __restrict__ nf, const float* __restrict__ W,
                     const float* __restrict__ as_, const float* __restrict__ ad_,
                     __bf16* __restrict__ xh16, float* __restrict__ asrc,
                     float* __restrict__ adst) {
  int t = blockIdx.x * 4 + (threadIdx.x >> 6);
  int d = threadIdx.x & 63;
  if (t >= NN) return;
  const float* x = nf + (size_t)t * DD;
  float acc = 0.f;
#pragma unroll
  for (int k = 0; k < DD; ++k) acc = fmaf(x[k], W[k * DD + d], acc);
  xh16[(size_t)t * DD + d] = (__bf16)acc;
  int h = d >> 4, c = d & 15;
  float ps = acc * as_[h * NC + c];
  float pd = acc * ad_[h * NC + c];
#pragma unroll
  for (int off = 8; off >= 1; off >>= 1) {
    ps += __shfl_xor(ps, off, 64);
    pd += __shfl_xor(pd, off, 64);
  }
  if (c == 0) { asrc[t * NH + h] = ps; adst[t * NH + h] = pd; }
}

// layer-0: edge_feats -> ef16 + RAW pe into araw[e] (both coalesced)
__global__ void k_pass1f(const float* __restrict__ edge_feats,
                         const float* __restrict__ v,
                         __bf16* __restrict__ ef16, float* __restrict__ araw) {
  int e = blockIdx.x * 64 + (threadIdx.x >> 2);
  int part = threadIdx.x & 3;
  if (e >= NE) return;
  float ph0 = 0.f, ph1 = 0.f, ph2 = 0.f, ph3 = 0.f;
  const float4* ep = (const float4*)(edge_feats + (size_t)e * DD + part * 16);
  const float4* v4 = (const float4*)v;
  bf4 outv[4];
#pragma unroll
  for (int c4 = 0; c4 < 4; ++c4) {
    float4 x = ep[c4];
    outv[c4][0] = (__bf16)x.x; outv[c4][1] = (__bf16)x.y;
    outv[c4][2] = (__bf16)x.z; outv[c4][3] = (__bf16)x.w;
    int d0 = part * 16 + c4 * 4;
    float4 va = v4[d0], vb = v4[d0 + 1], vc = v4[d0 + 2], vd = v4[d0 + 3];
    ph0 = fmaf(x.x, va.x, fmaf(x.y, vb.x, fmaf(x.z, vc.x, fmaf(x.w, vd.x, ph0))));
    ph1 = fmaf(x.x, va.y, fmaf(x.y, vb.y, fmaf(x.z, vc.y, fmaf(x.w, vd.y, ph1))));
    ph2 = fmaf(x.x, va.z, fmaf(x.y, vb.z, fmaf(x.z, vc.z, fmaf(x.w, vd.z, ph2))));
    ph3 = fmaf(x.x, va.w, fmaf(x.y, vb.w, fmaf(x.z, vc.w, fmaf(x.w, vd.w, ph3))));
  }
  *(bf8*)&ef16[(size_t)e * DD + part * 16] =
      (bf8){outv[0][0], outv[0][1], outv[0][2], outv[0][3],
            outv[1][0], outv[1][1], outv[1][2], outv[1][3]};
  *(bf8*)&ef16[(size_t)e * DD + part * 16 + 8] =
      (bf8){outv[2][0], outv[2][1], outv[2][2], outv[2][3],
            outv[3][0], outv[3][1], outv[3][2], outv[3][3]};
#pragma unroll
  for (int off = 1; off <= 2; off <<= 1) {
    ph0 += __shfl_xor(ph0, off, 64);
    ph1 += __shfl_xor(ph1, off, 64);
    ph2 += __shfl_xor(ph2, off, 64);
    ph3 += __shfl_xor(ph3, off, 64);
  }
  float pe = (part == 0) ? ph0 : (part == 1) ? ph1 : (part == 2) ? ph2 : ph3;
  araw[(size_t)e * NH + part] = pe;
}

// gather: araw holds RAW pe in EDGE order; leaky+LOG2E applied inline
__global__ __launch_bounds__(256) void k_gather2(
    const __bf16* __restrict__ xh16, const float* __restrict__ araw,
    const int* __restrict__ csr_src, const int* __restrict__ csr_eid,
    const int* __restrict__ offs,
    const float* __restrict__ asrc, const float* __restrict__ adst,
    const float* __restrict__ cb, const float* __restrict__ g,
    const float* __restrict__ bln, float* __restrict__ nf,
    __bf16* __restrict__ nf16) {
  int t = blockIdx.x * 4 + (threadIdx.x >> 6);
  int d = threadIdx.x & 63;
  if (t >= NN) return;
  int h = d >> 4;
  int o0 = offs[t], o1 = offs[t + 1];
  int deg = o1 - o0;
  float4 ad4 = ((const float4*)adst)[t];

  float m0 = -INFINITY, m1 = -INFINITY, m2 = -INFINITY, m3 = -INFINITY;
  for (int base = 0; base < deg; base += 64) {
    int j = base + d;
    if (j < deg) {
      int pos = o0 + j;
      int eid = csr_eid[pos];
      float4 pe = *(const float4*)(araw + (size_t)eid * NH);
      int sp = csr_src[pos];
      float4 as4 = ((const float4*)asrc)[sp];
      float a0 = as4.x + ad4.x + pe.x; a0 = ((a0 > 0.f) ? a0 : SLOPE * a0) * LOG2E;
      float a1 = as4.y + ad4.y + pe.y; a1 = ((a1 > 0.f) ? a1 : SLOPE * a1) * LOG2E;
      float a2 = as4.z + ad4.z + pe.z; a2 = ((a2 > 0.f) ? a2 : SLOPE * a2) * LOG2E;
      float a3 = as4.w + ad4.w + pe.w; a3 = ((a3 > 0.f) ? a3 : SLOPE * a3) * LOG2E;
      m0 = fmaxf(m0, a0); m1 = fmaxf(m1, a1);
      m2 = fmaxf(m2, a2); m3 = fmaxf(m3, a3);
    }
  }
#pragma unroll
  for (int off = 32; off >= 1; off >>= 1) {
    m0 = fmaxf(m0, __shfl_xor(m0, off, 64));
    m1 = fmaxf(m1, __shfl_xor(m1, off, 64));
    m2 = fmaxf(m2, __shfl_xor(m2, off, 64));
    m3 = fmaxf(m3, __shfl_xor(m3, off, 64));
  }
  float adh = (h == 0) ? ad4.x : (h == 1) ? ad4.y : (h == 2) ? ad4.z : ad4.w;
  float sh = asrc[t * NH + h] + adh;
  sh = ((sh > 0.f) ? sh : SLOPE * sh) * LOG2E;
  float mh = (h == 0) ? m0 : (h == 1) ? m1 : (h == 2) ? m2 : m3;
  mh = fmaxf(mh, sh);

  float acc = 0.f, wsum = 0.f;
  int j = 0;
  for (; j + 1 < deg; j += 2) {
    int pos0 = o0 + j, pos1 = o0 + j + 1;
    int sp0 = csr_src[pos0], sp1 = csr_src[pos1];
    int e0i = csr_eid[pos0], e1i = csr_eid[pos1];
    float ar0 = asrc[sp0 * NH + h] + adh + araw[(size_t)e0i * NH + h];
    float ar1 = asrc[sp1 * NH + h] + adh + araw[(size_t)e1i * NH + h];
    ar0 = ((ar0 > 0.f) ? ar0 : SLOPE * ar0) * LOG2E;
    ar1 = ((ar1 > 0.f) ? ar1 : SLOPE * ar1) * LOG2E;
    float w0 = exp2f(ar0 - mh), w1 = exp2f(ar1 - mh);
    acc = fmaf(w0, (float)xh16[(size_t)sp0 * DD + d], acc);
    acc = fmaf(w1, (float)xh16[(size_t)sp1 * DD + d], acc);
    wsum += w0 + w1;
  }
  if (j < deg) {
    int pos = o0 + j;
    int sp = csr_src[pos];
    int ei = csr_eid[pos];
    float ar = asrc[sp * NH + h] + adh + araw[(size_t)ei * NH + h];
    ar = ((ar > 0.f) ? ar : SLOPE * ar) * LOG2E;
    float w = exp2f(ar - mh);
    acc = fmaf(w, (float)xh16[(size_t)sp * DD + d], acc);
    wsum += w;
  }
  float wself = exp2f(sh - mh);
  acc = fmaf(wself, (float)xh16[(size_t)t * DD + d], acc);
  wsum += wself;

  float val = acc / (wsum + 1e-16f) + cb[d];
  float m = val;
#pragma unroll
  for (int off = 32; off >= 1; off >>= 1) m += __shfl_xor(m, off, 64);
  m *= (1.f / 64.f);
  float c = val - m;
  float q = c * c;
#pragma unroll
  for (int off = 32; off >= 1; off >>= 1) q += __shfl_xor(q, off, 64);
  float rstd = 1.f / sqrtf(q * (1.f / 64.f) + 1e-5f);
  float y = c * rstd * g[d] + bln[d];
  y = fmaxf(y, 0.f);
  float out = y + nf[(size_t)t * DD + d];
  nf[(size_t)t * DD + d] = out;
  nf16[(size_t)t * DD + d] = (__bf16)out;
}

// ---------------- edge MLP v15: mlp14 tile at 64 edges / 4 waves / 256 thr ---
// Same per-wave (4rt x 3t) tile and pe fusion; finer blocks -> ~4 independent
// blocks per CU interleave across barriers (latency hiding without more regs).
__global__ __launch_bounds__(256, 4) void k_edge_mlp15(
    const __bf16* __restrict__ nf16, __bf16* __restrict__ ef16,
    float* __restrict__ efout,
    const int* __restrict__ src, const int* __restrict__ dst,
    const __bf16* __restrict__ W1H, const float* __restrict__ b1,
    const float* __restrict__ g, const float* __restrict__ bg,
    const __bf16* __restrict__ W2H, const float* __restrict__ b2,
    const __bf16* __restrict__ W2VP, const __bf16* __restrict__ VP,
    const float* __restrict__ bvdot, float* __restrict__ araw, int last) {
  __shared__ __bf16 XH[EB * XSTR];    // 25600 B: X | H | f32 output funnel
  __shared__ __bf16 RESB[EB * RSTR];  //  8704 B: ef_old residual (survives H)
  __shared__ __bf16 Pb[EB * 8];       //  1024 B: LN partials; slot 0 -> (mean,rstd)
  int tid = threadIdx.x;
  int e0 = blockIdx.x * EB;
  float* XF = (float*)XH;             // funnel view (64*66*4 = 16896 B)

  // stage X: thread owns (row = tid>>2, part p = tid&3); ef dual-written
  {
    int row = tid >> 2, p = tid & 3;
    int se = src[e0 + row], de = dst[e0 + row];
    const bf8* psrc = (const bf8*)(nf16 + (size_t)se * DD + p * 16);
    *(bf8*)&XH[row * XSTR + p * 16]     = psrc[0];
    *(bf8*)&XH[row * XSTR + p * 16 + 8] = psrc[1];
    const bf8* pdst = (const bf8*)(nf16 + (size_t)de * DD + p * 16);
    *(bf8*)&XH[row * XSTR + 64 + p * 16]     = pdst[0];
    *(bf8*)&XH[row * XSTR + 64 + p * 16 + 8] = pdst[1];
    const bf8* pef = (const bf8*)(ef16 + (size_t)(e0 + row) * DD + p * 16);
    bf8 ev0 = pef[0], ev1 = pef[1];
    *(bf8*)&XH[row * XSTR + 128 + p * 16]     = ev0;
    *(bf8*)&XH[row * XSTR + 128 + p * 16 + 8] = ev1;
    *(bf8*)&RESB[row * RSTR + p * 16]     = ev0;
    *(bf8*)&RESB[row * RSTR + p * 16 + 8] = ev1;
  }
  __syncthreads();

  int cg = tid >> 6, l = tid & 63;
  int gq = l >> 4, i = l & 15;
  int col = cg * 16 + i;

  f32x4 acc[4][3];
#pragma unroll
  for (int rt = 0; rt < 4; ++rt)
#pragma unroll
    for (int t = 0; t < 3; ++t) acc[rt][t] = (f32x4){0.f, 0.f, 0.f, 0.f};
  f32x4 accP = (f32x4){0.f, 0.f, 0.f, 0.f};   // ef_old . v_next
  f32x4 accQ = (f32x4){0.f, 0.f, 0.f, 0.f};   // H @ (W2 v_next)

  // GEMM1: no barriers; B-tiles from global (L2-hot)
#pragma unroll
  for (int s = 0; s < 6; ++s) {
    bf8 a[4];
#pragma unroll
    for (int rt = 0; rt < 4; ++rt)
      a[rt] = *(const bf8*)&XH[(rt * 16 + i) * XSTR + s * 32 + gq * 8];
#pragma unroll
    for (int t = 0; t < 3; ++t) {
      bf8 bh = *(const bf8*)(W1H + ((size_t)((cg * 3 + t) * 6 + s) * 64 + l) * 8);
#pragma unroll
      for (int rt = 0; rt < 4; ++rt) acc[rt][t] = MFMA(a[rt], bh, acc[rt][t]);
    }
    if (!last && s >= 4) {
      // ef_old rows for THIS wave's pe block: rt = cg (direct load, no dyn index)
      bf8 acg = *(const bf8*)&XH[(cg * 16 + i) * XSTR + s * 32 + gq * 8];
      bf8 vp = *(const bf8*)(VP + ((size_t)((s - 4) * 64 + l)) * 8);
      accP = MFMA(acg, vp, accP);
    }
  }

  float b1v[3], gv[3], bgv[3];
#pragma unroll
  for (int t = 0; t < 3; ++t) {
    int n = cg * 48 + t * 16 + i;
    b1v[t] = b1[n]; gv[t] = g[n]; bgv[t] = bg[n];
  }
#pragma unroll
  for (int rt = 0; rt < 4; ++rt)
#pragma unroll
    for (int t = 0; t < 3; ++t)
#pragma unroll
      for (int r = 0; r < 4; ++r) acc[rt][t][r] += b1v[t];

#pragma unroll
  for (int rt = 0; rt < 4; ++rt)
#pragma unroll
    for (int r = 0; r < 4; ++r) {
      float sm = 0.f, sq = 0.f;
#pragma unroll
      for (int t = 0; t < 3; ++t) { float x = acc[rt][t][r]; sm += x; sq = fmaf(x, x, sq); }
#pragma unroll
      for (int off = 1; off <= 8; off <<= 1) {
        sm += __shfl_xor(sm, off, 64);
        sq += __shfl_xor(sq, off, 64);
      }
      if (i == 0) {
        int row = rt * 16 + gq * 4 + r;
        bf2 pr; pr[0] = (__bf16)sm; pr[1] = (__bf16)sq;
        *(bf2*)&Pb[row * 8 + cg * 2] = pr;
      }
    }
  __syncthreads();   // barrier 1: partials ready; all X reads done

  if (tid < EB) {
    bf8 pv = *(const bf8*)&Pb[tid * 8];
    float sm = (float)pv[0] + (float)pv[2] + (float)pv[4] + (float)pv[6];
    float sq = (float)pv[1] + (float)pv[3] + (float)pv[5] + (float)pv[7];
    float mean = sm * (1.f / (float)DIN);
    float var = sq * (1.f / (float)DIN) - mean * mean;
    float rstd = 1.f / sqrtf(var + 1e-5f);
    bf2 mv; mv[0] = (__bf16)mean; mv[1] = (__bf16)rstd;
    *(bf2*)&Pb[tid * 8] = mv;
  }
  __syncthreads();   // barrier 2: (mean,rstd) ready

#pragma unroll
  for (int rt = 0; rt < 4; ++rt)
#pragma unroll
    for (int r = 0; r < 4; ++r) {
      int row = rt * 16 + gq * 4 + r;
      bf2 mv = *(const bf2*)&Pb[row * 8];
      float mean = (float)mv[0], rstd = (float)mv[1];
#pragma unroll
      for (int t = 0; t < 3; ++t) {
        float y = (acc[rt][t][r] - mean) * rstd * gv[t] + bgv[t];
        y = fmaxf(y, 0.f);
        XH[row * XSTR + cg * 48 + t * 16 + i] = (__bf16)y;
      }
    }
  __syncthreads();   // barrier 3: H fully published

  // GEMM2 (+ accQ on this wave's rt=cg rows)
  f32x4 acc2[4];
#pragma unroll
  for (int rt = 0; rt < 4; ++rt) acc2[rt] = (f32x4){0.f, 0.f, 0.f, 0.f};

#pragma unroll
  for (int s = 0; s < 6; ++s) {
    bf8 a2[4];
#pragma unroll
    for (int rt = 0; rt < 4; ++rt)
      a2[rt] = *(const bf8*)&XH[(rt * 16 + i) * XSTR + s * 32 + gq * 8];
    bf8 bh = *(const bf8*)(W2H + ((size_t)(cg * 6 + s) * 64 + l) * 8);
#pragma unroll
    for (int rt = 0; rt < 4; ++rt) acc2[rt] = MFMA(a2[rt], bh, acc2[rt]);
    if (!last) {
      bf8 acg = *(const bf8*)&XH[(cg * 16 + i) * XSTR + s * 32 + gq * 8];
      bf8 wv = *(const bf8*)(W2VP + ((size_t)(s * 64 + l)) * 8);
      accQ = MFMA(acg, wv, accQ);
    }
  }
  __syncthreads();   // barrier 4: all H reads done; XH free for funnel

  float b2v = b2[col];
#pragma unroll
  for (int rt = 0; rt < 4; ++rt)
#pragma unroll
    for (int r = 0; r < 4; ++r) {
      int row = rt * 16 + gq * 4 + r;
      float resv = (float)RESB[row * RSTR + col];
      XF[row * FSTR + col] = acc2[rt][r] + b2v + resv;
    }

  // pe scatter: this wave's rows cg*16+gq*4+r, head i<4
  if (!last && i < 4) {
    float bvd = bvdot[i];
#pragma unroll
    for (int r = 0; r < 4; ++r) {
      int row = cg * 16 + gq * 4 + r;
      araw[(size_t)(e0 + row) * NH + i] = accP[r] + accQ[r] + bvd;
    }
  }
  __syncthreads();   // barrier 5: funnel filled

  // full-line coalesced ef output: thread owns (row = tid>>2, q = tid&3)
  {
    int row = tid >> 2, q = tid & 3;
    const float* fr = &XF[row * FSTR + q * 16];
    if (last) {
      float* op = efout + (size_t)(e0 + row) * DD + q * 16;
#pragma unroll
      for (int k = 0; k < 4; ++k)
        *(float4*)(op + k * 4) = *(const float4*)(fr + k * 4);
    } else {
      bf8 o0, o1;
#pragma unroll
      for (int k = 0; k < 8; ++k) { o0[k] = (__bf16)fr[k]; o1[k] = (__bf16)fr[k + 8]; }
      __bf16* op = ef16 + (size_t)(e0 + row) * DD + q * 16;
      *(bf8*)op = o0;
      *(bf8*)(op + 8) = o1;
    }
  }
}

extern "C" void kernel_launch(void* const* d_in, const int* in_sizes, int n_in,
                              void* d_out, int out_size, void* d_ws, size_t ws_size,
                              hipStream_t stream) {
  const float* node_feats = (const float*)d_in[0];
  const float* edge_feats = (const float*)d_in[1];
  const int*   edge_index = (const int*)d_in[2];
  const float* conv_w  = (const float*)d_in[3];
  const float* att_src = (const float*)d_in[4];
  const float* att_dst = (const float*)d_in[5];
  const float* edge_w  = (const float*)d_in[6];
  const float* att_edge= (const float*)d_in[7];
  const float* conv_b  = (const float*)d_in[8];
  const float* ln_g    = (const float*)d_in[9];
  const float* ln_b    = (const float*)d_in[10];
  const float* up1_w   = (const float*)d_in[11];
  const float* up1_b   = (const float*)d_in[12];
  const float* up_ln_g = (const float*)d_in[13];
  const float* up_ln_b = (const float*)d_in[14];
  const float* up2_w   = (const float*)d_in[15];
  const float* up2_b   = (const float*)d_in[16];

  const int* src = edge_index;
  const int* dst = edge_index + NE;

  float* nf = (float*)d_out;
  float* efout = nf + (size_t)NN * DD;

  float* w = (float*)d_ws;
  __bf16* xh16 = (__bf16*)w; w += (size_t)NN * DD / 2;
  __bf16* nf16 = (__bf16*)w; w += (size_t)NN * DD / 2;
  __bf16* ef16 = (__bf16*)w; w += (size_t)NE * DD / 2;
  float* asrc  = w; w += (size_t)NN * NH;
  float* adst  = w; w += (size_t)NN * NH;
  float* araw  = w; w += (size_t)NE * NH;
  float* vbuf  = w; w += 4 * 256;
  float* bvdot = w; w += 16;
  __bf16* W1H  = (__bf16*)w; w += (size_t)4 * 36864 / 2;
  __bf16* W2H  = (__bf16*)w; w += (size_t)4 * 12288 / 2;
  __bf16* W2VP = (__bf16*)w; w += (size_t)3 * 3072 / 2;
  __bf16* VPb  = (__bf16*)w; w += (size_t)3 * 1024 / 2;
  int* deg     = (int*)w; w += NN;
  int* offs    = (int*)w; w += NN + 1;
  int* cursor  = (int*)w; w += NN;
  int* bsum    = (int*)w; w += 128;
  int* boff    = (int*)w; w += 128;
  int* csr_src = (int*)w; w += NE;
  int* csr_eid = (int*)w; w += NE;

  k_init_nf<<<(NN * DD + 255) / 256, 256, 0, stream>>>(node_feats, nf);
  k_pack_w1<<<72, 256, 0, stream>>>(up1_w, W1H);
  k_pack_w2<<<24, 256, 0, stream>>>(up2_w, W2H);

  const int nb = (NN + 1023) / 1024;
  k_zero<<<(NN + 255) / 256, 256, 0, stream>>>(deg);
  k_hist<<<(NE + 255) / 256, 256, 0, stream>>>(dst, deg);
  k_scan1<<<nb, 256, 0, stream>>>(deg, offs, bsum);
  k_scan2<<<1, 64, 0, stream>>>(bsum, boff, offs, nb);
  k_scan3<<<(NN + 255) / 256, 256, 0, stream>>>(offs, boff, cursor);
  k_scatter<<<(NE + 255) / 256, 256, 0, stream>>>(src, dst, cursor, csr_src, csr_eid);

  k_v_all<<<4, 256, 0, stream>>>(edge_w, att_edge, vbuf);
  k_w2v<<<3, 384, 0, stream>>>(up2_w, up2_b, vbuf, W2VP, VPb, bvdot);
  k_pass1f<<<NE / 64, 256, 0, stream>>>(edge_feats, vbuf, ef16, araw);

  for (int l = 0; l < NL; ++l) {
    int last = (l == NL - 1) ? 1 : 0;
    k_xh<<<NN / 4, 256, 0, stream>>>(nf, conv_w + (size_t)l * DD * DD,
                                     att_src + (size_t)l * NH * NC,
                                     att_dst + (size_t)l * NH * NC, xh16, asrc, adst);
    k_gather2<<<NN / 4, 256, 0, stream>>>(xh16, araw, csr_src, csr_eid, offs,
                                          asrc, adst,
                                          conv_b + (size_t)l * DD,
                                          ln_g + (size_t)l * DD,
                                          ln_b + (size_t)l * DD, nf, nf16);
    k_edge_mlp15<<<NE / EB, 256, 0, stream>>>(
        nf16, ef16, efout, src, dst,
        W1H + (size_t)l * 36864, up1_b + (size_t)l * DIN,
        up_ln_g + (size_t)l * DIN, up_ln_b + (size_t)l * DIN,
        W2H + (size_t)l * 12288, up2_b + (size_t)l * DD,
        last ? W2VP : (W2VP + (size_t)l * 3072),
        last ? VPb : (VPb + (size_t)l * 1024),
        bvdot + (size_t)l * 4, araw, last);
  }
}

// Round 19
// 2788.660 us; speedup vs baseline: 1.6248x; 1.0213x over previous
//
#include <hip/hip_runtime.h>
#include <math.h>

#define NN 100000
#define NE 1600000
#define DD 64
#define NL 4
#define NH 4
#define NC 16
#define DIN 192
#define SLOPE 0.2f
#define EB 64
#define XSTR 200
#define FSTR 66
#define RSTR 68
#define LOG2E 1.44269504088896340736f

typedef __bf16 bf8 __attribute__((ext_vector_type(8)));
typedef __bf16 bf4 __attribute__((ext_vector_type(4)));
typedef __bf16 bf2 __attribute__((ext_vector_type(2)));
typedef float f32x4 __attribute__((ext_vector_type(4)));

__device__ __forceinline__ f32x4 MFMA(bf8 a, bf8 b, f32x4 c) {
  return __builtin_amdgcn_mfma_f32_16x16x32_bf16(a, b, c, 0, 0, 0);
}

// ---------------- weight packing: single bf16 plane, 1KB tiles ----------------
__global__ void k_pack_w1(const float* __restrict__ W1, __bf16* __restrict__ WH) {
  int gidx = blockIdx.x * 256 + threadIdx.x;
  if (gidx >= 4 * 4608) return;
  int lyr = gidx / 4608, rem = gidx % 4608;
  int lane = rem & 63, ts = rem >> 6;
  int s = ts % 6, t = ts / 6;
  const float* Wl = W1 + (size_t)lyr * DIN * DIN;
  size_t base = (size_t)lyr * 36864 + ((size_t)(t * 6 + s) * 64 + lane) * 8;
  int k0 = s * 32 + (lane >> 4) * 8, n = t * 16 + (lane & 15);
#pragma unroll
  for (int j = 0; j < 8; ++j)
    WH[base + j] = (__bf16)Wl[(size_t)(k0 + j) * DIN + n];
}

__global__ void k_pack_w2(const float* __restrict__ W2, __bf16* __restrict__ WH) {
  int gidx = blockIdx.x * 256 + threadIdx.x;
  if (gidx >= 4 * 1536) return;
  int lyr = gidx / 1536, rem = gidx % 1536;
  int lane = rem & 63, ts = rem >> 6;
  int s = ts % 6, t = ts / 6;
  const float* Wl = W2 + (size_t)lyr * DIN * DD;
  size_t base = (size_t)lyr * 12288 + ((size_t)(t * 6 + s) * 64 + lane) * 8;
  int k0 = s * 32 + (lane >> 4) * 8, n = t * 16 + (lane & 15);
#pragma unroll
  for (int j = 0; j < 8; ++j)
    WH[base + j] = (__bf16)Wl[(size_t)(k0 + j) * DD + n];
}

// W2VP[l] = W2_l @ v_{l+1} packed as 6 B-tiles; VP[l] = v_{l+1} packed as 2 B-tiles;
// bvdot[l][h] = b2_l . v_{l+1}[:,h]   (l = 0..2)
__global__ void k_w2v(const float* __restrict__ up2_w, const float* __restrict__ up2_b,
                      const float* __restrict__ vbuf, __bf16* __restrict__ W2VP,
                      __bf16* __restrict__ VP, float* __restrict__ bvdot) {
  int l = blockIdx.x;
  const float* vn = vbuf + (l + 1) * 256;
  int t = threadIdx.x;
  if (t < 384) {
    int s = t >> 6, lane = t & 63;
    int i = lane & 15, k0 = s * 32 + (lane >> 4) * 8;
    const float* W2 = up2_w + (size_t)l * DIN * DD;
    __bf16* out = W2VP + (size_t)l * 3072 + ((size_t)(s * 64 + lane)) * 8;
#pragma unroll
    for (int j = 0; j < 8; ++j) {
      float val = 0.f;
      if (i < 4)
        for (int n = 0; n < DD; ++n)
          val = fmaf(W2[(size_t)(k0 + j) * DD + n], vn[n * NH + i], val);
      out[j] = (__bf16)val;
    }
  }
  if (t < 128) {
    int s2 = t >> 6, lane = t & 63;
    int i = lane & 15, k0 = s2 * 32 + (lane >> 4) * 8;
    __bf16* out = VP + (size_t)l * 1024 + ((size_t)(s2 * 64 + lane)) * 8;
#pragma unroll
    for (int j = 0; j < 8; ++j)
      out[j] = (i < 4) ? (__bf16)vn[(k0 + j) * NH + i] : (__bf16)0.f;
  }
  if (t < 4) {
    const float* b2 = up2_b + (size_t)l * DD;
    float bv = 0.f;
    for (int n = 0; n < DD; ++n) bv = fmaf(b2[n], vn[n * NH + t], bv);
    bvdot[l * 4 + t] = bv;
  }
}

// ---------------- CSR build ----------------
__global__ void k_zero(int* __restrict__ deg) {
  int i = blockIdx.x * 256 + threadIdx.x;
  if (i < NN) deg[i] = 0;
}

__global__ void k_hist(const int* __restrict__ dst, int* __restrict__ deg) {
  int e = blockIdx.x * 256 + threadIdx.x;
  if (e < NE) atomicAdd(&deg[dst[e]], 1);
}

__global__ void k_scan1(const int* __restrict__ deg, int* __restrict__ offs,
                        int* __restrict__ bsum) {
  __shared__ int sh[256];
  int t = threadIdx.x, b = blockIdx.x;
  int i0 = b * 1024 + t * 4;
  int d0 = (i0 + 0 < NN) ? deg[i0 + 0] : 0;
  int d1 = (i0 + 1 < NN) ? deg[i0 + 1] : 0;
  int d2 = (i0 + 2 < NN) ? deg[i0 + 2] : 0;
  int d3 = (i0 + 3 < NN) ? deg[i0 + 3] : 0;
  int s4 = d0 + d1 + d2 + d3;
  sh[t] = s4;
  __syncthreads();
  int p = 0;
#pragma unroll
  for (int off = 1; off < 256; off <<= 1) {
    int v = (t >= off) ? sh[t - off] : 0;
    __syncthreads();
    sh[t] += v;
    __syncthreads();
  }
  p = sh[t] - s4;
  if (t == 255) bsum[b] = sh[255];
  if (i0 + 0 < NN) offs[i0 + 0] = p;
  if (i0 + 1 < NN) offs[i0 + 1] = p + d0;
  if (i0 + 2 < NN) offs[i0 + 2] = p + d0 + d1;
  if (i0 + 3 < NN) offs[i0 + 3] = p + d0 + d1 + d2;
}

__global__ void k_scan2(int* __restrict__ bsum, int* __restrict__ boff,
                        int* __restrict__ offs, int nb) {
  if (threadIdx.x == 0 && blockIdx.x == 0) {
    int run = 0;
    for (int k = 0; k < nb; ++k) { boff[k] = run; run += bsum[k]; }
    offs[NN] = NE;
  }
}

__global__ void k_scan3(int* __restrict__ offs, const int* __restrict__ boff,
                        int* __restrict__ cursor) {
  int i = blockIdx.x * 256 + threadIdx.x;
  if (i < NN) {
    int v = offs[i] + boff[i >> 10];
    offs[i] = v;
    cursor[i] = v;
  }
}

__global__ void k_scatter(const int* __restrict__ src, const int* __restrict__ dst,
                          int* __restrict__ cursor, int* __restrict__ csr_src,
                          int* __restrict__ csr_eid) {
  int e = blockIdx.x * 256 + threadIdx.x;
  if (e >= NE) return;
  int pos = atomicAdd(&cursor[dst[e]], 1);
  csr_src[pos] = src[e];
  csr_eid[pos] = e;
}

// ---------------- upfront precomputes ----------------
__global__ void k_v_all(const float* __restrict__ ew_all, const float* __restrict__ ae_all,
                        float* __restrict__ vbuf) {
  int l = blockIdx.x;
  const float* ew = ew_all + (size_t)l * DD * DD;
  const float* ae = ae_all + (size_t)l * NH * NC;
  int d = threadIdx.x >> 2, h = threadIdx.x & 3;
  float s = 0.f;
#pragma unroll
  for (int c = 0; c < NC; ++c) s = fmaf(ew[d * DD + h * NC + c], ae[h * NC + c], s);
  vbuf[l * 256 + d * NH + h] = s;
}

__global__ void k_init_nf(const float* __restrict__ node_feats, float* __restrict__ nf) {
  int i = blockIdx.x * 256 + threadIdx.x;
  if (i < NN * DD) nf[i] = node_feats[i];
}

// ---------------- conv path ----------------
__global__ void k_xh(const float* __restrict__ nf, const float* __restrict__ W,
                     const float* __restrict__ as_, const float* __restrict__ ad_,
                     __bf16* __restrict__ xh16, float* __restrict__ asrc,
                     float* __restrict__ adst) {
  int t = blockIdx.x * 4 + (threadIdx.x >> 6);
  int d = threadIdx.x & 63;
  if (t >= NN) return;
  const float* x = nf + (size_t)t * DD;
  float acc = 0.f;
#pragma unroll
  for (int k = 0; k < DD; ++k) acc = fmaf(x[k], W[k * DD + d], acc);
  xh16[(size_t)t * DD + d] = (__bf16)acc;
  int h = d >> 4, c = d & 15;
  float ps = acc * as_[h * NC + c];
  float pd = acc * ad_[h * NC + c];
#pragma unroll
  for (int off = 8; off >= 1; off >>= 1) {
    ps += __shfl_xor(ps, off, 64);
    pd += __shfl_xor(pd, off, 64);
  }
  if (c == 0) { asrc[t * NH + h] = ps; adst[t * NH + h] = pd; }
}

// layer-0: edge_feats -> ef16 + RAW pe into araw[e] (both coalesced)
__global__ void k_pass1f(const float* __restrict__ edge_feats,
                         const float* __restrict__ v,
                         __bf16* __restrict__ ef16, float* __restrict__ araw) {
  int e = blockIdx.x * 64 + (threadIdx.x >> 2);
  int part = threadIdx.x & 3;
  if (e >= NE) return;
  float ph0 = 0.f, ph1 = 0.f, ph2 = 0.f, ph3 = 0.f;
  const float4* ep = (const float4*)(edge_feats + (size_t)e * DD + part * 16);
  const float4* v4 = (const float4*)v;
  bf4 outv[4];
#pragma unroll
  for (int c4 = 0; c4 < 4; ++c4) {
    float4 x = ep[c4];
    outv[c4][0] = (__bf16)x.x; outv[c4][1] = (__bf16)x.y;
    outv[c4][2] = (__bf16)x.z; outv[c4][3] = (__bf16)x.w;
    int d0 = part * 16 + c4 * 4;
    float4 va = v4[d0], vb = v4[d0 + 1], vc = v4[d0 + 2], vd = v4[d0 + 3];
    ph0 = fmaf(x.x, va.x, fmaf(x.y, vb.x, fmaf(x.z, vc.x, fmaf(x.w, vd.x, ph0))));
    ph1 = fmaf(x.x, va.y, fmaf(x.y, vb.y, fmaf(x.z, vc.y, fmaf(x.w, vd.y, ph1))));
    ph2 = fmaf(x.x, va.z, fmaf(x.y, vb.z, fmaf(x.z, vc.z, fmaf(x.w, vd.z, ph2))));
    ph3 = fmaf(x.x, va.w, fmaf(x.y, vb.w, fmaf(x.z, vc.w, fmaf(x.w, vd.w, ph3))));
  }
  *(bf8*)&ef16[(size_t)e * DD + part * 16] =
      (bf8){outv[0][0], outv[0][1], outv[0][2], outv[0][3],
            outv[1][0], outv[1][1], outv[1][2], outv[1][3]};
  *(bf8*)&ef16[(size_t)e * DD + part * 16 + 8] =
      (bf8){outv[2][0], outv[2][1], outv[2][2], outv[2][3],
            outv[3][0], outv[3][1], outv[3][2], outv[3][3]};
#pragma unroll
  for (int off = 1; off <= 2; off <<= 1) {
    ph0 += __shfl_xor(ph0, off, 64);
    ph1 += __shfl_xor(ph1, off, 64);
    ph2 += __shfl_xor(ph2, off, 64);
    ph3 += __shfl_xor(ph3, off, 64);
  }
  float pe = (part == 0) ? ph0 : (part == 1) ? ph1 : (part == 2) ? ph2 : ph3;
  araw[(size_t)e * NH + part] = pe;
}

// gather v3: ONLINE softmax, single pass (no segment-max sweep)
__global__ __launch_bounds__(256) void k_gather3(
    const __bf16* __restrict__ xh16, const float* __restrict__ araw,
    const int* __restrict__ csr_src, const int* __restrict__ csr_eid,
    const int* __restrict__ offs,
    const float* __restrict__ asrc, const float* __restrict__ adst,
    const float* __restrict__ cb, const float* __restrict__ g,
    const float* __restrict__ bln, float* __restrict__ nf,
    __bf16* __restrict__ nf16) {
  int t = blockIdx.x * 4 + (threadIdx.x >> 6);
  int d = threadIdx.x & 63;
  if (t >= NN) return;
  int h = d >> 4;
  int o0 = offs[t], o1 = offs[t + 1];
  int deg = o1 - o0;
  float adh = adst[t * NH + h];

  // seed with self-loop (edge attr = 0)
  float sh = asrc[t * NH + h] + adh;
  sh = ((sh > 0.f) ? sh : SLOPE * sh) * LOG2E;
  float m_run = sh;
  float wsum = 1.f;
  float acc = (float)xh16[(size_t)t * DD + d];

  int j = 0;
  for (; j + 1 < deg; j += 2) {
    int pos0 = o0 + j, pos1 = o0 + j + 1;
    int sp0 = csr_src[pos0], sp1 = csr_src[pos1];
    int e0i = csr_eid[pos0], e1i = csr_eid[pos1];
    float ar0 = asrc[sp0 * NH + h] + adh + araw[(size_t)e0i * NH + h];
    float ar1 = asrc[sp1 * NH + h] + adh + araw[(size_t)e1i * NH + h];
    ar0 = ((ar0 > 0.f) ? ar0 : SLOPE * ar0) * LOG2E;
    ar1 = ((ar1 > 0.f) ? ar1 : SLOPE * ar1) * LOG2E;
    float x0 = (float)xh16[(size_t)sp0 * DD + d];
    float x1 = (float)xh16[(size_t)sp1 * DD + d];
    float mnew = fmaxf(m_run, fmaxf(ar0, ar1));
    float rold = exp2f(m_run - mnew);
    float w0 = exp2f(ar0 - mnew), w1 = exp2f(ar1 - mnew);
    acc = fmaf(w1, x1, fmaf(w0, x0, acc * rold));
    wsum = fmaf(w0 + w1, 1.f, wsum * rold);
    m_run = mnew;
  }
  if (j < deg) {
    int pos = o0 + j;
    int sp = csr_src[pos];
    int ei = csr_eid[pos];
    float ar = asrc[sp * NH + h] + adh + araw[(size_t)ei * NH + h];
    ar = ((ar > 0.f) ? ar : SLOPE * ar) * LOG2E;
    float xv = (float)xh16[(size_t)sp * DD + d];
    float mnew = fmaxf(m_run, ar);
    float rold = exp2f(m_run - mnew);
    float w = exp2f(ar - mnew);
    acc = fmaf(w, xv, acc * rold);
    wsum = fmaf(w, 1.f, wsum * rold);
    m_run = mnew;
  }

  float val = acc / (wsum + 1e-16f) + cb[d];
  float m = val;
#pragma unroll
  for (int off = 32; off >= 1; off >>= 1) m += __shfl_xor(m, off, 64);
  m *= (1.f / 64.f);
  float c = val - m;
  float q = c * c;
#pragma unroll
  for (int off = 32; off >= 1; off >>= 1) q += __shfl_xor(q, off, 64);
  float rstd = 1.f / sqrtf(q * (1.f / 64.f) + 1e-5f);
  float y = c * rstd * g[d] + bln[d];
  y = fmaxf(y, 0.f);
  float out = y + nf[(size_t)t * DD + d];
  nf[(size_t)t * DD + d] = out;
  nf16[(size_t)t * DD + d] = (__bf16)out;
}

// ---------------- edge MLP v15: 64 edges / 4 waves / 256 thr (R18 best) ------
__global__ __launch_bounds__(256, 4) void k_edge_mlp15(
    const __bf16* __restrict__ nf16, __bf16* __restrict__ ef16,
    float* __restrict__ efout,
    const int* __restrict__ src, const int* __restrict__ dst,
    const __bf16* __restrict__ W1H, const float* __restrict__ b1,
    const float* __restrict__ g, const float* __restrict__ bg,
    const __bf16* __restrict__ W2H, const float* __restrict__ b2,
    const __bf16* __restrict__ W2VP, const __bf16* __restrict__ VP,
    const float* __restrict__ bvdot, float* __restrict__ araw, int last) {
  __shared__ __bf16 XH[EB * XSTR];    // 25600 B: X | H | f32 output funnel
  __shared__ __bf16 RESB[EB * RSTR];  //  8704 B: ef_old residual (survives H)
  __shared__ __bf16 Pb[EB * 8];       //  1024 B: LN partials; slot 0 -> (mean,rstd)
  int tid = threadIdx.x;
  int e0 = blockIdx.x * EB;
  float* XF = (float*)XH;             // funnel view (64*66*4 = 16896 B)

  {
    int row = tid >> 2, p = tid & 3;
    int se = src[e0 + row], de = dst[e0 + row];
    const bf8* psrc = (const bf8*)(nf16 + (size_t)se * DD + p * 16);
    *(bf8*)&XH[row * XSTR + p * 16]     = psrc[0];
    *(bf8*)&XH[row * XSTR + p * 16 + 8] = psrc[1];
    const bf8* pdst = (const bf8*)(nf16 + (size_t)de * DD + p * 16);
    *(bf8*)&XH[row * XSTR + 64 + p * 16]     = pdst[0];
    *(bf8*)&XH[row * XSTR + 64 + p * 16 + 8] = pdst[1];
    const bf8* pef = (const bf8*)(ef16 + (size_t)(e0 + row) * DD + p * 16);
    bf8 ev0 = pef[0], ev1 = pef[1];
    *(bf8*)&XH[row * XSTR + 128 + p * 16]     = ev0;
    *(bf8*)&XH[row * XSTR + 128 + p * 16 + 8] = ev1;
    *(bf8*)&RESB[row * RSTR + p * 16]     = ev0;
    *(bf8*)&RESB[row * RSTR + p * 16 + 8] = ev1;
  }
  __syncthreads();

  int cg = tid >> 6, l = tid & 63;
  int gq = l >> 4, i = l & 15;
  int col = cg * 16 + i;

  f32x4 acc[4][3];
#pragma unroll
  for (int rt = 0; rt < 4; ++rt)
#pragma unroll
    for (int t = 0; t < 3; ++t) acc[rt][t] = (f32x4){0.f, 0.f, 0.f, 0.f};
  f32x4 accP = (f32x4){0.f, 0.f, 0.f, 0.f};
  f32x4 accQ = (f32x4){0.f, 0.f, 0.f, 0.f};

#pragma unroll
  for (int s = 0; s < 6; ++s) {
    bf8 a[4];
#pragma unroll
    for (int rt = 0; rt < 4; ++rt)
      a[rt] = *(const bf8*)&XH[(rt * 16 + i) * XSTR + s * 32 + gq * 8];
#pragma unroll
    for (int t = 0; t < 3; ++t) {
      bf8 bh = *(const bf8*)(W1H + ((size_t)((cg * 3 + t) * 6 + s) * 64 + l) * 8);
#pragma unroll
      for (int rt = 0; rt < 4; ++rt) acc[rt][t] = MFMA(a[rt], bh, acc[rt][t]);
    }
    if (!last && s >= 4) {
      bf8 acg = *(const bf8*)&XH[(cg * 16 + i) * XSTR + s * 32 + gq * 8];
      bf8 vp = *(const bf8*)(VP + ((size_t)((s - 4) * 64 + l)) * 8);
      accP = MFMA(acg, vp, accP);
    }
  }

  float b1v[3], gv[3], bgv[3];
#pragma unroll
  for (int t = 0; t < 3; ++t) {
    int n = cg * 48 + t * 16 + i;
    b1v[t] = b1[n]; gv[t] = g[n]; bgv[t] = bg[n];
  }
#pragma unroll
  for (int rt = 0; rt < 4; ++rt)
#pragma unroll
    for (int t = 0; t < 3; ++t)
#pragma unroll
      for (int r = 0; r < 4; ++r) acc[rt][t][r] += b1v[t];

#pragma unroll
  for (int rt = 0; rt < 4; ++rt)
#pragma unroll
    for (int r = 0; r < 4; ++r) {
      float sm = 0.f, sq = 0.f;
#pragma unroll
      for (int t = 0; t < 3; ++t) { float x = acc[rt][t][r]; sm += x; sq = fmaf(x, x, sq); }
#pragma unroll
      for (int off = 1; off <= 8; off <<= 1) {
        sm += __shfl_xor(sm, off, 64);
        sq += __shfl_xor(sq, off, 64);
      }
      if (i == 0) {
        int row = rt * 16 + gq * 4 + r;
        bf2 pr; pr[0] = (__bf16)sm; pr[1] = (__bf16)sq;
        *(bf2*)&Pb[row * 8 + cg * 2] = pr;
      }
    }
  __syncthreads();   // barrier 1

  if (tid < EB) {
    bf8 pv = *(const bf8*)&Pb[tid * 8];
    float sm = (float)pv[0] + (float)pv[2] + (float)pv[4] + (float)pv[6];
    float sq = (float)pv[1] + (float)pv[3] + (float)pv[5] + (float)pv[7];
    float mean = sm * (1.f / (float)DIN);
    float var = sq * (1.f / (float)DIN) - mean * mean;
    float rstd = 1.f / sqrtf(var + 1e-5f);
    bf2 mv; mv[0] = (__bf16)mean; mv[1] = (__bf16)rstd;
    *(bf2*)&Pb[tid * 8] = mv;
  }
  __syncthreads();   // barrier 2

#pragma unroll
  for (int rt = 0; rt < 4; ++rt)
#pragma unroll
    for (int r = 0; r < 4; ++r) {
      int row = rt * 16 + gq * 4 + r;
      bf2 mv = *(const bf2*)&Pb[row * 8];
      float mean = (float)mv[0], rstd = (float)mv[1];
#pragma unroll
      for (int t = 0; t < 3; ++t) {
        float y = (acc[rt][t][r] - mean) * rstd * gv[t] + bgv[t];
        y = fmaxf(y, 0.f);
        XH[row * XSTR + cg * 48 + t * 16 + i] = (__bf16)y;
      }
    }
  __syncthreads();   // barrier 3

  f32x4 acc2[4];
#pragma unroll
  for (int rt = 0; rt < 4; ++rt) acc2[rt] = (f32x4){0.f, 0.f, 0.f, 0.f};

#pragma unroll
  for (int s = 0; s < 6; ++s) {
    bf8 a2[4];
#pragma unroll
    for (int rt = 0; rt < 4; ++rt)
      a2[rt] = *(const bf8*)&XH[(rt * 16 + i) * XSTR + s * 32 + gq * 8];
    bf8 bh = *(const bf8*)(W2H + ((size_t)(cg * 6 + s) * 64 + l) * 8);
#pragma unroll
    for (int rt = 0; rt < 4; ++rt) acc2[rt] = MFMA(a2[rt], bh, acc2[rt]);
    if (!last) {
      bf8 acg = *(const bf8*)&XH[(cg * 16 + i) * XSTR + s * 32 + gq * 8];
      bf8 wv = *(const bf8*)(W2VP + ((size_t)(s * 64 + l)) * 8);
      accQ = MFMA(acg, wv, accQ);
    }
  }
  __syncthreads();   // barrier 4

  float b2v = b2[col];
#pragma unroll
  for (int rt = 0; rt < 4; ++rt)
#pragma unroll
    for (int r = 0; r < 4; ++r) {
      int row = rt * 16 + gq * 4 + r;
      float resv = (float)RESB[row * RSTR + col];
      XF[row * FSTR + col] = acc2[rt][r] + b2v + resv;
    }

  if (!last && i < 4) {
    float bvd = bvdot[i];
#pragma unroll
    for (int r = 0; r < 4; ++r) {
      int row = cg * 16 + gq * 4 + r;
      araw[(size_t)(e0 + row) * NH + i] = accP[r] + accQ[r] + bvd;
    }
  }
  __syncthreads();   // barrier 5

  {
    int row = tid >> 2, q = tid & 3;
    const float* fr = &XF[row * FSTR + q * 16];
    if (last) {
      float* op = efout + (size_t)(e0 + row) * DD + q * 16;
#pragma unroll
      for (int k = 0; k < 4; ++k)
        *(float4*)(op + k * 4) = *(const float4*)(fr + k * 4);
    } else {
      bf8 o0, o1;
#pragma unroll
      for (int k = 0; k < 8; ++k) { o0[k] = (__bf16)fr[k]; o1[k] = (__bf16)fr[k + 8]; }
      __bf16* op = ef16 + (size_t)(e0 + row) * DD + q * 16;
      *(bf8*)op = o0;
      *(bf8*)(op + 8) = o1;
    }
  }
}

extern "C" void kernel_launch(void* const* d_in, const int* in_sizes, int n_in,
                              void* d_out, int out_size, void* d_ws, size_t ws_size,
                              hipStream_t stream) {
  const float* node_feats = (const float*)d_in[0];
  const float* edge_feats = (const float*)d_in[1];
  const int*   edge_index = (const int*)d_in[2];
  const float* conv_w  = (const float*)d_in[3];
  const float* att_src = (const float*)d_in[4];
  const float* att_dst = (const float*)d_in[5];
  const float* edge_w  = (const float*)d_in[6];
  const float* att_edge= (const float*)d_in[7];
  const float* conv_b  = (const float*)d_in[8];
  const float* ln_g    = (const float*)d_in[9];
  const float* ln_b    = (const float*)d_in[10];
  const float* up1_w   = (const float*)d_in[11];
  const float* up1_b   = (const float*)d_in[12];
  const float* up_ln_g = (const float*)d_in[13];
  const float* up_ln_b = (const float*)d_in[14];
  const float* up2_w   = (const float*)d_in[15];
  const float* up2_b   = (const float*)d_in[16];

  const int* src = edge_index;
  const int* dst = edge_index + NE;

  float* nf = (float*)d_out;
  float* efout = nf + (size_t)NN * DD;

  float* w = (float*)d_ws;
  __bf16* xh16 = (__bf16*)w; w += (size_t)NN * DD / 2;
  __bf16* nf16 = (__bf16*)w; w += (size_t)NN * DD / 2;
  __bf16* ef16 = (__bf16*)w; w += (size_t)NE * DD / 2;
  float* asrc  = w; w += (size_t)NN * NH;
  float* adst  = w; w += (size_t)NN * NH;
  float* araw  = w; w += (size_t)NE * NH;
  float* vbuf  = w; w += 4 * 256;
  float* bvdot = w; w += 16;
  __bf16* W1H  = (__bf16*)w; w += (size_t)4 * 36864 / 2;
  __bf16* W2H  = (__bf16*)w; w += (size_t)4 * 12288 / 2;
  __bf16* W2VP = (__bf16*)w; w += (size_t)3 * 3072 / 2;
  __bf16* VPb  = (__bf16*)w; w += (size_t)3 * 1024 / 2;
  int* deg     = (int*)w; w += NN;
  int* offs    = (int*)w; w += NN + 1;
  int* cursor  = (int*)w; w += NN;
  int* bsum    = (int*)w; w += 128;
  int* boff    = (int*)w; w += 128;
  int* csr_src = (int*)w; w += NE;
  int* csr_eid = (int*)w; w += NE;

  k_init_nf<<<(NN * DD + 255) / 256, 256, 0, stream>>>(node_feats, nf);
  k_pack_w1<<<72, 256, 0, stream>>>(up1_w, W1H);
  k_pack_w2<<<24, 256, 0, stream>>>(up2_w, W2H);

  const int nb = (NN + 1023) / 1024;
  k_zero<<<(NN + 255) / 256, 256, 0, stream>>>(deg);
  k_hist<<<(NE + 255) / 256, 256, 0, stream>>>(dst, deg);
  k_scan1<<<nb, 256, 0, stream>>>(deg, offs, bsum);
  k_scan2<<<1, 64, 0, stream>>>(bsum, boff, offs, nb);
  k_scan3<<<(NN + 255) / 256, 256, 0, stream>>>(offs, boff, cursor);
  k_scatter<<<(NE + 255) / 256, 256, 0, stream>>>(src, dst, cursor, csr_src, csr_eid);

  k_v_all<<<4, 256, 0, stream>>>(edge_w, att_edge, vbuf);
  k_w2v<<<3, 384, 0, stream>>>(up2_w, up2_b, vbuf, W2VP, VPb, bvdot);
  k_pass1f<<<NE / 64, 256, 0, stream>>>(edge_feats, vbuf, ef16, araw);

  for (int l = 0; l < NL; ++l) {
    int last = (l == NL - 1) ? 1 : 0;
    k_xh<<<NN / 4, 256, 0, stream>>>(nf, conv_w + (size_t)l * DD * DD,
                                     att_src + (size_t)l * NH * NC,
                                     att_dst + (size_t)l * NH * NC, xh16, asrc, adst);
    k_gather3<<<NN / 4, 256, 0, stream>>>(xh16, araw, csr_src, csr_eid, offs,
                                          asrc, adst,
                                          conv_b + (size_t)l * DD,
                                          ln_g + (size_t)l * DD,
                                          ln_b + (size_t)l * DD, nf, nf16);
    k_edge_mlp15<<<NE / EB, 256, 0, stream>>>(
        nf16, ef16, efout, src, dst,
        W1H + (size_t)l * 36864, up1_b + (size_t)l * DIN,
        up_ln_g + (size_t)l * DIN, up_ln_b + (size_t)l * DIN,
        W2H + (size_t)l * 12288, up2_b + (size_t)l * DD,
        last ? W2VP : (W2VP + (size_t)l * 3072),
        last ? VPb : (VPb + (size_t)l * 1024),
        bvdot + (size_t)l * 4, araw, last);
  }
}

// Round 20
// 2643.135 us; speedup vs baseline: 1.7142x; 1.0551x over previous
//
#include <hip/hip_runtime.h>
#include <math.h>

#define NN 100000
#define NE 1600000
#define DD 64
#define NL 4
#define NH 4
#define NC 16
#define DIN 192
#define SLOPE 0.2f
#define EB 64
#define XSTR 200
#define FSTR 66
#define RSTR 68
#define LOG2E 1.44269504088896340736f

typedef __bf16 bf8 __attribute__((ext_vector_type(8)));
typedef __bf16 bf4 __attribute__((ext_vector_type(4)));
typedef __bf16 bf2 __attribute__((ext_vector_type(2)));
typedef float f32x4 __attribute__((ext_vector_type(4)));

__device__ __forceinline__ f32x4 MFMA(bf8 a, bf8 b, f32x4 c) {
  return __builtin_amdgcn_mfma_f32_16x16x32_bf16(a, b, c, 0, 0, 0);
}

// ---------------- weight packing: single bf16 plane, 1KB tiles ----------------
__global__ void k_pack_w1(const float* __restrict__ W1, __bf16* __restrict__ WH) {
  int gidx = blockIdx.x * 256 + threadIdx.x;
  if (gidx >= 4 * 4608) return;
  int lyr = gidx / 4608, rem = gidx % 4608;
  int lane = rem & 63, ts = rem >> 6;
  int s = ts % 6, t = ts / 6;
  const float* Wl = W1 + (size_t)lyr * DIN * DIN;
  size_t base = (size_t)lyr * 36864 + ((size_t)(t * 6 + s) * 64 + lane) * 8;
  int k0 = s * 32 + (lane >> 4) * 8, n = t * 16 + (lane & 15);
#pragma unroll
  for (int j = 0; j < 8; ++j)
    WH[base + j] = (__bf16)Wl[(size_t)(k0 + j) * DIN + n];
}

__global__ void k_pack_w2(const float* __restrict__ W2, __bf16* __restrict__ WH) {
  int gidx = blockIdx.x * 256 + threadIdx.x;
  if (gidx >= 4 * 1536) return;
  int lyr = gidx / 1536, rem = gidx % 1536;
  int lane = rem & 63, ts = rem >> 6;
  int s = ts % 6, t = ts / 6;
  const float* Wl = W2 + (size_t)lyr * DIN * DD;
  size_t base = (size_t)lyr * 12288 + ((size_t)(t * 6 + s) * 64 + lane) * 8;
  int k0 = s * 32 + (lane >> 4) * 8, n = t * 16 + (lane & 15);
#pragma unroll
  for (int j = 0; j < 8; ++j)
    WH[base + j] = (__bf16)Wl[(size_t)(k0 + j) * DD + n];
}

// W2VP[l] = W2_l @ v_{l+1}; VP[l] = v_{l+1}; bvdot[l][h] = b2_l . v_{l+1}[:,h]
__global__ void k_w2v(const float* __restrict__ up2_w, const float* __restrict__ up2_b,
                      const float* __restrict__ vbuf, __bf16* __restrict__ W2VP,
                      __bf16* __restrict__ VP, float* __restrict__ bvdot) {
  int l = blockIdx.x;
  const float* vn = vbuf + (l + 1) * 256;
  int t = threadIdx.x;
  if (t < 384) {
    int s = t >> 6, lane = t & 63;
    int i = lane & 15, k0 = s * 32 + (lane >> 4) * 8;
    const float* W2 = up2_w + (size_t)l * DIN * DD;
    __bf16* out = W2VP + (size_t)l * 3072 + ((size_t)(s * 64 + lane)) * 8;
#pragma unroll
    for (int j = 0; j < 8; ++j) {
      float val = 0.f;
      if (i < 4)
        for (int n = 0; n < DD; ++n)
          val = fmaf(W2[(size_t)(k0 + j) * DD + n], vn[n * NH + i], val);
      out[j] = (__bf16)val;
    }
  }
  if (t < 128) {
    int s2 = t >> 6, lane = t & 63;
    int i = lane & 15, k0 = s2 * 32 + (lane >> 4) * 8;
    __bf16* out = VP + (size_t)l * 1024 + ((size_t)(s2 * 64 + lane)) * 8;
#pragma unroll
    for (int j = 0; j < 8; ++j)
      out[j] = (i < 4) ? (__bf16)vn[(k0 + j) * NH + i] : (__bf16)0.f;
  }
  if (t < 4) {
    const float* b2 = up2_b + (size_t)l * DD;
    float bv = 0.f;
    for (int n = 0; n < DD; ++n) bv = fmaf(b2[n], vn[n * NH + t], bv);
    bvdot[l * 4 + t] = bv;
  }
}

// ---------------- CSR build ----------------
__global__ void k_zero(int* __restrict__ deg) {
  int i = blockIdx.x * 256 + threadIdx.x;
  if (i < NN) deg[i] = 0;
}

__global__ void k_hist(const int* __restrict__ dst, int* __restrict__ deg) {
  int e = blockIdx.x * 256 + threadIdx.x;
  if (e < NE) atomicAdd(&deg[dst[e]], 1);
}

__global__ void k_scan1(const int* __restrict__ deg, int* __restrict__ offs,
                        int* __restrict__ bsum) {
  __shared__ int sh[256];
  int t = threadIdx.x, b = blockIdx.x;
  int i0 = b * 1024 + t * 4;
  int d0 = (i0 + 0 < NN) ? deg[i0 + 0] : 0;
  int d1 = (i0 + 1 < NN) ? deg[i0 + 1] : 0;
  int d2 = (i0 + 2 < NN) ? deg[i0 + 2] : 0;
  int d3 = (i0 + 3 < NN) ? deg[i0 + 3] : 0;
  int s4 = d0 + d1 + d2 + d3;
  sh[t] = s4;
  __syncthreads();
  int p = 0;
#pragma unroll
  for (int off = 1; off < 256; off <<= 1) {
    int v = (t >= off) ? sh[t - off] : 0;
    __syncthreads();
    sh[t] += v;
    __syncthreads();
  }
  p = sh[t] - s4;
  if (t == 255) bsum[b] = sh[255];
  if (i0 + 0 < NN) offs[i0 + 0] = p;
  if (i0 + 1 < NN) offs[i0 + 1] = p + d0;
  if (i0 + 2 < NN) offs[i0 + 2] = p + d0 + d1;
  if (i0 + 3 < NN) offs[i0 + 3] = p + d0 + d1 + d2;
}

__global__ void k_scan2(int* __restrict__ bsum, int* __restrict__ boff,
                        int* __restrict__ offs, int nb) {
  if (threadIdx.x == 0 && blockIdx.x == 0) {
    int run = 0;
    for (int k = 0; k < nb; ++k) { boff[k] = run; run += bsum[k]; }
    offs[NN] = NE;
  }
}

__global__ void k_scan3(int* __restrict__ offs, const int* __restrict__ boff,
                        int* __restrict__ cursor) {
  int i = blockIdx.x * 256 + threadIdx.x;
  if (i < NN) {
    int v = offs[i] + boff[i >> 10];
    offs[i] = v;
    cursor[i] = v;
  }
}

__global__ void k_scatter(const int* __restrict__ src, const int* __restrict__ dst,
                          int* __restrict__ cursor, int* __restrict__ csr_src,
                          int* __restrict__ csr_eid) {
  int e = blockIdx.x * 256 + threadIdx.x;
  if (e >= NE) return;
  int pos = atomicAdd(&cursor[dst[e]], 1);
  csr_src[pos] = src[e];
  csr_eid[pos] = e;
}

// ---------------- upfront precomputes ----------------
__global__ void k_v_all(const float* __restrict__ ew_all, const float* __restrict__ ae_all,
                        float* __restrict__ vbuf) {
  int l = blockIdx.x;
  const float* ew = ew_all + (size_t)l * DD * DD;
  const float* ae = ae_all + (size_t)l * NH * NC;
  int d = threadIdx.x >> 2, h = threadIdx.x & 3;
  float s = 0.f;
#pragma unroll
  for (int c = 0; c < NC; ++c) s = fmaf(ew[d * DD + h * NC + c], ae[h * NC + c], s);
  vbuf[l * 256 + d * NH + h] = s;
}

// layer-0 xh from node_feats; also emits nf16 carry
__global__ void k_xh0(const float* __restrict__ node_feats, const float* __restrict__ W,
                      const float* __restrict__ as_, const float* __restrict__ ad_,
                      __bf16* __restrict__ nf16, __bf16* __restrict__ xh16,
                      float* __restrict__ asrc, float* __restrict__ adst) {
  int t = blockIdx.x * 4 + (threadIdx.x >> 6);
  int d = threadIdx.x & 63;
  if (t >= NN) return;
  const float* x = node_feats + (size_t)t * DD;
  nf16[(size_t)t * DD + d] = (__bf16)x[d];
  float acc = 0.f;
#pragma unroll
  for (int k = 0; k < DD; ++k) acc = fmaf(x[k], W[k * DD + d], acc);
  xh16[(size_t)t * DD + d] = (__bf16)acc;
  int h = d >> 4, c = d & 15;
  float ps = acc * as_[h * NC + c];
  float pd = acc * ad_[h * NC + c];
#pragma unroll
  for (int off = 8; off >= 1; off >>= 1) {
    ps += __shfl_xor(ps, off, 64);
    pd += __shfl_xor(pd, off, 64);
  }
  if (c == 0) { asrc[t * NH + h] = ps; adst[t * NH + h] = pd; }
}

// layer-0: edge_feats -> ef16 + RAW pe into araw[e] (both coalesced)
__global__ void k_pass1f(const float* __restrict__ edge_feats,
                         const float* __restrict__ v,
                         __bf16* __restrict__ ef16, float* __restrict__ araw) {
  int e = blockIdx.x * 64 + (threadIdx.x >> 2);
  int part = threadIdx.x & 3;
  if (e >= NE) return;
  float ph0 = 0.f, ph1 = 0.f, ph2 = 0.f, ph3 = 0.f;
  const float4* ep = (const float4*)(edge_feats + (size_t)e * DD + part * 16);
  const float4* v4 = (const float4*)v;
  bf4 outv[4];
#pragma unroll
  for (int c4 = 0; c4 < 4; ++c4) {
    float4 x = ep[c4];
    outv[c4][0] = (__bf16)x.x; outv[c4][1] = (__bf16)x.y;
    outv[c4][2] = (__bf16)x.z; outv[c4][3] = (__bf16)x.w;
    int d0 = part * 16 + c4 * 4;
    float4 va = v4[d0], vb = v4[d0 + 1], vc = v4[d0 + 2], vd = v4[d0 + 3];
    ph0 = fmaf(x.x, va.x, fmaf(x.y, vb.x, fmaf(x.z, vc.x, fmaf(x.w, vd.x, ph0))));
    ph1 = fmaf(x.x, va.y, fmaf(x.y, vb.y, fmaf(x.z, vc.y, fmaf(x.w, vd.y, ph1))));
    ph2 = fmaf(x.x, va.z, fmaf(x.y, vb.z, fmaf(x.z, vc.z, fmaf(x.w, vd.z, ph2))));
    ph3 = fmaf(x.x, va.w, fmaf(x.y, vb.w, fmaf(x.z, vc.w, fmaf(x.w, vd.w, ph3))));
  }
  *(bf8*)&ef16[(size_t)e * DD + part * 16] =
      (bf8){outv[0][0], outv[0][1], outv[0][2], outv[0][3],
            outv[1][0], outv[1][1], outv[1][2], outv[1][3]};
  *(bf8*)&ef16[(size_t)e * DD + part * 16 + 8] =
      (bf8){outv[2][0], outv[2][1], outv[2][2], outv[2][3],
            outv[3][0], outv[3][1], outv[3][2], outv[3][3]};
#pragma unroll
  for (int off = 1; off <= 2; off <<= 1) {
    ph0 += __shfl_xor(ph0, off, 64);
    ph1 += __shfl_xor(ph1, off, 64);
    ph2 += __shfl_xor(ph2, off, 64);
    ph3 += __shfl_xor(ph3, off, 64);
  }
  float pe = (part == 0) ? ph0 : (part == 1) ? ph1 : (part == 2) ? ph2 : ph3;
  araw[(size_t)e * NH + part] = pe;
}

// gather v4: online softmax + fused next-layer xh (64-shfl matvec epilogue)
__global__ __launch_bounds__(256) void k_gather4(
    const __bf16* __restrict__ xh16, const float* __restrict__ araw,
    const int* __restrict__ csr_src, const int* __restrict__ csr_eid,
    const int* __restrict__ offs,
    const float* __restrict__ asrc, const float* __restrict__ adst,
    const float* __restrict__ cb, const float* __restrict__ g,
    const float* __restrict__ bln, __bf16* __restrict__ nf16,
    float* __restrict__ nfout,
    const float* __restrict__ Wn, const float* __restrict__ asn,
    const float* __restrict__ adn, __bf16* __restrict__ xh16n,
    float* __restrict__ asrcn, float* __restrict__ adstn, int last) {
  int t = blockIdx.x * 4 + (threadIdx.x >> 6);
  int d = threadIdx.x & 63;
  if (t >= NN) return;
  int h = d >> 4;
  int o0 = offs[t], o1 = offs[t + 1];
  int deg = o1 - o0;
  float adh = adst[t * NH + h];

  // seed with self-loop (edge attr = 0)
  float sh = asrc[t * NH + h] + adh;
  sh = ((sh > 0.f) ? sh : SLOPE * sh) * LOG2E;
  float m_run = sh;
  float wsum = 1.f;
  float acc = (float)xh16[(size_t)t * DD + d];

  int j = 0;
  for (; j + 1 < deg; j += 2) {
    int pos0 = o0 + j, pos1 = o0 + j + 1;
    int sp0 = csr_src[pos0], sp1 = csr_src[pos1];
    int e0i = csr_eid[pos0], e1i = csr_eid[pos1];
    float ar0 = asrc[sp0 * NH + h] + adh + araw[(size_t)e0i * NH + h];
    float ar1 = asrc[sp1 * NH + h] + adh + araw[(size_t)e1i * NH + h];
    ar0 = ((ar0 > 0.f) ? ar0 : SLOPE * ar0) * LOG2E;
    ar1 = ((ar1 > 0.f) ? ar1 : SLOPE * ar1) * LOG2E;
    float x0 = (float)xh16[(size_t)sp0 * DD + d];
    float x1 = (float)xh16[(size_t)sp1 * DD + d];
    float mnew = fmaxf(m_run, fmaxf(ar0, ar1));
    float rold = exp2f(m_run - mnew);
    float w0 = exp2f(ar0 - mnew), w1 = exp2f(ar1 - mnew);
    acc = fmaf(w1, x1, fmaf(w0, x0, acc * rold));
    wsum = fmaf(w0 + w1, 1.f, wsum * rold);
    m_run = mnew;
  }
  if (j < deg) {
    int pos = o0 + j;
    int sp = csr_src[pos];
    int ei = csr_eid[pos];
    float ar = asrc[sp * NH + h] + adh + araw[(size_t)ei * NH + h];
    ar = ((ar > 0.f) ? ar : SLOPE * ar) * LOG2E;
    float xv = (float)xh16[(size_t)sp * DD + d];
    float mnew = fmaxf(m_run, ar);
    float rold = exp2f(m_run - mnew);
    float w = exp2f(ar - mnew);
    acc = fmaf(w, xv, acc * rold);
    wsum = fmaf(w, 1.f, wsum * rold);
    m_run = mnew;
  }

  float val = acc / (wsum + 1e-16f) + cb[d];
  float m = val;
#pragma unroll
  for (int off = 32; off >= 1; off >>= 1) m += __shfl_xor(m, off, 64);
  m *= (1.f / 64.f);
  float c = val - m;
  float q = c * c;
#pragma unroll
  for (int off = 32; off >= 1; off >>= 1) q += __shfl_xor(q, off, 64);
  float rstd = 1.f / sqrtf(q * (1.f / 64.f) + 1e-5f);
  float y = c * rstd * g[d] + bln[d];
  y = fmaxf(y, 0.f);
  float out = y + (float)nf16[(size_t)t * DD + d];
  nf16[(size_t)t * DD + d] = (__bf16)out;

  if (last) {
    nfout[(size_t)t * DD + d] = out;
  } else {
    // fused next-layer xh: wave holds the full row (lane k = dim k)
    float acc2 = 0.f;
#pragma unroll 8
    for (int k = 0; k < DD; ++k) {
      float xk = __shfl(out, k, 64);
      acc2 = fmaf(xk, Wn[k * DD + d], acc2);
    }
    xh16n[(size_t)t * DD + d] = (__bf16)acc2;
    int cc = d & 15;
    float ps = acc2 * asn[h * NC + cc];
    float pd = acc2 * adn[h * NC + cc];
#pragma unroll
    for (int off = 8; off >= 1; off >>= 1) {
      ps += __shfl_xor(ps, off, 64);
      pd += __shfl_xor(pd, off, 64);
    }
    if (cc == 0) { asrcn[t * NH + h] = ps; adstn[t * NH + h] = pd; }
  }
}

// ---------------- edge MLP v15: 64 edges / 4 waves / 256 thr (R18 best) ------
__global__ __launch_bounds__(256, 4) void k_edge_mlp15(
    const __bf16* __restrict__ nf16, __bf16* __restrict__ ef16,
    float* __restrict__ efout,
    const int* __restrict__ src, const int* __restrict__ dst,
    const __bf16* __restrict__ W1H, const float* __restrict__ b1,
    const float* __restrict__ g, const float* __restrict__ bg,
    const __bf16* __restrict__ W2H, const float* __restrict__ b2,
    const __bf16* __restrict__ W2VP, const __bf16* __restrict__ VP,
    const float* __restrict__ bvdot, float* __restrict__ araw, int last) {
  __shared__ __bf16 XH[EB * XSTR];
  __shared__ __bf16 RESB[EB * RSTR];
  __shared__ __bf16 Pb[EB * 8];
  int tid = threadIdx.x;
  int e0 = blockIdx.x * EB;
  float* XF = (float*)XH;

  {
    int row = tid >> 2, p = tid & 3;
    int se = src[e0 + row], de = dst[e0 + row];
    const bf8* psrc = (const bf8*)(nf16 + (size_t)se * DD + p * 16);
    *(bf8*)&XH[row * XSTR + p * 16]     = psrc[0];
    *(bf8*)&XH[row * XSTR + p * 16 + 8] = psrc[1];
    const bf8* pdst = (const bf8*)(nf16 + (size_t)de * DD + p * 16);
    *(bf8*)&XH[row * XSTR + 64 + p * 16]     = pdst[0];
    *(bf8*)&XH[row * XSTR + 64 + p * 16 + 8] = pdst[1];
    const bf8* pef = (const bf8*)(ef16 + (size_t)(e0 + row) * DD + p * 16);
    bf8 ev0 = pef[0], ev1 = pef[1];
    *(bf8*)&XH[row * XSTR + 128 + p * 16]     = ev0;
    *(bf8*)&XH[row * XSTR + 128 + p * 16 + 8] = ev1;
    *(bf8*)&RESB[row * RSTR + p * 16]     = ev0;
    *(bf8*)&RESB[row * RSTR + p * 16 + 8] = ev1;
  }
  __syncthreads();

  int cg = tid >> 6, l = tid & 63;
  int gq = l >> 4, i = l & 15;
  int col = cg * 16 + i;

  f32x4 acc[4][3];
#pragma unroll
  for (int rt = 0; rt < 4; ++rt)
#pragma unroll
    for (int t = 0; t < 3; ++t) acc[rt][t] = (f32x4){0.f, 0.f, 0.f, 0.f};
  f32x4 accP = (f32x4){0.f, 0.f, 0.f, 0.f};
  f32x4 accQ = (f32x4){0.f, 0.f, 0.f, 0.f};

#pragma unroll
  for (int s = 0; s < 6; ++s) {
    bf8 a[4];
#pragma unroll
    for (int rt = 0; rt < 4; ++rt)
      a[rt] = *(const bf8*)&XH[(rt * 16 + i) * XSTR + s * 32 + gq * 8];
#pragma unroll
    for (int t = 0; t < 3; ++t) {
      bf8 bh = *(const bf8*)(W1H + ((size_t)((cg * 3 + t) * 6 + s) * 64 + l) * 8);
#pragma unroll
      for (int rt = 0; rt < 4; ++rt) acc[rt][t] = MFMA(a[rt], bh, acc[rt][t]);
    }
    if (!last && s >= 4) {
      bf8 acg = *(const bf8*)&XH[(cg * 16 + i) * XSTR + s * 32 + gq * 8];
      bf8 vp = *(const bf8*)(VP + ((size_t)((s - 4) * 64 + l)) * 8);
      accP = MFMA(acg, vp, accP);
    }
  }

  float b1v[3], gv[3], bgv[3];
#pragma unroll
  for (int t = 0; t < 3; ++t) {
    int n = cg * 48 + t * 16 + i;
    b1v[t] = b1[n]; gv[t] = g[n]; bgv[t] = bg[n];
  }
#pragma unroll
  for (int rt = 0; rt < 4; ++rt)
#pragma unroll
    for (int t = 0; t < 3; ++t)
#pragma unroll
      for (int r = 0; r < 4; ++r) acc[rt][t][r] += b1v[t];

#pragma unroll
  for (int rt = 0; rt < 4; ++rt)
#pragma unroll
    for (int r = 0; r < 4; ++r) {
      float sm = 0.f, sq = 0.f;
#pragma unroll
      for (int t = 0; t < 3; ++t) { float x = acc[rt][t][r]; sm += x; sq = fmaf(x, x, sq); }
#pragma unroll
      for (int off = 1; off <= 8; off <<= 1) {
        sm += __shfl_xor(sm, off, 64);
        sq += __shfl_xor(sq, off, 64);
      }
      if (i == 0) {
        int row = rt * 16 + gq * 4 + r;
        bf2 pr; pr[0] = (__bf16)sm; pr[1] = (__bf16)sq;
        *(bf2*)&Pb[row * 8 + cg * 2] = pr;
      }
    }
  __syncthreads();   // barrier 1

  if (tid < EB) {
    bf8 pv = *(const bf8*)&Pb[tid * 8];
    float sm = (float)pv[0] + (float)pv[2] + (float)pv[4] + (float)pv[6];
    float sq = (float)pv[1] + (float)pv[3] + (float)pv[5] + (float)pv[7];
    float mean = sm * (1.f / (float)DIN);
    float var = sq * (1.f / (float)DIN) - mean * mean;
    float rstd = 1.f / sqrtf(var + 1e-5f);
    bf2 mv; mv[0] = (__bf16)mean; mv[1] = (__bf16)rstd;
    *(bf2*)&Pb[tid * 8] = mv;
  }
  __syncthreads();   // barrier 2

#pragma unroll
  for (int rt = 0; rt < 4; ++rt)
#pragma unroll
    for (int r = 0; r < 4; ++r) {
      int row = rt * 16 + gq * 4 + r;
      bf2 mv = *(const bf2*)&Pb[row * 8];
      float mean = (float)mv[0], rstd = (float)mv[1];
#pragma unroll
      for (int t = 0; t < 3; ++t) {
        float y = (acc[rt][t][r] - mean) * rstd * gv[t] + bgv[t];
        y = fmaxf(y, 0.f);
        XH[row * XSTR + cg * 48 + t * 16 + i] = (__bf16)y;
      }
    }
  __syncthreads();   // barrier 3

  f32x4 acc2[4];
#pragma unroll
  for (int rt = 0; rt < 4; ++rt) acc2[rt] = (f32x4){0.f, 0.f, 0.f, 0.f};

#pragma unroll
  for (int s = 0; s < 6; ++s) {
    bf8 a2[4];
#pragma unroll
    for (int rt = 0; rt < 4; ++rt)
      a2[rt] = *(const bf8*)&XH[(rt * 16 + i) * XSTR + s * 32 + gq * 8];
    bf8 bh = *(const bf8*)(W2H + ((size_t)(cg * 6 + s) * 64 + l) * 8);
#pragma unroll
    for (int rt = 0; rt < 4; ++rt) acc2[rt] = MFMA(a2[rt], bh, acc2[rt]);
    if (!last) {
      bf8 acg = *(const bf8*)&XH[(cg * 16 + i) * XSTR + s * 32 + gq * 8];
      bf8 wv = *(const bf8*)(W2VP + ((size_t)(s * 64 + l)) * 8);
      accQ = MFMA(acg, wv, accQ);
    }
  }
  __syncthreads();   // barrier 4

  float b2v = b2[col];
#pragma unroll
  for (int rt = 0; rt < 4; ++rt)
#pragma unroll
    for (int r = 0; r < 4; ++r) {
      int row = rt * 16 + gq * 4 + r;
      float resv = (float)RESB[row * RSTR + col];
      XF[row * FSTR + col] = acc2[rt][r] + b2v + resv;
    }

  if (!last && i < 4) {
    float bvd = bvdot[i];
#pragma unroll
    for (int r = 0; r < 4; ++r) {
      int row = cg * 16 + gq * 4 + r;
      araw[(size_t)(e0 + row) * NH + i] = accP[r] + accQ[r] + bvd;
    }
  }
  __syncthreads();   // barrier 5

  {
    int row = tid >> 2, q = tid & 3;
    const float* fr = &XF[row * FSTR + q * 16];
    if (last) {
      float* op = efout + (size_t)(e0 + row) * DD + q * 16;
#pragma unroll
      for (int k = 0; k < 4; ++k)
        *(float4*)(op + k * 4) = *(const float4*)(fr + k * 4);
    } else {
      bf8 o0, o1;
#pragma unroll
      for (int k = 0; k < 8; ++k) { o0[k] = (__bf16)fr[k]; o1[k] = (__bf16)fr[k + 8]; }
      __bf16* op = ef16 + (size_t)(e0 + row) * DD + q * 16;
      *(bf8*)op = o0;
      *(bf8*)(op + 8) = o1;
    }
  }
}

extern "C" void kernel_launch(void* const* d_in, const int* in_sizes, int n_in,
                              void* d_out, int out_size, void* d_ws, size_t ws_size,
                              hipStream_t stream) {
  const float* node_feats = (const float*)d_in[0];
  const float* edge_feats = (const float*)d_in[1];
  const int*   edge_index = (const int*)d_in[2];
  const float* conv_w  = (const float*)d_in[3];
  const float* att_src = (const float*)d_in[4];
  const float* att_dst = (const float*)d_in[5];
  const float* edge_w  = (const float*)d_in[6];
  const float* att_edge= (const float*)d_in[7];
  const float* conv_b  = (const float*)d_in[8];
  const float* ln_g    = (const float*)d_in[9];
  const float* ln_b    = (const float*)d_in[10];
  const float* up1_w   = (const float*)d_in[11];
  const float* up1_b   = (const float*)d_in[12];
  const float* up_ln_g = (const float*)d_in[13];
  const float* up_ln_b = (const float*)d_in[14];
  const float* up2_w   = (const float*)d_in[15];
  const float* up2_b   = (const float*)d_in[16];

  const int* src = edge_index;
  const int* dst = edge_index + NE;

  float* nf = (float*)d_out;
  float* efout = nf + (size_t)NN * DD;

  float* w = (float*)d_ws;
  __bf16* xh16a = (__bf16*)w; w += (size_t)NN * DD / 2;
  __bf16* xh16b = (__bf16*)w; w += (size_t)NN * DD / 2;
  __bf16* nf16 = (__bf16*)w; w += (size_t)NN * DD / 2;
  __bf16* ef16 = (__bf16*)w; w += (size_t)NE * DD / 2;
  float* asA   = w; w += (size_t)NN * NH;
  float* adA   = w; w += (size_t)NN * NH;
  float* asB   = w; w += (size_t)NN * NH;
  float* adB   = w; w += (size_t)NN * NH;
  float* araw  = w; w += (size_t)NE * NH;
  float* vbuf  = w; w += 4 * 256;
  float* bvdot = w; w += 16;
  __bf16* W1H  = (__bf16*)w; w += (size_t)4 * 36864 / 2;
  __bf16* W2H  = (__bf16*)w; w += (size_t)4 * 12288 / 2;
  __bf16* W2VP = (__bf16*)w; w += (size_t)3 * 3072 / 2;
  __bf16* VPb  = (__bf16*)w; w += (size_t)3 * 1024 / 2;
  int* deg     = (int*)w; w += NN;
  int* offs    = (int*)w; w += NN + 1;
  int* cursor  = (int*)w; w += NN;
  int* bsum    = (int*)w; w += 128;
  int* boff    = (int*)w; w += 128;
  int* csr_src = (int*)w; w += NE;
  int* csr_eid = (int*)w; w += NE;

  __bf16* xh[2] = {xh16a, xh16b};
  float* as_[2] = {asA, asB};
  float* ad_[2] = {adA, adB};

  k_pack_w1<<<72, 256, 0, stream>>>(up1_w, W1H);
  k_pack_w2<<<24, 256, 0, stream>>>(up2_w, W2H);

  const int nb = (NN + 1023) / 1024;
  k_zero<<<(NN + 255) / 256, 256, 0, stream>>>(deg);
  k_hist<<<(NE + 255) / 256, 256, 0, stream>>>(dst, deg);
  k_scan1<<<nb, 256, 0, stream>>>(deg, offs, bsum);
  k_scan2<<<1, 64, 0, stream>>>(bsum, boff, offs, nb);
  k_scan3<<<(NN + 255) / 256, 256, 0, stream>>>(offs, boff, cursor);
  k_scatter<<<(NE + 255) / 256, 256, 0, stream>>>(src, dst, cursor, csr_src, csr_eid);

  k_v_all<<<4, 256, 0, stream>>>(edge_w, att_edge, vbuf);
  k_w2v<<<3, 384, 0, stream>>>(up2_w, up2_b, vbuf, W2VP, VPb, bvdot);
  k_xh0<<<NN / 4 + 1, 256, 0, stream>>>(node_feats, conv_w, att_src, att_dst,
                                        nf16, xh16a, asA, adA);
  k_pass1f<<<NE / 64, 256, 0, stream>>>(edge_feats, vbuf, ef16, araw);

  for (int l = 0; l < NL; ++l) {
    int last = (l == NL - 1) ? 1 : 0;
    int cur = l & 1, nxt = (l + 1) & 1;
    k_gather4<<<NN / 4 + 1, 256, 0, stream>>>(
        xh[cur], araw, csr_src, csr_eid, offs, as_[cur], ad_[cur],
        conv_b + (size_t)l * DD, ln_g + (size_t)l * DD, ln_b + (size_t)l * DD,
        nf16, nf,
        last ? conv_w : (conv_w + (size_t)(l + 1) * DD * DD),
        last ? att_src : (att_src + (size_t)(l + 1) * NH * NC),
        last ? att_dst : (att_dst + (size_t)(l + 1) * NH * NC),
        xh[nxt], as_[nxt], ad_[nxt], last);
    k_edge_mlp15<<<NE / EB, 256, 0, stream>>>(
        nf16, ef16, efout, src, dst,
        W1H + (size_t)l * 36864, up1_b + (size_t)l * DIN,
        up_ln_g + (size_t)l * DIN, up_ln_b + (size_t)l * DIN,
        W2H + (size_t)l * 12288, up2_b + (size_t)l * DD,
        last ? W2VP : (W2VP + (size_t)l * 3072),
        last ? VPb : (VPb + (size_t)l * 1024),
        bvdot + (size_t)l * 4, araw, last);
  }
}

// Round 21
// 2553.574 us; speedup vs baseline: 1.7743x; 1.0351x over previous
//
#include <hip/hip_runtime.h>
#include <math.h>

#define NN 100000
#define NE 1600000
#define DD 64
#define NL 4
#define NH 4
#define NC 16
#define DIN 192
#define SLOPE 0.2f
#define EB 64
#define XSTR 200
#define FSTR 66
#define RSTR 68
#define LOG2E 1.44269504088896340736f

typedef __bf16 bf8 __attribute__((ext_vector_type(8)));
typedef __bf16 bf4 __attribute__((ext_vector_type(4)));
typedef __bf16 bf2 __attribute__((ext_vector_type(2)));
typedef float f32x4 __attribute__((ext_vector_type(4)));

__device__ __forceinline__ f32x4 MFMA(bf8 a, bf8 b, f32x4 c) {
  return __builtin_amdgcn_mfma_f32_16x16x32_bf16(a, b, c, 0, 0, 0);
}

// ---------------- weight packing: single bf16 plane, 1KB tiles ----------------
__global__ void k_pack_w1(const float* __restrict__ W1, __bf16* __restrict__ WH) {
  int gidx = blockIdx.x * 256 + threadIdx.x;
  if (gidx >= 4 * 4608) return;
  int lyr = gidx / 4608, rem = gidx % 4608;
  int lane = rem & 63, ts = rem >> 6;
  int s = ts % 6, t = ts / 6;
  const float* Wl = W1 + (size_t)lyr * DIN * DIN;
  size_t base = (size_t)lyr * 36864 + ((size_t)(t * 6 + s) * 64 + lane) * 8;
  int k0 = s * 32 + (lane >> 4) * 8, n = t * 16 + (lane & 15);
#pragma unroll
  for (int j = 0; j < 8; ++j)
    WH[base + j] = (__bf16)Wl[(size_t)(k0 + j) * DIN + n];
}

__global__ void k_pack_w2(const float* __restrict__ W2, __bf16* __restrict__ WH) {
  int gidx = blockIdx.x * 256 + threadIdx.x;
  if (gidx >= 4 * 1536) return;
  int lyr = gidx / 1536, rem = gidx % 1536;
  int lane = rem & 63, ts = rem >> 6;
  int s = ts % 6, t = ts / 6;
  const float* Wl = W2 + (size_t)lyr * DIN * DD;
  size_t base = (size_t)lyr * 12288 + ((size_t)(t * 6 + s) * 64 + lane) * 8;
  int k0 = s * 32 + (lane >> 4) * 8, n = t * 16 + (lane & 15);
#pragma unroll
  for (int j = 0; j < 8; ++j)
    WH[base + j] = (__bf16)Wl[(size_t)(k0 + j) * DD + n];
}

// W2VP[l] = W2_l @ v_{l+1}; VP[l] = v_{l+1}; bvdot[l][h] = b2_l . v_{l+1}[:,h]
__global__ void k_w2v(const float* __restrict__ up2_w, const float* __restrict__ up2_b,
                      const float* __restrict__ vbuf, __bf16* __restrict__ W2VP,
                      __bf16* __restrict__ VP, float* __restrict__ bvdot) {
  int l = blockIdx.x;
  const float* vn = vbuf + (l + 1) * 256;
  int t = threadIdx.x;
  if (t < 384) {
    int s = t >> 6, lane = t & 63;
    int i = lane & 15, k0 = s * 32 + (lane >> 4) * 8;
    const float* W2 = up2_w + (size_t)l * DIN * DD;
    __bf16* out = W2VP + (size_t)l * 3072 + ((size_t)(s * 64 + lane)) * 8;
#pragma unroll
    for (int j = 0; j < 8; ++j) {
      float val = 0.f;
      if (i < 4)
        for (int n = 0; n < DD; ++n)
          val = fmaf(W2[(size_t)(k0 + j) * DD + n], vn[n * NH + i], val);
      out[j] = (__bf16)val;
    }
  }
  if (t < 128) {
    int s2 = t >> 6, lane = t & 63;
    int i = lane & 15, k0 = s2 * 32 + (lane >> 4) * 8;
    __bf16* out = VP + (size_t)l * 1024 + ((size_t)(s2 * 64 + lane)) * 8;
#pragma unroll
    for (int j = 0; j < 8; ++j)
      out[j] = (i < 4) ? (__bf16)vn[(k0 + j) * NH + i] : (__bf16)0.f;
  }
  if (t < 4) {
    const float* b2 = up2_b + (size_t)l * DD;
    float bv = 0.f;
    for (int n = 0; n < DD; ++n) bv = fmaf(b2[n], vn[n * NH + t], bv);
    bvdot[l * 4 + t] = bv;
  }
}

// ---------------- CSR build ----------------
__global__ void k_zero(int* __restrict__ deg) {
  int i = blockIdx.x * 256 + threadIdx.x;
  if (i < NN) deg[i] = 0;
}

__global__ void k_hist(const int* __restrict__ dst, int* __restrict__ deg) {
  int e = blockIdx.x * 256 + threadIdx.x;
  if (e < NE) atomicAdd(&deg[dst[e]], 1);
}

__global__ void k_scan1(const int* __restrict__ deg, int* __restrict__ offs,
                        int* __restrict__ bsum) {
  __shared__ int sh[256];
  int t = threadIdx.x, b = blockIdx.x;
  int i0 = b * 1024 + t * 4;
  int d0 = (i0 + 0 < NN) ? deg[i0 + 0] : 0;
  int d1 = (i0 + 1 < NN) ? deg[i0 + 1] : 0;
  int d2 = (i0 + 2 < NN) ? deg[i0 + 2] : 0;
  int d3 = (i0 + 3 < NN) ? deg[i0 + 3] : 0;
  int s4 = d0 + d1 + d2 + d3;
  sh[t] = s4;
  __syncthreads();
  int p = 0;
#pragma unroll
  for (int off = 1; off < 256; off <<= 1) {
    int v = (t >= off) ? sh[t - off] : 0;
    __syncthreads();
    sh[t] += v;
    __syncthreads();
  }
  p = sh[t] - s4;
  if (t == 255) bsum[b] = sh[255];
  if (i0 + 0 < NN) offs[i0 + 0] = p;
  if (i0 + 1 < NN) offs[i0 + 1] = p + d0;
  if (i0 + 2 < NN) offs[i0 + 2] = p + d0 + d1;
  if (i0 + 3 < NN) offs[i0 + 3] = p + d0 + d1 + d2;
}

__global__ void k_scan2(int* __restrict__ bsum, int* __restrict__ boff,
                        int* __restrict__ offs, int nb) {
  if (threadIdx.x == 0 && blockIdx.x == 0) {
    int run = 0;
    for (int k = 0; k < nb; ++k) { boff[k] = run; run += bsum[k]; }
    offs[NN] = NE;
  }
}

__global__ void k_scan3(int* __restrict__ offs, const int* __restrict__ boff,
                        int* __restrict__ cursor) {
  int i = blockIdx.x * 256 + threadIdx.x;
  if (i < NN) {
    int v = offs[i] + boff[i >> 10];
    offs[i] = v;
    cursor[i] = v;
  }
}

// packed CSR: csr_pack[pos] = (src[e], e)
__global__ void k_scatter(const int* __restrict__ src, const int* __restrict__ dst,
                          int* __restrict__ cursor, int2* __restrict__ csr_pack) {
  int e = blockIdx.x * 256 + threadIdx.x;
  if (e >= NE) return;
  int pos = atomicAdd(&cursor[dst[e]], 1);
  csr_pack[pos] = make_int2(src[e], e);
}

// ---------------- upfront precomputes ----------------
__global__ void k_v_all(const float* __restrict__ ew_all, const float* __restrict__ ae_all,
                        float* __restrict__ vbuf) {
  int l = blockIdx.x;
  const float* ew = ew_all + (size_t)l * DD * DD;
  const float* ae = ae_all + (size_t)l * NH * NC;
  int d = threadIdx.x >> 2, h = threadIdx.x & 3;
  float s = 0.f;
#pragma unroll
  for (int c = 0; c < NC; ++c) s = fmaf(ew[d * DD + h * NC + c], ae[h * NC + c], s);
  vbuf[l * 256 + d * NH + h] = s;
}

// layer-0 xh from node_feats; also emits nf16 carry
__global__ void k_xh0(const float* __restrict__ node_feats, const float* __restrict__ W,
                      const float* __restrict__ as_, const float* __restrict__ ad_,
                      __bf16* __restrict__ nf16, __bf16* __restrict__ xh16,
                      float* __restrict__ asrc, float* __restrict__ adst) {
  int t = blockIdx.x * 4 + (threadIdx.x >> 6);
  int d = threadIdx.x & 63;
  if (t >= NN) return;
  const float* x = node_feats + (size_t)t * DD;
  nf16[(size_t)t * DD + d] = (__bf16)x[d];
  float acc = 0.f;
#pragma unroll
  for (int k = 0; k < DD; ++k) acc = fmaf(x[k], W[k * DD + d], acc);
  xh16[(size_t)t * DD + d] = (__bf16)acc;
  int h = d >> 4, c = d & 15;
  float ps = acc * as_[h * NC + c];
  float pd = acc * ad_[h * NC + c];
#pragma unroll
  for (int off = 8; off >= 1; off >>= 1) {
    ps += __shfl_xor(ps, off, 64);
    pd += __shfl_xor(pd, off, 64);
  }
  if (c == 0) { asrc[t * NH + h] = ps; adst[t * NH + h] = pd; }
}

// layer-0: edge_feats -> ef16 + RAW pe into araw[e] (both coalesced)
__global__ void k_pass1f(const float* __restrict__ edge_feats,
                         const float* __restrict__ v,
                         __bf16* __restrict__ ef16, float* __restrict__ araw) {
  int e = blockIdx.x * 64 + (threadIdx.x >> 2);
  int part = threadIdx.x & 3;
  if (e >= NE) return;
  float ph0 = 0.f, ph1 = 0.f, ph2 = 0.f, ph3 = 0.f;
  const float4* ep = (const float4*)(edge_feats + (size_t)e * DD + part * 16);
  const float4* v4 = (const float4*)v;
  bf4 outv[4];
#pragma unroll
  for (int c4 = 0; c4 < 4; ++c4) {
    float4 x = ep[c4];
    outv[c4][0] = (__bf16)x.x; outv[c4][1] = (__bf16)x.y;
    outv[c4][2] = (__bf16)x.z; outv[c4][3] = (__bf16)x.w;
    int d0 = part * 16 + c4 * 4;
    float4 va = v4[d0], vb = v4[d0 + 1], vc = v4[d0 + 2], vd = v4[d0 + 3];
    ph0 = fmaf(x.x, va.x, fmaf(x.y, vb.x, fmaf(x.z, vc.x, fmaf(x.w, vd.x, ph0))));
    ph1 = fmaf(x.x, va.y, fmaf(x.y, vb.y, fmaf(x.z, vc.y, fmaf(x.w, vd.y, ph1))));
    ph2 = fmaf(x.x, va.z, fmaf(x.y, vb.z, fmaf(x.z, vc.z, fmaf(x.w, vd.z, ph2))));
    ph3 = fmaf(x.x, va.w, fmaf(x.y, vb.w, fmaf(x.z, vc.w, fmaf(x.w, vd.w, ph3))));
  }
  *(bf8*)&ef16[(size_t)e * DD + part * 16] =
      (bf8){outv[0][0], outv[0][1], outv[0][2], outv[0][3],
            outv[1][0], outv[1][1], outv[1][2], outv[1][3]};
  *(bf8*)&ef16[(size_t)e * DD + part * 16 + 8] =
      (bf8){outv[2][0], outv[2][1], outv[2][2], outv[2][3],
            outv[3][0], outv[3][1], outv[3][2], outv[3][3]};
#pragma unroll
  for (int off = 1; off <= 2; off <<= 1) {
    ph0 += __shfl_xor(ph0, off, 64);
    ph1 += __shfl_xor(ph1, off, 64);
    ph2 += __shfl_xor(ph2, off, 64);
    ph3 += __shfl_xor(ph3, off, 64);
  }
  float pe = (part == 0) ? ph0 : (part == 1) ? ph1 : (part == 2) ? ph2 : ph3;
  araw[(size_t)e * NH + part] = pe;
}

// gather v5: online softmax 4-wide + packed CSR + fused next-layer xh
__global__ __launch_bounds__(256) void k_gather5(
    const __bf16* __restrict__ xh16, const float* __restrict__ araw,
    const int2* __restrict__ csr_pack, const int* __restrict__ offs,
    const float* __restrict__ asrc, const float* __restrict__ adst,
    const float* __restrict__ cb, const float* __restrict__ g,
    const float* __restrict__ bln, __bf16* __restrict__ nf16,
    float* __restrict__ nfout,
    const float* __restrict__ Wn, const float* __restrict__ asn,
    const float* __restrict__ adn, __bf16* __restrict__ xh16n,
    float* __restrict__ asrcn, float* __restrict__ adstn, int last) {
  int t = blockIdx.x * 4 + (threadIdx.x >> 6);
  int d = threadIdx.x & 63;
  if (t >= NN) return;
  int h = d >> 4;
  int o0 = offs[t], o1 = offs[t + 1];
  int deg = o1 - o0;
  float adh = adst[t * NH + h];

  // seed with self-loop (edge attr = 0)
  float sh = asrc[t * NH + h] + adh;
  sh = ((sh > 0.f) ? sh : SLOPE * sh) * LOG2E;
  float m_run = sh;
  float wsum = 1.f;
  float acc = (float)xh16[(size_t)t * DD + d];

  int j = 0;
  for (; j + 3 < deg; j += 4) {
    int2 p0 = csr_pack[o0 + j], p1 = csr_pack[o0 + j + 1];
    int2 p2 = csr_pack[o0 + j + 2], p3 = csr_pack[o0 + j + 3];
    float ar0 = asrc[p0.x * NH + h] + adh + araw[(size_t)p0.y * NH + h];
    float ar1 = asrc[p1.x * NH + h] + adh + araw[(size_t)p1.y * NH + h];
    float ar2 = asrc[p2.x * NH + h] + adh + araw[(size_t)p2.y * NH + h];
    float ar3 = asrc[p3.x * NH + h] + adh + araw[(size_t)p3.y * NH + h];
    ar0 = ((ar0 > 0.f) ? ar0 : SLOPE * ar0) * LOG2E;
    ar1 = ((ar1 > 0.f) ? ar1 : SLOPE * ar1) * LOG2E;
    ar2 = ((ar2 > 0.f) ? ar2 : SLOPE * ar2) * LOG2E;
    ar3 = ((ar3 > 0.f) ? ar3 : SLOPE * ar3) * LOG2E;
    float x0 = (float)xh16[(size_t)p0.x * DD + d];
    float x1 = (float)xh16[(size_t)p1.x * DD + d];
    float x2 = (float)xh16[(size_t)p2.x * DD + d];
    float x3 = (float)xh16[(size_t)p3.x * DD + d];
    float mnew = fmaxf(fmaxf(m_run, fmaxf(ar0, ar1)), fmaxf(ar2, ar3));
    float rold = exp2f(m_run - mnew);
    float w0 = exp2f(ar0 - mnew), w1 = exp2f(ar1 - mnew);
    float w2 = exp2f(ar2 - mnew), w3 = exp2f(ar3 - mnew);
    acc = fmaf(w3, x3, fmaf(w2, x2, fmaf(w1, x1, fmaf(w0, x0, acc * rold))));
    wsum = (w0 + w1) + (w2 + w3) + wsum * rold;
    m_run = mnew;
  }
  for (; j < deg; ++j) {
    int2 p = csr_pack[o0 + j];
    float ar = asrc[p.x * NH + h] + adh + araw[(size_t)p.y * NH + h];
    ar = ((ar > 0.f) ? ar : SLOPE * ar) * LOG2E;
    float xv = (float)xh16[(size_t)p.x * DD + d];
    float mnew = fmaxf(m_run, ar);
    float rold = exp2f(m_run - mnew);
    float w = exp2f(ar - mnew);
    acc = fmaf(w, xv, acc * rold);
    wsum = fmaf(w, 1.f, wsum * rold);
    m_run = mnew;
  }

  float val = acc / (wsum + 1e-16f) + cb[d];
  float m = val;
#pragma unroll
  for (int off = 32; off >= 1; off >>= 1) m += __shfl_xor(m, off, 64);
  m *= (1.f / 64.f);
  float c = val - m;
  float q = c * c;
#pragma unroll
  for (int off = 32; off >= 1; off >>= 1) q += __shfl_xor(q, off, 64);
  float rstd = 1.f / sqrtf(q * (1.f / 64.f) + 1e-5f);
  float y = c * rstd * g[d] + bln[d];
  y = fmaxf(y, 0.f);
  float out = y + (float)nf16[(size_t)t * DD + d];
  nf16[(size_t)t * DD + d] = (__bf16)out;

  if (last) {
    nfout[(size_t)t * DD + d] = out;
  } else {
    // fused next-layer xh: wave holds the full row (lane k = dim k)
    float acc2 = 0.f;
#pragma unroll 8
    for (int k = 0; k < DD; ++k) {
      float xk = __shfl(out, k, 64);
      acc2 = fmaf(xk, Wn[k * DD + d], acc2);
    }
    xh16n[(size_t)t * DD + d] = (__bf16)acc2;
    int cc = d & 15;
    float ps = acc2 * asn[h * NC + cc];
    float pd = acc2 * adn[h * NC + cc];
#pragma unroll
    for (int off = 8; off >= 1; off >>= 1) {
      ps += __shfl_xor(ps, off, 64);
      pd += __shfl_xor(pd, off, 64);
    }
    if (cc == 0) { asrcn[t * NH + h] = ps; adstn[t * NH + h] = pd; }
  }
}

// ---------------- edge MLP v15: 64 edges / 4 waves / 256 thr (R18 best) ------
__global__ __launch_bounds__(256, 4) void k_edge_mlp15(
    const __bf16* __restrict__ nf16, __bf16* __restrict__ ef16,
    float* __restrict__ efout,
    const int* __restrict__ src, const int* __restrict__ dst,
    const __bf16* __restrict__ W1H, const float* __restrict__ b1,
    const float* __restrict__ g, const float* __restrict__ bg,
    const __bf16* __restrict__ W2H, const float* __restrict__ b2,
    const __bf16* __restrict__ W2VP, const __bf16* __restrict__ VP,
    const float* __restrict__ bvdot, float* __restrict__ araw, int last) {
  __shared__ __bf16 XH[EB * XSTR];
  __shared__ __bf16 RESB[EB * RSTR];
  __shared__ __bf16 Pb[EB * 8];
  int tid = threadIdx.x;
  int e0 = blockIdx.x * EB;
  float* XF = (float*)XH;

  {
    int row = tid >> 2, p = tid & 3;
    int se = src[e0 + row], de = dst[e0 + row];
    const bf8* psrc = (const bf8*)(nf16 + (size_t)se * DD + p * 16);
    *(bf8*)&XH[row * XSTR + p * 16]     = psrc[0];
    *(bf8*)&XH[row * XSTR + p * 16 + 8] = psrc[1];
    const bf8* pdst = (const bf8*)(nf16 + (size_t)de * DD + p * 16);
    *(bf8*)&XH[row * XSTR + 64 + p * 16]     = pdst[0];
    *(bf8*)&XH[row * XSTR + 64 + p * 16 + 8] = pdst[1];
    const bf8* pef = (const bf8*)(ef16 + (size_t)(e0 + row) * DD + p * 16);
    bf8 ev0 = pef[0], ev1 = pef[1];
    *(bf8*)&XH[row * XSTR + 128 + p * 16]     = ev0;
    *(bf8*)&XH[row * XSTR + 128 + p * 16 + 8] = ev1;
    *(bf8*)&RESB[row * RSTR + p * 16]     = ev0;
    *(bf8*)&RESB[row * RSTR + p * 16 + 8] = ev1;
  }
  __syncthreads();

  int cg = tid >> 6, l = tid & 63;
  int gq = l >> 4, i = l & 15;
  int col = cg * 16 + i;

  f32x4 acc[4][3];
#pragma unroll
  for (int rt = 0; rt < 4; ++rt)
#pragma unroll
    for (int t = 0; t < 3; ++t) acc[rt][t] = (f32x4){0.f, 0.f, 0.f, 0.f};
  f32x4 accP = (f32x4){0.f, 0.f, 0.f, 0.f};
  f32x4 accQ = (f32x4){0.f, 0.f, 0.f, 0.f};

#pragma unroll
  for (int s = 0; s < 6; ++s) {
    bf8 a[4];
#pragma unroll
    for (int rt = 0; rt < 4; ++rt)
      a[rt] = *(const bf8*)&XH[(rt * 16 + i) * XSTR + s * 32 + gq * 8];
#pragma unroll
    for (int t = 0; t < 3; ++t) {
      bf8 bh = *(const bf8*)(W1H + ((size_t)((cg * 3 + t) * 6 + s) * 64 + l) * 8);
#pragma unroll
      for (int rt = 0; rt < 4; ++rt) acc[rt][t] = MFMA(a[rt], bh, acc[rt][t]);
    }
    if (!last && s >= 4) {
      bf8 acg = *(const bf8*)&XH[(cg * 16 + i) * XSTR + s * 32 + gq * 8];
      bf8 vp = *(const bf8*)(VP + ((size_t)((s - 4) * 64 + l)) * 8);
      accP = MFMA(acg, vp, accP);
    }
  }

  float b1v[3], gv[3], bgv[3];
#pragma unroll
  for (int t = 0; t < 3; ++t) {
    int n = cg * 48 + t * 16 + i;
    b1v[t] = b1[n]; gv[t] = g[n]; bgv[t] = bg[n];
  }
#pragma unroll
  for (int rt = 0; rt < 4; ++rt)
#pragma unroll
    for (int t = 0; t < 3; ++t)
#pragma unroll
      for (int r = 0; r < 4; ++r) acc[rt][t][r] += b1v[t];

#pragma unroll
  for (int rt = 0; rt < 4; ++rt)
#pragma unroll
    for (int r = 0; r < 4; ++r) {
      float sm = 0.f, sq = 0.f;
#pragma unroll
      for (int t = 0; t < 3; ++t) { float x = acc[rt][t][r]; sm += x; sq = fmaf(x, x, sq); }
#pragma unroll
      for (int off = 1; off <= 8; off <<= 1) {
        sm += __shfl_xor(sm, off, 64);
        sq += __shfl_xor(sq, off, 64);
      }
      if (i == 0) {
        int row = rt * 16 + gq * 4 + r;
        bf2 pr; pr[0] = (__bf16)sm; pr[1] = (__bf16)sq;
        *(bf2*)&Pb[row * 8 + cg * 2] = pr;
      }
    }
  __syncthreads();   // barrier 1

  if (tid < EB) {
    bf8 pv = *(const bf8*)&Pb[tid * 8];
    float sm = (float)pv[0] + (float)pv[2] + (float)pv[4] + (float)pv[6];
    float sq = (float)pv[1] + (float)pv[3] + (float)pv[5] + (float)pv[7];
    float mean = sm * (1.f / (float)DIN);
    float var = sq * (1.f / (float)DIN) - mean * mean;
    float rstd = 1.f / sqrtf(var + 1e-5f);
    bf2 mv; mv[0] = (__bf16)mean; mv[1] = (__bf16)rstd;
    *(bf2*)&Pb[tid * 8] = mv;
  }
  __syncthreads();   // barrier 2

#pragma unroll
  for (int rt = 0; rt < 4; ++rt)
#pragma unroll
    for (int r = 0; r < 4; ++r) {
      int row = rt * 16 + gq * 4 + r;
      bf2 mv = *(const bf2*)&Pb[row * 8];
      float mean = (float)mv[0], rstd = (float)mv[1];
#pragma unroll
      for (int t = 0; t < 3; ++t) {
        float y = (acc[rt][t][r] - mean) * rstd * gv[t] + bgv[t];
        y = fmaxf(y, 0.f);
        XH[row * XSTR + cg * 48 + t * 16 + i] = (__bf16)y;
      }
    }
  __syncthreads();   // barrier 3

  f32x4 acc2[4];
#pragma unroll
  for (int rt = 0; rt < 4; ++rt) acc2[rt] = (f32x4){0.f, 0.f, 0.f, 0.f};

#pragma unroll
  for (int s = 0; s < 6; ++s) {
    bf8 a2[4];
#pragma unroll
    for (int rt = 0; rt < 4; ++rt)
      a2[rt] = *(const bf8*)&XH[(rt * 16 + i) * XSTR + s * 32 + gq * 8];
    bf8 bh = *(const bf8*)(W2H + ((size_t)(cg * 6 + s) * 64 + l) * 8);
#pragma unroll
    for (int rt = 0; rt < 4; ++rt) acc2[rt] = MFMA(a2[rt], bh, acc2[rt]);
    if (!last) {
      bf8 acg = *(const bf8*)&XH[(cg * 16 + i) * XSTR + s * 32 + gq * 8];
      bf8 wv = *(const bf8*)(W2VP + ((size_t)(s * 64 + l)) * 8);
      accQ = MFMA(acg, wv, accQ);
    }
  }
  __syncthreads();   // barrier 4

  float b2v = b2[col];
#pragma unroll
  for (int rt = 0; rt < 4; ++rt)
#pragma unroll
    for (int r = 0; r < 4; ++r) {
      int row = rt * 16 + gq * 4 + r;
      float resv = (float)RESB[row * RSTR + col];
      XF[row * FSTR + col] = acc2[rt][r] + b2v + resv;
    }

  if (!last && i < 4) {
    float bvd = bvdot[i];
#pragma unroll
    for (int r = 0; r < 4; ++r) {
      int row = cg * 16 + gq * 4 + r;
      araw[(size_t)(e0 + row) * NH + i] = accP[r] + accQ[r] + bvd;
    }
  }
  __syncthreads();   // barrier 5

  {
    int row = tid >> 2, q = tid & 3;
    const float* fr = &XF[row * FSTR + q * 16];
    if (last) {
      float* op = efout + (size_t)(e0 + row) * DD + q * 16;
#pragma unroll
      for (int k = 0; k < 4; ++k)
        *(float4*)(op + k * 4) = *(const float4*)(fr + k * 4);
    } else {
      bf8 o0, o1;
#pragma unroll
      for (int k = 0; k < 8; ++k) { o0[k] = (__bf16)fr[k]; o1[k] = (__bf16)fr[k + 8]; }
      __bf16* op = ef16 + (size_t)(e0 + row) * DD + q * 16;
      *(bf8*)op = o0;
      *(bf8*)(op + 8) = o1;
    }
  }
}

extern "C" void kernel_launch(void* const* d_in, const int* in_sizes, int n_in,
                              void* d_out, int out_size, void* d_ws, size_t ws_size,
                              hipStream_t stream) {
  const float* node_feats = (const float*)d_in[0];
  const float* edge_feats = (const float*)d_in[1];
  const int*   edge_index = (const int*)d_in[2];
  const float* conv_w  = (const float*)d_in[3];
  const float* att_src = (const float*)d_in[4];
  const float* att_dst = (const float*)d_in[5];
  const float* edge_w  = (const float*)d_in[6];
  const float* att_edge= (const float*)d_in[7];
  const float* conv_b  = (const float*)d_in[8];
  const float* ln_g    = (const float*)d_in[9];
  const float* ln_b    = (const float*)d_in[10];
  const float* up1_w   = (const float*)d_in[11];
  const float* up1_b   = (const float*)d_in[12];
  const float* up_ln_g = (const float*)d_in[13];
  const float* up_ln_b = (const float*)d_in[14];
  const float* up2_w   = (const float*)d_in[15];
  const float* up2_b   = (const float*)d_in[16];

  const int* src = edge_index;
  const int* dst = edge_index + NE;

  float* nf = (float*)d_out;
  float* efout = nf + (size_t)NN * DD;

  float* w = (float*)d_ws;
  __bf16* xh16a = (__bf16*)w; w += (size_t)NN * DD / 2;
  __bf16* xh16b = (__bf16*)w; w += (size_t)NN * DD / 2;
  __bf16* nf16 = (__bf16*)w; w += (size_t)NN * DD / 2;
  __bf16* ef16 = (__bf16*)w; w += (size_t)NE * DD / 2;
  float* asA   = w; w += (size_t)NN * NH;
  float* adA   = w; w += (size_t)NN * NH;
  float* asB   = w; w += (size_t)NN * NH;
  float* adB   = w; w += (size_t)NN * NH;
  float* araw  = w; w += (size_t)NE * NH;
  float* vbuf  = w; w += 4 * 256;
  float* bvdot = w; w += 16;
  __bf16* W1H  = (__bf16*)w; w += (size_t)4 * 36864 / 2;
  __bf16* W2H  = (__bf16*)w; w += (size_t)4 * 12288 / 2;
  __bf16* W2VP = (__bf16*)w; w += (size_t)3 * 3072 / 2;
  __bf16* VPb  = (__bf16*)w; w += (size_t)3 * 1024 / 2;
  int* deg     = (int*)w; w += NN;
  int* offs    = (int*)w; w += NN + 2;          // padded: keep 8B alignment below
  int* cursor  = (int*)w; w += NN;
  int* bsum    = (int*)w; w += 128;
  int* boff    = (int*)w; w += 128;
  int2* csr_pack = (int2*)w; w += (size_t)NE * 2;

  __bf16* xh[2] = {xh16a, xh16b};
  float* as_[2] = {asA, asB};
  float* ad_[2] = {adA, adB};

  k_pack_w1<<<72, 256, 0, stream>>>(up1_w, W1H);
  k_pack_w2<<<24, 256, 0, stream>>>(up2_w, W2H);

  const int nb = (NN + 1023) / 1024;
  k_zero<<<(NN + 255) / 256, 256, 0, stream>>>(deg);
  k_hist<<<(NE + 255) / 256, 256, 0, stream>>>(dst, deg);
  k_scan1<<<nb, 256, 0, stream>>>(deg, offs, bsum);
  k_scan2<<<1, 64, 0, stream>>>(bsum, boff, offs, nb);
  k_scan3<<<(NN + 255) / 256, 256, 0, stream>>>(offs, boff, cursor);
  k_scatter<<<(NE + 255) / 256, 256, 0, stream>>>(src, dst, cursor, csr_pack);

  k_v_all<<<4, 256, 0, stream>>>(edge_w, att_edge, vbuf);
  k_w2v<<<3, 384, 0, stream>>>(up2_w, up2_b, vbuf, W2VP, VPb, bvdot);
  k_xh0<<<NN / 4 + 1, 256, 0, stream>>>(node_feats, conv_w, att_src, att_dst,
                                        nf16, xh16a, asA, adA);
  k_pass1f<<<NE / 64, 256, 0, stream>>>(edge_feats, vbuf, ef16, araw);

  for (int l = 0; l < NL; ++l) {
    int last = (l == NL - 1) ? 1 : 0;
    int cur = l & 1, nxt = (l + 1) & 1;
    k_gather5<<<NN / 4 + 1, 256, 0, stream>>>(
        xh[cur], araw, csr_pack, offs, as_[cur], ad_[cur],
        conv_b + (size_t)l * DD, ln_g + (size_t)l * DD, ln_b + (size_t)l * DD,
        nf16, nf,
        last ? conv_w : (conv_w + (size_t)(l + 1) * DD * DD),
        last ? att_src : (att_src + (size_t)(l + 1) * NH * NC),
        last ? att_dst : (att_dst + (size_t)(l + 1) * NH * NC),
        xh[nxt], as_[nxt], ad_[nxt], last);
    k_edge_mlp15<<<NE / EB, 256, 0, stream>>>(
        nf16, ef16, efout, src, dst,
        W1H + (size_t)l * 36864, up1_b + (size_t)l * DIN,
        up_ln_g + (size_t)l * DIN, up_ln_b + (size_t)l * DIN,
        W2H + (size_t)l * 12288, up2_b + (size_t)l * DD,
        last ? W2VP : (W2VP + (size_t)l * 3072),
        last ? VPb : (VPb + (size_t)l * 1024),
        bvdot + (size_t)l * 4, araw, last);
  }
}

// Round 22
// 2539.342 us; speedup vs baseline: 1.7843x; 1.0056x over previous
//
#include <hip/hip_runtime.h>
#include <math.h>

#define NN 100000
#define NE 1600000
#define DD 64
#define NL 4
#define NH 4
#define NC 16
#define DIN 192
#define SLOPE 0.2f
#define EB 64
#define XSTR 200
#define FSTR 66
#define RSTR 68
#define LOG2E 1.44269504088896340736f

typedef __bf16 bf8 __attribute__((ext_vector_type(8)));
typedef __bf16 bf4 __attribute__((ext_vector_type(4)));
typedef __bf16 bf2 __attribute__((ext_vector_type(2)));
typedef float f32x4 __attribute__((ext_vector_type(4)));

__device__ __forceinline__ f32x4 MFMA(bf8 a, bf8 b, f32x4 c) {
  return __builtin_amdgcn_mfma_f32_16x16x32_bf16(a, b, c, 0, 0, 0);
}

// ---------------- weight packing: single bf16 plane, 1KB tiles ----------------
__global__ void k_pack_w1(const float* __restrict__ W1, __bf16* __restrict__ WH) {
  int gidx = blockIdx.x * 256 + threadIdx.x;
  if (gidx >= 4 * 4608) return;
  int lyr = gidx / 4608, rem = gidx % 4608;
  int lane = rem & 63, ts = rem >> 6;
  int s = ts % 6, t = ts / 6;
  const float* Wl = W1 + (size_t)lyr * DIN * DIN;
  size_t base = (size_t)lyr * 36864 + ((size_t)(t * 6 + s) * 64 + lane) * 8;
  int k0 = s * 32 + (lane >> 4) * 8, n = t * 16 + (lane & 15);
#pragma unroll
  for (int j = 0; j < 8; ++j)
    WH[base + j] = (__bf16)Wl[(size_t)(k0 + j) * DIN + n];
}

__global__ void k_pack_w2(const float* __restrict__ W2, __bf16* __restrict__ WH) {
  int gidx = blockIdx.x * 256 + threadIdx.x;
  if (gidx >= 4 * 1536) return;
  int lyr = gidx / 1536, rem = gidx % 1536;
  int lane = rem & 63, ts = rem >> 6;
  int s = ts % 6, t = ts / 6;
  const float* Wl = W2 + (size_t)lyr * DIN * DD;
  size_t base = (size_t)lyr * 12288 + ((size_t)(t * 6 + s) * 64 + lane) * 8;
  int k0 = s * 32 + (lane >> 4) * 8, n = t * 16 + (lane & 15);
#pragma unroll
  for (int j = 0; j < 8; ++j)
    WH[base + j] = (__bf16)Wl[(size_t)(k0 + j) * DD + n];
}

// W2VP[l] = W2_l @ v_{l+1}; VP[l] = v_{l+1}; bvdot[l][h] = b2_l . v_{l+1}[:,h]
__global__ void k_w2v(const float* __restrict__ up2_w, const float* __restrict__ up2_b,
                      const float* __restrict__ vbuf, __bf16* __restrict__ W2VP,
                      __bf16* __restrict__ VP, float* __restrict__ bvdot) {
  int l = blockIdx.x;
  const float* vn = vbuf + (l + 1) * 256;
  int t = threadIdx.x;
  if (t < 384) {
    int s = t >> 6, lane = t & 63;
    int i = lane & 15, k0 = s * 32 + (lane >> 4) * 8;
    const float* W2 = up2_w + (size_t)l * DIN * DD;
    __bf16* out = W2VP + (size_t)l * 3072 + ((size_t)(s * 64 + lane)) * 8;
#pragma unroll
    for (int j = 0; j < 8; ++j) {
      float val = 0.f;
      if (i < 4)
        for (int n = 0; n < DD; ++n)
          val = fmaf(W2[(size_t)(k0 + j) * DD + n], vn[n * NH + i], val);
      out[j] = (__bf16)val;
    }
  }
  if (t < 128) {
    int s2 = t >> 6, lane = t & 63;
    int i = lane & 15, k0 = s2 * 32 + (lane >> 4) * 8;
    __bf16* out = VP + (size_t)l * 1024 + ((size_t)(s2 * 64 + lane)) * 8;
#pragma unroll
    for (int j = 0; j < 8; ++j)
      out[j] = (i < 4) ? (__bf16)vn[(k0 + j) * NH + i] : (__bf16)0.f;
  }
  if (t < 4) {
    const float* b2 = up2_b + (size_t)l * DD;
    float bv = 0.f;
    for (int n = 0; n < DD; ++n) bv = fmaf(b2[n], vn[n * NH + t], bv);
    bvdot[l * 4 + t] = bv;
  }
}

// ---------------- CSR build ----------------
__global__ void k_zero(int* __restrict__ deg) {
  int i = blockIdx.x * 256 + threadIdx.x;
  if (i < NN) deg[i] = 0;
}

__global__ void k_hist(const int* __restrict__ dst, int* __restrict__ deg) {
  int e = blockIdx.x * 256 + threadIdx.x;
  if (e < NE) atomicAdd(&deg[dst[e]], 1);
}

__global__ void k_scan1(const int* __restrict__ deg, int* __restrict__ offs,
                        int* __restrict__ bsum) {
  __shared__ int sh[256];
  int t = threadIdx.x, b = blockIdx.x;
  int i0 = b * 1024 + t * 4;
  int d0 = (i0 + 0 < NN) ? deg[i0 + 0] : 0;
  int d1 = (i0 + 1 < NN) ? deg[i0 + 1] : 0;
  int d2 = (i0 + 2 < NN) ? deg[i0 + 2] : 0;
  int d3 = (i0 + 3 < NN) ? deg[i0 + 3] : 0;
  int s4 = d0 + d1 + d2 + d3;
  sh[t] = s4;
  __syncthreads();
  int p = 0;
#pragma unroll
  for (int off = 1; off < 256; off <<= 1) {
    int v = (t >= off) ? sh[t - off] : 0;
    __syncthreads();
    sh[t] += v;
    __syncthreads();
  }
  p = sh[t] - s4;
  if (t == 255) bsum[b] = sh[255];
  if (i0 + 0 < NN) offs[i0 + 0] = p;
  if (i0 + 1 < NN) offs[i0 + 1] = p + d0;
  if (i0 + 2 < NN) offs[i0 + 2] = p + d0 + d1;
  if (i0 + 3 < NN) offs[i0 + 3] = p + d0 + d1 + d2;
}

__global__ void k_scan2(int* __restrict__ bsum, int* __restrict__ boff,
                        int* __restrict__ offs, int nb) {
  if (threadIdx.x == 0 && blockIdx.x == 0) {
    int run = 0;
    for (int k = 0; k < nb; ++k) { boff[k] = run; run += bsum[k]; }
    offs[NN] = NE;
  }
}

__global__ void k_scan3(int* __restrict__ offs, const int* __restrict__ boff,
                        int* __restrict__ cursor) {
  int i = blockIdx.x * 256 + threadIdx.x;
  if (i < NN) {
    int v = offs[i] + boff[i >> 10];
    offs[i] = v;
    cursor[i] = v;
  }
}

// packed CSR: csr_pack[pos] = (src[e], e)
__global__ void k_scatter(const int* __restrict__ src, const int* __restrict__ dst,
                          int* __restrict__ cursor, int2* __restrict__ csr_pack) {
  int e = blockIdx.x * 256 + threadIdx.x;
  if (e >= NE) return;
  int pos = atomicAdd(&cursor[dst[e]], 1);
  csr_pack[pos] = make_int2(src[e], e);
}

// ---------------- upfront precomputes ----------------
__global__ void k_v_all(const float* __restrict__ ew_all, const float* __restrict__ ae_all,
                        float* __restrict__ vbuf) {
  int l = blockIdx.x;
  const float* ew = ew_all + (size_t)l * DD * DD;
  const float* ae = ae_all + (size_t)l * NH * NC;
  int d = threadIdx.x >> 2, h = threadIdx.x & 3;
  float s = 0.f;
#pragma unroll
  for (int c = 0; c < NC; ++c) s = fmaf(ew[d * DD + h * NC + c], ae[h * NC + c], s);
  vbuf[l * 256 + d * NH + h] = s;
}

// layer-0 xh from node_feats; also emits nf16 carry
__global__ void k_xh0(const float* __restrict__ node_feats, const float* __restrict__ W,
                      const float* __restrict__ as_, const float* __restrict__ ad_,
                      __bf16* __restrict__ nf16, __bf16* __restrict__ xh16,
                      float* __restrict__ asrc, float* __restrict__ adst) {
  int t = blockIdx.x * 4 + (threadIdx.x >> 6);
  int d = threadIdx.x & 63;
  if (t >= NN) return;
  const float* x = node_feats + (size_t)t * DD;
  nf16[(size_t)t * DD + d] = (__bf16)x[d];
  float acc = 0.f;
#pragma unroll
  for (int k = 0; k < DD; ++k) acc = fmaf(x[k], W[k * DD + d], acc);
  xh16[(size_t)t * DD + d] = (__bf16)acc;
  int h = d >> 4, c = d & 15;
  float ps = acc * as_[h * NC + c];
  float pd = acc * ad_[h * NC + c];
#pragma unroll
  for (int off = 8; off >= 1; off >>= 1) {
    ps += __shfl_xor(ps, off, 64);
    pd += __shfl_xor(pd, off, 64);
  }
  if (c == 0) { asrc[t * NH + h] = ps; adst[t * NH + h] = pd; }
}

// layer-0: edge_feats -> ef16 + RAW pe into araw[e] (both coalesced)
__global__ void k_pass1f(const float* __restrict__ edge_feats,
                         const float* __restrict__ v,
                         __bf16* __restrict__ ef16, float* __restrict__ araw) {
  int e = blockIdx.x * 64 + (threadIdx.x >> 2);
  int part = threadIdx.x & 3;
  if (e >= NE) return;
  float ph0 = 0.f, ph1 = 0.f, ph2 = 0.f, ph3 = 0.f;
  const float4* ep = (const float4*)(edge_feats + (size_t)e * DD + part * 16);
  const float4* v4 = (const float4*)v;
  bf4 outv[4];
#pragma unroll
  for (int c4 = 0; c4 < 4; ++c4) {
    float4 x = ep[c4];
    outv[c4][0] = (__bf16)x.x; outv[c4][1] = (__bf16)x.y;
    outv[c4][2] = (__bf16)x.z; outv[c4][3] = (__bf16)x.w;
    int d0 = part * 16 + c4 * 4;
    float4 va = v4[d0], vb = v4[d0 + 1], vc = v4[d0 + 2], vd = v4[d0 + 3];
    ph0 = fmaf(x.x, va.x, fmaf(x.y, vb.x, fmaf(x.z, vc.x, fmaf(x.w, vd.x, ph0))));
    ph1 = fmaf(x.x, va.y, fmaf(x.y, vb.y, fmaf(x.z, vc.y, fmaf(x.w, vd.y, ph1))));
    ph2 = fmaf(x.x, va.z, fmaf(x.y, vb.z, fmaf(x.z, vc.z, fmaf(x.w, vd.z, ph2))));
    ph3 = fmaf(x.x, va.w, fmaf(x.y, vb.w, fmaf(x.z, vc.w, fmaf(x.w, vd.w, ph3))));
  }
  *(bf8*)&ef16[(size_t)e * DD + part * 16] =
      (bf8){outv[0][0], outv[0][1], outv[0][2], outv[0][3],
            outv[1][0], outv[1][1], outv[1][2], outv[1][3]};
  *(bf8*)&ef16[(size_t)e * DD + part * 16 + 8] =
      (bf8){outv[2][0], outv[2][1], outv[2][2], outv[2][3],
            outv[3][0], outv[3][1], outv[3][2], outv[3][3]};
#pragma unroll
  for (int off = 1; off <= 2; off <<= 1) {
    ph0 += __shfl_xor(ph0, off, 64);
    ph1 += __shfl_xor(ph1, off, 64);
    ph2 += __shfl_xor(ph2, off, 64);
    ph3 += __shfl_xor(ph3, off, 64);
  }
  float pe = (part == 0) ? ph0 : (part == 1) ? ph1 : (part == 2) ? ph2 : ph3;
  araw[(size_t)e * NH + part] = pe;
}

// gather v5: online softmax 4-wide + packed CSR + fused next-layer xh
__global__ __launch_bounds__(256) void k_gather5(
    const __bf16* __restrict__ xh16, const float* __restrict__ araw,
    const int2* __restrict__ csr_pack, const int* __restrict__ offs,
    const float* __restrict__ asrc, const float* __restrict__ adst,
    const float* __restrict__ cb, const float* __restrict__ g,
    const float* __restrict__ bln, __bf16* __restrict__ nf16,
    float* __restrict__ nfout,
    const float* __restrict__ Wn, const float* __restrict__ asn,
    const float* __restrict__ adn, __bf16* __restrict__ xh16n,
    float* __restrict__ asrcn, float* __restrict__ adstn, int last) {
  int t = blockIdx.x * 4 + (threadIdx.x >> 6);
  int d = threadIdx.x & 63;
  if (t >= NN) return;
  int h = d >> 4;
  int o0 = offs[t], o1 = offs[t + 1];
  int deg = o1 - o0;
  float adh = adst[t * NH + h];

  float sh = asrc[t * NH + h] + adh;
  sh = ((sh > 0.f) ? sh : SLOPE * sh) * LOG2E;
  float m_run = sh;
  float wsum = 1.f;
  float acc = (float)xh16[(size_t)t * DD + d];

  int j = 0;
  for (; j + 3 < deg; j += 4) {
    int2 p0 = csr_pack[o0 + j], p1 = csr_pack[o0 + j + 1];
    int2 p2 = csr_pack[o0 + j + 2], p3 = csr_pack[o0 + j + 3];
    float ar0 = asrc[p0.x * NH + h] + adh + araw[(size_t)p0.y * NH + h];
    float ar1 = asrc[p1.x * NH + h] + adh + araw[(size_t)p1.y * NH + h];
    float ar2 = asrc[p2.x * NH + h] + adh + araw[(size_t)p2.y * NH + h];
    float ar3 = asrc[p3.x * NH + h] + adh + araw[(size_t)p3.y * NH + h];
    ar0 = ((ar0 > 0.f) ? ar0 : SLOPE * ar0) * LOG2E;
    ar1 = ((ar1 > 0.f) ? ar1 : SLOPE * ar1) * LOG2E;
    ar2 = ((ar2 > 0.f) ? ar2 : SLOPE * ar2) * LOG2E;
    ar3 = ((ar3 > 0.f) ? ar3 : SLOPE * ar3) * LOG2E;
    float x0 = (float)xh16[(size_t)p0.x * DD + d];
    float x1 = (float)xh16[(size_t)p1.x * DD + d];
    float x2 = (float)xh16[(size_t)p2.x * DD + d];
    float x3 = (float)xh16[(size_t)p3.x * DD + d];
    float mnew = fmaxf(fmaxf(m_run, fmaxf(ar0, ar1)), fmaxf(ar2, ar3));
    float rold = exp2f(m_run - mnew);
    float w0 = exp2f(ar0 - mnew), w1 = exp2f(ar1 - mnew);
    float w2 = exp2f(ar2 - mnew), w3 = exp2f(ar3 - mnew);
    acc = fmaf(w3, x3, fmaf(w2, x2, fmaf(w1, x1, fmaf(w0, x0, acc * rold))));
    wsum = (w0 + w1) + (w2 + w3) + wsum * rold;
    m_run = mnew;
  }
  for (; j < deg; ++j) {
    int2 p = csr_pack[o0 + j];
    float ar = asrc[p.x * NH + h] + adh + araw[(size_t)p.y * NH + h];
    ar = ((ar > 0.f) ? ar : SLOPE * ar) * LOG2E;
    float xv = (float)xh16[(size_t)p.x * DD + d];
    float mnew = fmaxf(m_run, ar);
    float rold = exp2f(m_run - mnew);
    float w = exp2f(ar - mnew);
    acc = fmaf(w, xv, acc * rold);
    wsum = fmaf(w, 1.f, wsum * rold);
    m_run = mnew;
  }

  float val = acc / (wsum + 1e-16f) + cb[d];
  float m = val;
#pragma unroll
  for (int off = 32; off >= 1; off >>= 1) m += __shfl_xor(m, off, 64);
  m *= (1.f / 64.f);
  float c = val - m;
  float q = c * c;
#pragma unroll
  for (int off = 32; off >= 1; off >>= 1) q += __shfl_xor(q, off, 64);
  float rstd = 1.f / sqrtf(q * (1.f / 64.f) + 1e-5f);
  float y = c * rstd * g[d] + bln[d];
  y = fmaxf(y, 0.f);
  float out = y + (float)nf16[(size_t)t * DD + d];
  nf16[(size_t)t * DD + d] = (__bf16)out;

  if (last) {
    nfout[(size_t)t * DD + d] = out;
  } else {
    float acc2 = 0.f;
#pragma unroll 8
    for (int k = 0; k < DD; ++k) {
      float xk = __shfl(out, k, 64);
      acc2 = fmaf(xk, Wn[k * DD + d], acc2);
    }
    xh16n[(size_t)t * DD + d] = (__bf16)acc2;
    int cc = d & 15;
    float ps = acc2 * asn[h * NC + cc];
    float pd = acc2 * adn[h * NC + cc];
#pragma unroll
    for (int off = 8; off >= 1; off >>= 1) {
      ps += __shfl_xor(ps, off, 64);
      pd += __shfl_xor(pd, off, 64);
    }
    if (cc == 0) { asrcn[t * NH + h] = ps; adstn[t * NH + h] = pd; }
  }
}

// ---------------- edge MLP v16: accP folded into accQ (ef from RESB in GEMM2)
// pe = [H | ef_old] @ [W2 v ; v] + b2.v ; total regs 60 VGPR + 68 AGPR = 128
// -> 4 waves/SIMD under __launch_bounds__(256,4).
__global__ __launch_bounds__(256, 4) void k_edge_mlp16(
    const __bf16* __restrict__ nf16, __bf16* __restrict__ ef16,
    float* __restrict__ efout,
    const int* __restrict__ src, const int* __restrict__ dst,
    const __bf16* __restrict__ W1H, const float* __restrict__ b1,
    const float* __restrict__ g, const float* __restrict__ bg,
    const __bf16* __restrict__ W2H, const float* __restrict__ b2,
    const __bf16* __restrict__ W2VP, const __bf16* __restrict__ VP,
    const float* __restrict__ bvdot, float* __restrict__ araw, int last) {
  __shared__ __bf16 XH[EB * XSTR];
  __shared__ __bf16 RESB[EB * RSTR];
  __shared__ __bf16 Pb[EB * 8];
  int tid = threadIdx.x;
  int e0 = blockIdx.x * EB;
  float* XF = (float*)XH;

  {
    int row = tid >> 2, p = tid & 3;
    int se = src[e0 + row], de = dst[e0 + row];
    const bf8* psrc = (const bf8*)(nf16 + (size_t)se * DD + p * 16);
    *(bf8*)&XH[row * XSTR + p * 16]     = psrc[0];
    *(bf8*)&XH[row * XSTR + p * 16 + 8] = psrc[1];
    const bf8* pdst = (const bf8*)(nf16 + (size_t)de * DD + p * 16);
    *(bf8*)&XH[row * XSTR + 64 + p * 16]     = pdst[0];
    *(bf8*)&XH[row * XSTR + 64 + p * 16 + 8] = pdst[1];
    const bf8* pef = (const bf8*)(ef16 + (size_t)(e0 + row) * DD + p * 16);
    bf8 ev0 = pef[0], ev1 = pef[1];
    *(bf8*)&XH[row * XSTR + 128 + p * 16]     = ev0;
    *(bf8*)&XH[row * XSTR + 128 + p * 16 + 8] = ev1;
    *(bf8*)&RESB[row * RSTR + p * 16]     = ev0;
    *(bf8*)&RESB[row * RSTR + p * 16 + 8] = ev1;
  }
  __syncthreads();

  int cg = tid >> 6, l = tid & 63;
  int gq = l >> 4, i = l & 15;
  int col = cg * 16 + i;

  f32x4 acc[4][3];
#pragma unroll
  for (int rt = 0; rt < 4; ++rt)
#pragma unroll
    for (int t = 0; t < 3; ++t) acc[rt][t] = (f32x4){0.f, 0.f, 0.f, 0.f};
  f32x4 accQ = (f32x4){0.f, 0.f, 0.f, 0.f};   // pe accumulator

  // GEMM1: no barriers, no conditionals; B-tiles from global (L2-hot)
#pragma unroll
  for (int s = 0; s < 6; ++s) {
    bf8 a[4];
#pragma unroll
    for (int rt = 0; rt < 4; ++rt)
      a[rt] = *(const bf8*)&XH[(rt * 16 + i) * XSTR + s * 32 + gq * 8];
#pragma unroll
    for (int t = 0; t < 3; ++t) {
      bf8 bh = *(const bf8*)(W1H + ((size_t)((cg * 3 + t) * 6 + s) * 64 + l) * 8);
#pragma unroll
      for (int rt = 0; rt < 4; ++rt) acc[rt][t] = MFMA(a[rt], bh, acc[rt][t]);
    }
  }

  float b1v[3], gv[3], bgv[3];
#pragma unroll
  for (int t = 0; t < 3; ++t) {
    int n = cg * 48 + t * 16 + i;
    b1v[t] = b1[n]; gv[t] = g[n]; bgv[t] = bg[n];
  }
#pragma unroll
  for (int rt = 0; rt < 4; ++rt)
#pragma unroll
    for (int t = 0; t < 3; ++t)
#pragma unroll
      for (int r = 0; r < 4; ++r) acc[rt][t][r] += b1v[t];

#pragma unroll
  for (int rt = 0; rt < 4; ++rt)
#pragma unroll
    for (int r = 0; r < 4; ++r) {
      float sm = 0.f, sq = 0.f;
#pragma unroll
      for (int t = 0; t < 3; ++t) { float x = acc[rt][t][r]; sm += x; sq = fmaf(x, x, sq); }
#pragma unroll
      for (int off = 1; off <= 8; off <<= 1) {
        sm += __shfl_xor(sm, off, 64);
        sq += __shfl_xor(sq, off, 64);
      }
      if (i == 0) {
        int row = rt * 16 + gq * 4 + r;
        bf2 pr; pr[0] = (__bf16)sm; pr[1] = (__bf16)sq;
        *(bf2*)&Pb[row * 8 + cg * 2] = pr;
      }
    }
  __syncthreads();   // barrier 1

  if (tid < EB) {
    bf8 pv = *(const bf8*)&Pb[tid * 8];
    float sm = (float)pv[0] + (float)pv[2] + (float)pv[4] + (float)pv[6];
    float sq = (float)pv[1] + (float)pv[3] + (float)pv[5] + (float)pv[7];
    float mean = sm * (1.f / (float)DIN);
    float var = sq * (1.f / (float)DIN) - mean * mean;
    float rstd = 1.f / sqrtf(var + 1e-5f);
    bf2 mv; mv[0] = (__bf16)mean; mv[1] = (__bf16)rstd;
    *(bf2*)&Pb[tid * 8] = mv;
  }
  __syncthreads();   // barrier 2

#pragma unroll
  for (int rt = 0; rt < 4; ++rt)
#pragma unroll
    for (int r = 0; r < 4; ++r) {
      int row = rt * 16 + gq * 4 + r;
      bf2 mv = *(const bf2*)&Pb[row * 8];
      float mean = (float)mv[0], rstd = (float)mv[1];
#pragma unroll
      for (int t = 0; t < 3; ++t) {
        float y = (acc[rt][t][r] - mean) * rstd * gv[t] + bgv[t];
        y = fmaxf(y, 0.f);
        XH[row * XSTR + cg * 48 + t * 16 + i] = (__bf16)y;
      }
    }
  __syncthreads();   // barrier 3

  // GEMM2 (+ pe: H@(W2 v) over s=0..5, then ef_old@v over 2 RESB K-steps)
  f32x4 acc2[4];
#pragma unroll
  for (int rt = 0; rt < 4; ++rt) acc2[rt] = (f32x4){0.f, 0.f, 0.f, 0.f};

#pragma unroll
  for (int s = 0; s < 6; ++s) {
    bf8 a2[4];
#pragma unroll
    for (int rt = 0; rt < 4; ++rt)
      a2[rt] = *(const bf8*)&XH[(rt * 16 + i) * XSTR + s * 32 + gq * 8];
    bf8 bh = *(const bf8*)(W2H + ((size_t)(cg * 6 + s) * 64 + l) * 8);
#pragma unroll
    for (int rt = 0; rt < 4; ++rt) acc2[rt] = MFMA(a2[rt], bh, acc2[rt]);
    if (!last) {
      bf8 acg = *(const bf8*)&XH[(cg * 16 + i) * XSTR + s * 32 + gq * 8];
      bf8 wv = *(const bf8*)(W2VP + ((size_t)(s * 64 + l)) * 8);
      accQ = MFMA(acg, wv, accQ);
    }
  }
  if (!last) {
#pragma unroll
    for (int s2 = 0; s2 < 2; ++s2) {
      bf8 ae = *(const bf8*)&RESB[(cg * 16 + i) * RSTR + s2 * 32 + gq * 8];
      bf8 vp = *(const bf8*)(VP + ((size_t)(s2 * 64 + l)) * 8);
      accQ = MFMA(ae, vp, accQ);
    }
  }
  __syncthreads();   // barrier 4

  float b2v = b2[col];
#pragma unroll
  for (int rt = 0; rt < 4; ++rt)
#pragma unroll
    for (int r = 0; r < 4; ++r) {
      int row = rt * 16 + gq * 4 + r;
      float resv = (float)RESB[row * RSTR + col];
      XF[row * FSTR + col] = acc2[rt][r] + b2v + resv;
    }

  if (!last && i < 4) {
    float bvd = bvdot[i];
#pragma unroll
    for (int r = 0; r < 4; ++r) {
      int row = cg * 16 + gq * 4 + r;
      araw[(size_t)(e0 + row) * NH + i] = accQ[r] + bvd;
    }
  }
  __syncthreads();   // barrier 5

  {
    int row = tid >> 2, q = tid & 3;
    const float* fr = &XF[row * FSTR + q * 16];
    if (last) {
      float* op = efout + (size_t)(e0 + row) * DD + q * 16;
#pragma unroll
      for (int k = 0; k < 4; ++k)
        *(float4*)(op + k * 4) = *(const float4*)(fr + k * 4);
    } else {
      bf8 o0, o1;
#pragma unroll
      for (int k = 0; k < 8; ++k) { o0[k] = (__bf16)fr[k]; o1[k] = (__bf16)fr[k + 8]; }
      __bf16* op = ef16 + (size_t)(e0 + row) * DD + q * 16;
      *(bf8*)op = o0;
      *(bf8*)(op + 8) = o1;
    }
  }
}

extern "C" void kernel_launch(void* const* d_in, const int* in_sizes, int n_in,
                              void* d_out, int out_size, void* d_ws, size_t ws_size,
                              hipStream_t stream) {
  const float* node_feats = (const float*)d_in[0];
  const float* edge_feats = (const float*)d_in[1];
  const int*   edge_index = (const int*)d_in[2];
  const float* conv_w  = (const float*)d_in[3];
  const float* att_src = (const float*)d_in[4];
  const float* att_dst = (const float*)d_in[5];
  const float* edge_w  = (const float*)d_in[6];
  const float* att_edge= (const float*)d_in[7];
  const float* conv_b  = (const float*)d_in[8];
  const float* ln_g    = (const float*)d_in[9];
  const float* ln_b    = (const float*)d_in[10];
  const float* up1_w   = (const float*)d_in[11];
  const float* up1_b   = (const float*)d_in[12];
  const float* up_ln_g = (const float*)d_in[13];
  const float* up_ln_b = (const float*)d_in[14];
  const float* up2_w   = (const float*)d_in[15];
  const float* up2_b   = (const float*)d_in[16];

  const int* src = edge_index;
  const int* dst = edge_index + NE;

  float* nf = (float*)d_out;
  float* efout = nf + (size_t)NN * DD;

  float* w = (float*)d_ws;
  __bf16* xh16a = (__bf16*)w; w += (size_t)NN * DD / 2;
  __bf16* xh16b = (__bf16*)w; w += (size_t)NN * DD / 2;
  __bf16* nf16 = (__bf16*)w; w += (size_t)NN * DD / 2;
  __bf16* ef16 = (__bf16*)w; w += (size_t)NE * DD / 2;
  float* asA   = w; w += (size_t)NN * NH;
  float* adA   = w; w += (size_t)NN * NH;
  float* asB   = w; w += (size_t)NN * NH;
  float* adB   = w; w += (size_t)NN * NH;
  float* araw  = w; w += (size_t)NE * NH;
  float* vbuf  = w; w += 4 * 256;
  float* bvdot = w; w += 16;
  __bf16* W1H  = (__bf16*)w; w += (size_t)4 * 36864 / 2;
  __bf16* W2H  = (__bf16*)w; w += (size_t)4 * 12288 / 2;
  __bf16* W2VP = (__bf16*)w; w += (size_t)3 * 3072 / 2;
  __bf16* VPb  = (__bf16*)w; w += (size_t)3 * 1024 / 2;
  int* deg     = (int*)w; w += NN;
  int* offs    = (int*)w; w += NN + 2;
  int* cursor  = (int*)w; w += NN;
  int* bsum    = (int*)w; w += 128;
  int* boff    = (int*)w; w += 128;
  int2* csr_pack = (int2*)w; w += (size_t)NE * 2;

  __bf16* xh[2] = {xh16a, xh16b};
  float* as_[2] = {asA, asB};
  float* ad_[2] = {adA, adB};

  k_pack_w1<<<72, 256, 0, stream>>>(up1_w, W1H);
  k_pack_w2<<<24, 256, 0, stream>>>(up2_w, W2H);

  const int nb = (NN + 1023) / 1024;
  k_zero<<<(NN + 255) / 256, 256, 0, stream>>>(deg);
  k_hist<<<(NE + 255) / 256, 256, 0, stream>>>(dst, deg);
  k_scan1<<<nb, 256, 0, stream>>>(deg, offs, bsum);
  k_scan2<<<1, 64, 0, stream>>>(bsum, boff, offs, nb);
  k_scan3<<<(NN + 255) / 256, 256, 0, stream>>>(offs, boff, cursor);
  k_scatter<<<(NE + 255) / 256, 256, 0, stream>>>(src, dst, cursor, csr_pack);

  k_v_all<<<4, 256, 0, stream>>>(edge_w, att_edge, vbuf);
  k_w2v<<<3, 384, 0, stream>>>(up2_w, up2_b, vbuf, W2VP, VPb, bvdot);
  k_xh0<<<NN / 4 + 1, 256, 0, stream>>>(node_feats, conv_w, att_src, att_dst,
                                        nf16, xh16a, asA, adA);
  k_pass1f<<<NE / 64, 256, 0, stream>>>(edge_feats, vbuf, ef16, araw);

  for (int l = 0; l < NL; ++l) {
    int last = (l == NL - 1) ? 1 : 0;
    int cur = l & 1, nxt = (l + 1) & 1;
    k_gather5<<<NN / 4 + 1, 256, 0, stream>>>(
        xh[cur], araw, csr_pack, offs, as_[cur], ad_[cur],
        conv_b + (size_t)l * DD, ln_g + (size_t)l * DD, ln_b + (size_t)l * DD,
        nf16, nf,
        last ? conv_w : (conv_w + (size_t)(l + 1) * DD * DD),
        last ? att_src : (att_src + (size_t)(l + 1) * NH * NC),
        last ? att_dst : (att_dst + (size_t)(l + 1) * NH * NC),
        xh[nxt], as_[nxt], ad_[nxt], last);
    k_edge_mlp16<<<NE / EB, 256, 0, stream>>>(
        nf16, ef16, efout, src, dst,
        W1H + (size_t)l * 36864, up1_b + (size_t)l * DIN,
        up_ln_g + (size_t)l * DIN, up_ln_b + (size_t)l * DIN,
        W2H + (size_t)l * 12288, up2_b + (size_t)l * DD,
        last ? W2VP : (W2VP + (size_t)l * 3072),
        last ? VPb : (VPb + (size_t)l * 1024),
        bvdot + (size_t)l * 4, araw, last);
  }
}